// Round 1
// baseline (3852.638 us; speedup 1.0000x reference)
//
#include <hip/hip_runtime.h>

#define BB 32
#define LLAYERS 12
#define HDIM 768
#define NHEAD 12
#define DHEAD 64
#define SEQ 197
#define IND 800
#define NOUT 1000
#define EPSF 1e-5f
#define NTOK (BB * SEQ)     // 6304
#define NPATCH (BB * 196)   // 6272
#define SCALE 0.125f        // 1/sqrt(64)

// ---------------------------------------------------------------------------
// K1: conv(5x5, stride4, pad1) + bias + BN + ReLU + patchify -> X[n,p,800]
// one block per (n, patch); stage 21x21x3 input tile + all weights in LDS
// ---------------------------------------------------------------------------
__global__ __launch_bounds__(256) void k_conv_patch(
    const float* __restrict__ img, const float* __restrict__ cw,
    const float* __restrict__ cb, const float* __restrict__ bg,
    const float* __restrict__ bbias, const float* __restrict__ bm,
    const float* __restrict__ bvv, float* __restrict__ X)
{
    __shared__ float tile[3][21][21];
    __shared__ float w[2400];           // 32*75
    __shared__ float scale[32], shift[32];
    int blk = blockIdx.x;               // n*196 + p
    int n = blk / 196, p = blk % 196;
    int py = p / 14, px = p % 14;
    int tid = threadIdx.x;

    for (int i = tid; i < 2400; i += 256) w[i] = cw[i];
    if (tid < 32) {
        float sc = bg[tid] * rsqrtf(bvv[tid] + EPSF);
        scale[tid] = sc;
        shift[tid] = (cb[tid] - bm[tid]) * sc + bbias[tid];
    }
    int h0 = py * 20 - 1, w0 = px * 20 - 1;
    for (int i = tid; i < 3 * 21 * 21; i += 256) {
        int c = i / 441, r = (i / 21) % 21, cc = i % 21;
        int gh = h0 + r, gw = w0 + cc;
        float v = 0.f;
        if (gh >= 0 && gh < 280 && gw >= 0 && gw < 280)
            v = img[((long)(n * 3 + c) * 280 + gh) * 280 + gw];
        tile[c][r][cc] = v;
    }
    __syncthreads();
    for (int o = tid; o < 800; o += 256) {
        int c = o / 25, r = o % 25, ph = r / 5, pw = r % 5;
        float acc = 0.f;
        const float* wp = &w[c * 75];
        #pragma unroll
        for (int ci = 0; ci < 3; ci++)
            #pragma unroll
            for (int kh = 0; kh < 5; kh++)
                #pragma unroll
                for (int kw = 0; kw < 5; kw++)
                    acc += tile[ci][ph * 4 + kh][pw * 4 + kw] * wp[ci * 25 + kh * 5 + kw];
        float val = acc * scale[c] + shift[c];
        X[(long)blk * 800 + o] = fmaxf(val, 0.f);
    }
}

// ---------------------------------------------------------------------------
// K1b: cls row: tok[n,0,:] = cls_tok + pos_emb[0]  (pos[0,e] = e odd ? 1 : 0)
// ---------------------------------------------------------------------------
__global__ void k_cls(const float* __restrict__ cls_tok, float* __restrict__ tok)
{
    int n = blockIdx.x, tid = threadIdx.x;
    for (int e = tid; e < HDIM; e += 256)
        tok[(long)n * SEQ * HDIM + e] = cls_tok[e] + ((e & 1) ? 1.0f : 0.0f);
}

// ---------------------------------------------------------------------------
// K2: patch embed GEMM: tok[n,1+p,e] = X[n,p,:] @ map_w[e,:] + map_b[e] + pos(1+p,e)
// M=6272, N=768, K=800. BM=BN=64, BK=32, 256 thr, 4x4 micro.
// ---------------------------------------------------------------------------
__global__ __launch_bounds__(256) void k_embed(
    const float* __restrict__ Xg, const float* __restrict__ Wg,
    const float* __restrict__ bias, float* __restrict__ tok)
{
    __shared__ float As[64][33];
    __shared__ float Bs[64][33];
    int m0 = blockIdx.x * 64, e0 = blockIdx.y * 64;
    int tid = threadIdx.x;
    int tx = tid % 16, ty = tid / 16;
    float acc[4][4] = {};
    for (int k0 = 0; k0 < 800; k0 += 32) {
        #pragma unroll
        for (int i = 0; i < 2; i++) {
            int id = tid + i * 256;          // 0..511
            int r = id >> 3, c4 = id & 7;    // 64 rows x 8 float4
            float4 av = *(const float4*)&Xg[(long)(m0 + r) * 800 + k0 + c4 * 4];
            As[r][c4 * 4 + 0] = av.x; As[r][c4 * 4 + 1] = av.y;
            As[r][c4 * 4 + 2] = av.z; As[r][c4 * 4 + 3] = av.w;
            float4 bv = *(const float4*)&Wg[(long)(e0 + r) * 800 + k0 + c4 * 4];
            Bs[r][c4 * 4 + 0] = bv.x; Bs[r][c4 * 4 + 1] = bv.y;
            Bs[r][c4 * 4 + 2] = bv.z; Bs[r][c4 * 4 + 3] = bv.w;
        }
        __syncthreads();
        #pragma unroll
        for (int kk = 0; kk < 32; kk++) {
            float a[4], b[4];
            #pragma unroll
            for (int i = 0; i < 4; i++) a[i] = As[ty * 4 + i][kk];
            #pragma unroll
            for (int j = 0; j < 4; j++) b[j] = Bs[tx * 4 + j][kk];
            #pragma unroll
            for (int i = 0; i < 4; i++)
                #pragma unroll
                for (int j = 0; j < 4; j++) acc[i][j] += a[i] * b[j];
        }
        __syncthreads();
    }
    #pragma unroll
    for (int i = 0; i < 4; i++) {
        int m = m0 + ty * 4 + i;
        int n = m / 196, pp = m % 196, s = pp + 1;
        #pragma unroll
        for (int j = 0; j < 4; j++) {
            int e = e0 + tx * 4 + j;
            float freq = expf((float)(e & ~1) * (-9.210340371976184f / 768.0f));
            float ang = (float)s * freq;
            float pos = (e & 1) ? cosf(ang) : sinf(ang);
            tok[((long)n * SEQ + s) * HDIM + e] = acc[i][j] + bias[e] + pos;
        }
    }
}

// ---------------------------------------------------------------------------
// K3: LayerNorm stats per token row: mu, rstd
// ---------------------------------------------------------------------------
__global__ __launch_bounds__(256) void k_lnstats(
    const float* __restrict__ tok, float* __restrict__ stats)
{
    int row = blockIdx.x, tid = threadIdx.x;
    const float* p = tok + (long)row * HDIM;
    float s = 0.f, sq = 0.f;
    for (int i = tid; i < HDIM; i += 256) { float v = p[i]; s += v; sq += v * v; }
    __shared__ float rs[256], rq[256];
    rs[tid] = s; rq[tid] = sq; __syncthreads();
    for (int off = 128; off > 0; off >>= 1) {
        if (tid < off) { rs[tid] += rs[tid + off]; rq[tid] += rq[tid + off]; }
        __syncthreads();
    }
    if (tid == 0) {
        float mu = rs[0] / 768.f;
        float var = rq[0] / 768.f - mu * mu;
        stats[row * 2] = mu;
        stats[row * 2 + 1] = rsqrtf(var + EPSF);
    }
}

// ---------------------------------------------------------------------------
// K4: QKV per head, 64-token tiles. q[n,h,s,e] = LN(tok)[h-slice] @ Wq[h]^T + bq
// grid: (99 token tiles, 12 heads)
// ---------------------------------------------------------------------------
__global__ __launch_bounds__(256) void k_qkv(
    const float* __restrict__ tok, const float* __restrict__ stats,
    const float* __restrict__ lng, const float* __restrict__ lnb,
    const float* __restrict__ wqp, const float* __restrict__ bqp,
    const float* __restrict__ wkp, const float* __restrict__ bkp,
    const float* __restrict__ wvp, const float* __restrict__ bvp,
    float* __restrict__ qo, float* __restrict__ ko, float* __restrict__ vo)
{
    __shared__ float xh[64][65];
    __shared__ float W[3][64][65];
    __shared__ float bias[3][64];
    int h = blockIdx.y, t0 = blockIdx.x * 64, tid = threadIdx.x;

    const float* wsrc0 = wqp + (long)h * 4096;
    const float* wsrc1 = wkp + (long)h * 4096;
    const float* wsrc2 = wvp + (long)h * 4096;
    #pragma unroll
    for (int i = 0; i < 4; i++) {
        int id = tid + i * 256;          // 0..1023
        int r = id >> 4, c4 = id & 15;   // 64 rows x 16 float4
        float4 v0 = *(const float4*)&wsrc0[r * 64 + c4 * 4];
        W[0][r][c4 * 4 + 0] = v0.x; W[0][r][c4 * 4 + 1] = v0.y;
        W[0][r][c4 * 4 + 2] = v0.z; W[0][r][c4 * 4 + 3] = v0.w;
        float4 v1 = *(const float4*)&wsrc1[r * 64 + c4 * 4];
        W[1][r][c4 * 4 + 0] = v1.x; W[1][r][c4 * 4 + 1] = v1.y;
        W[1][r][c4 * 4 + 2] = v1.z; W[1][r][c4 * 4 + 3] = v1.w;
        float4 v2 = *(const float4*)&wsrc2[r * 64 + c4 * 4];
        W[2][r][c4 * 4 + 0] = v2.x; W[2][r][c4 * 4 + 1] = v2.y;
        W[2][r][c4 * 4 + 2] = v2.z; W[2][r][c4 * 4 + 3] = v2.w;
    }
    if (tid < 64) {
        bias[0][tid] = bqp[h * 64 + tid];
        bias[1][tid] = bkp[h * 64 + tid];
        bias[2][tid] = bvp[h * 64 + tid];
    }
    #pragma unroll
    for (int i = 0; i < 4; i++) {
        int id = tid + i * 256;
        int r = id >> 4, c4 = id & 15;
        int row = t0 + r;
        float4 v = {0.f, 0.f, 0.f, 0.f};
        float mu = 0.f, rstd = 0.f;
        if (row < NTOK) {
            v = *(const float4*)&tok[(long)row * HDIM + h * 64 + c4 * 4];
            mu = stats[row * 2]; rstd = stats[row * 2 + 1];
        }
        int d = c4 * 4;
        xh[r][d + 0] = (v.x - mu) * rstd * lng[h * 64 + d + 0] + lnb[h * 64 + d + 0];
        xh[r][d + 1] = (v.y - mu) * rstd * lng[h * 64 + d + 1] + lnb[h * 64 + d + 1];
        xh[r][d + 2] = (v.z - mu) * rstd * lng[h * 64 + d + 2] + lnb[h * 64 + d + 2];
        xh[r][d + 3] = (v.w - mu) * rstd * lng[h * 64 + d + 3] + lnb[h * 64 + d + 3];
    }
    __syncthreads();

    int tx = tid % 16, ty = tid / 16;
    for (int m = 0; m < 3; m++) {
        const float (*Wm)[65] = W[m];
        float acc[4][4] = {};
        #pragma unroll 8
        for (int d = 0; d < 64; d++) {
            float a[4], b[4];
            #pragma unroll
            for (int i = 0; i < 4; i++) a[i] = xh[ty * 4 + i][d];
            #pragma unroll
            for (int j = 0; j < 4; j++) b[j] = Wm[tx * 4 + j][d];
            #pragma unroll
            for (int i = 0; i < 4; i++)
                #pragma unroll
                for (int j = 0; j < 4; j++) acc[i][j] += a[i] * b[j];
        }
        float* op = (m == 0) ? qo : (m == 1) ? ko : vo;
        #pragma unroll
        for (int i = 0; i < 4; i++) {
            int row = t0 + ty * 4 + i;
            if (row < NTOK) {
                int n = row / SEQ, s = row % SEQ;
                long base = (((long)n * NHEAD + h) * SEQ + s) * DHEAD;
                #pragma unroll
                for (int j = 0; j < 4; j++)
                    op[base + tx * 4 + j] = acc[i][j] + bias[m][tx * 4 + j];
            }
        }
    }
}

// ---------------------------------------------------------------------------
// K5: attention + residual. grid (7 qtiles, 12 heads, 32 batch), 256 thr.
// Per block: 32 queries vs all 197 keys (full softmax, no online rescale).
// ---------------------------------------------------------------------------
__global__ __launch_bounds__(256) void k_attn(
    const float* __restrict__ qg, const float* __restrict__ kg,
    const float* __restrict__ vg, float* __restrict__ tok)
{
    __shared__ float Q[32][65];
    __shared__ float KV[128][65];
    __shared__ float Sc[32][200];
    __shared__ float redm[32][8];
    __shared__ float rowsum[32];
    int n = blockIdx.z, h = blockIdx.y, q0 = blockIdx.x * 32;
    int tid = threadIdx.x;
    long base = ((long)n * NHEAD + h) * SEQ * DHEAD;

    #pragma unroll
    for (int i = 0; i < 2; i++) {
        int id = tid + i * 256;          // 0..511
        int r = id >> 4, c4 = id & 15;
        int row = q0 + r;
        float4 v = {0.f, 0.f, 0.f, 0.f};
        if (row < SEQ) v = *(const float4*)&qg[base + (long)row * 64 + c4 * 4];
        Q[r][c4 * 4 + 0] = v.x; Q[r][c4 * 4 + 1] = v.y;
        Q[r][c4 * 4 + 2] = v.z; Q[r][c4 * 4 + 3] = v.w;
    }

    int tqg = tid >> 5;   // 0..7  -> tq = tqg*4
    int ttg = tid & 31;   // 0..31 -> t  = ttg*4 within chunk
    for (int c0 = 0; c0 < SEQ; c0 += 128) {
        __syncthreads();
        #pragma unroll
        for (int i = 0; i < 8; i++) {
            int id = tid + i * 256;        // 0..2047
            int r = id >> 4, c4 = id & 15;
            int row = c0 + r;
            float4 v = {0.f, 0.f, 0.f, 0.f};
            if (row < SEQ) v = *(const float4*)&kg[base + (long)row * 64 + c4 * 4];
            KV[r][c4 * 4 + 0] = v.x; KV[r][c4 * 4 + 1] = v.y;
            KV[r][c4 * 4 + 2] = v.z; KV[r][c4 * 4 + 3] = v.w;
        }
        __syncthreads();
        float acc[4][4] = {};
        #pragma unroll 8
        for (int d = 0; d < 64; d++) {
            float a[4], b[4];
            #pragma unroll
            for (int i = 0; i < 4; i++) a[i] = Q[tqg * 4 + i][d];
            #pragma unroll
            for (int j = 0; j < 4; j++) b[j] = KV[ttg * 4 + j][d];
            #pragma unroll
            for (int i = 0; i < 4; i++)
                #pragma unroll
                for (int j = 0; j < 4; j++) acc[i][j] += a[i] * b[j];
        }
        #pragma unroll
        for (int i = 0; i < 4; i++)
            #pragma unroll
            for (int j = 0; j < 4; j++) {
                int t = c0 + ttg * 4 + j;
                if (t < SEQ) Sc[tqg * 4 + i][t] = acc[i][j] * SCALE;
            }
    }
    __syncthreads();

    // softmax (store unnormalized exp, defer 1/sum to output)
    int row = tid >> 3, sub = tid & 7;
    float m = -1e30f;
    for (int t = sub; t < SEQ; t += 8) m = fmaxf(m, Sc[row][t]);
    redm[row][sub] = m;
    __syncthreads();
    if (sub == 0) {
        float mm = redm[row][0];
        #pragma unroll
        for (int u = 1; u < 8; u++) mm = fmaxf(mm, redm[row][u]);
        redm[row][0] = mm;
    }
    __syncthreads();
    float mx = redm[row][0];
    float ssum = 0.f;
    for (int t = sub; t < SEQ; t += 8) {
        float e = __expf(Sc[row][t] - mx);
        Sc[row][t] = e; ssum += e;
    }
    __syncthreads();
    redm[row][sub] = ssum;
    __syncthreads();
    if (sub == 0) {
        float ss = 0.f;
        #pragma unroll
        for (int u = 0; u < 8; u++) ss += redm[row][u];
        rowsum[row] = ss;
    }

    // P @ V
    int eg = tid & 31;    // e = eg*2
    int tg = tid >> 5;    // tq = tg*4
    float oacc[4][2] = {};
    for (int c0 = 0; c0 < SEQ; c0 += 128) {
        __syncthreads();
        #pragma unroll
        for (int i = 0; i < 8; i++) {
            int id = tid + i * 256;
            int r = id >> 4, c4 = id & 15;
            int row2 = c0 + r;
            float4 v = {0.f, 0.f, 0.f, 0.f};
            if (row2 < SEQ) v = *(const float4*)&vg[base + (long)row2 * 64 + c4 * 4];
            KV[r][c4 * 4 + 0] = v.x; KV[r][c4 * 4 + 1] = v.y;
            KV[r][c4 * 4 + 2] = v.z; KV[r][c4 * 4 + 3] = v.w;
        }
        __syncthreads();
        int tmax = (SEQ - c0 < 128) ? (SEQ - c0) : 128;
        for (int t = 0; t < tmax; t++) {
            float p[4], vv0, vv1;
            #pragma unroll
            for (int i = 0; i < 4; i++) p[i] = Sc[tg * 4 + i][c0 + t];
            vv0 = KV[t][eg * 2]; vv1 = KV[t][eg * 2 + 1];
            #pragma unroll
            for (int i = 0; i < 4; i++) {
                oacc[i][0] += p[i] * vv0;
                oacc[i][1] += p[i] * vv1;
            }
        }
    }
    #pragma unroll
    for (int i = 0; i < 4; i++) {
        int tq = tg * 4 + i, r = q0 + tq;
        if (r < SEQ) {
            float rinv = 1.f / rowsum[tq];
            long o = ((long)n * SEQ + r) * HDIM + h * 64 + eg * 2;
            tok[o]     += oacc[i][0] * rinv;
            tok[o + 1] += oacc[i][1] * rinv;
        }
    }
}

// ---------------------------------------------------------------------------
// K6: classifier head + softmax. one block per image.
// ---------------------------------------------------------------------------
__global__ __launch_bounds__(256) void k_head(
    const float* __restrict__ tok, const float* __restrict__ W,
    const float* __restrict__ b, float* __restrict__ out)
{
    __shared__ float cls[HDIM];
    __shared__ float logit[NOUT];
    __shared__ float red[256];
    int n = blockIdx.x, tid = threadIdx.x;
    for (int i = tid; i < HDIM; i += 256) cls[i] = tok[(long)n * SEQ * HDIM + i];
    __syncthreads();
    for (int o = tid; o < NOUT; o += 256) {
        float acc = 0.f;
        const float* wr = &W[(long)o * HDIM];
        for (int d = 0; d < HDIM; d++) acc += cls[d] * wr[d];
        logit[o] = acc + b[o];
    }
    __syncthreads();
    float m = -1e30f;
    for (int o = tid; o < NOUT; o += 256) m = fmaxf(m, logit[o]);
    red[tid] = m; __syncthreads();
    for (int off = 128; off > 0; off >>= 1) {
        if (tid < off) red[tid] = fmaxf(red[tid], red[tid + off]);
        __syncthreads();
    }
    float mx = red[0];
    __syncthreads();
    float s = 0.f;
    for (int o = tid; o < NOUT; o += 256) {
        float e = __expf(logit[o] - mx);
        logit[o] = e; s += e;
    }
    red[tid] = s; __syncthreads();
    for (int off = 128; off > 0; off >>= 1) {
        if (tid < off) red[tid] += red[tid + off];
        __syncthreads();
    }
    float inv = 1.f / red[0];
    for (int o = tid; o < NOUT; o += 256) out[(long)n * NOUT + o] = logit[o] * inv;
}

// ---------------------------------------------------------------------------
extern "C" void kernel_launch(void* const* d_in, const int* in_sizes, int n_in,
                              void* d_out, int out_size, void* d_ws, size_t ws_size,
                              hipStream_t stream)
{
    const float* images  = (const float*)d_in[0];
    const float* conv_w  = (const float*)d_in[1];
    const float* conv_b  = (const float*)d_in[2];
    const float* bn_g    = (const float*)d_in[3];
    const float* bn_b    = (const float*)d_in[4];
    const float* bn_m    = (const float*)d_in[5];
    const float* bn_v    = (const float*)d_in[6];
    const float* map_w   = (const float*)d_in[7];
    const float* map_b   = (const float*)d_in[8];
    const float* cls_tok = (const float*)d_in[9];
    const float* ln_g    = (const float*)d_in[10];
    const float* ln_b    = (const float*)d_in[11];
    const float* wq      = (const float*)d_in[12];
    const float* bq      = (const float*)d_in[13];
    const float* wk      = (const float*)d_in[14];
    const float* bk      = (const float*)d_in[15];
    const float* wv      = (const float*)d_in[16];
    const float* bv      = (const float*)d_in[17];
    const float* mlp_w   = (const float*)d_in[18];
    const float* mlp_b   = (const float*)d_in[19];
    float* out = (float*)d_out;

    float* ws = (float*)d_ws;
    const long SZ_X   = (long)NPATCH * IND;     // 5,017,600
    const long SZ_TOK = (long)NTOK * HDIM;      // 4,841,472
    float* X     = ws;                // reused as q buffer after embed
    float* tok   = X + SZ_X;
    float* kb    = tok + SZ_TOK;
    float* vb    = kb + SZ_TOK;
    float* stats = vb + SZ_TOK;       // 2*NTOK
    float* qb    = X;                 // overlap: X dead after k_embed

    k_conv_patch<<<NPATCH, 256, 0, stream>>>(images, conv_w, conv_b, bn_g, bn_b,
                                             bn_m, bn_v, X);
    k_cls<<<BB, 256, 0, stream>>>(cls_tok, tok);
    dim3 ge(98, 12);
    k_embed<<<ge, 256, 0, stream>>>(X, map_w, map_b, tok);

    for (int l = 0; l < LLAYERS; l++) {
        k_lnstats<<<NTOK, 256, 0, stream>>>(tok, stats);
        dim3 gq(99, 12);
        k_qkv<<<gq, 256, 0, stream>>>(tok, stats,
            ln_g + (long)l * HDIM, ln_b + (long)l * HDIM,
            wq + (long)l * NHEAD * DHEAD * DHEAD, bq + (long)l * NHEAD * DHEAD,
            wk + (long)l * NHEAD * DHEAD * DHEAD, bk + (long)l * NHEAD * DHEAD,
            wv + (long)l * NHEAD * DHEAD * DHEAD, bv + (long)l * NHEAD * DHEAD,
            qb, kb, vb);
        dim3 ga(7, 12, 32);
        k_attn<<<ga, 256, 0, stream>>>(qb, kb, vb, tok);
    }
    k_head<<<BB, 256, 0, stream>>>(tok, mlp_w, mlp_b, out);
}

// Round 2
// 1850.517 us; speedup vs baseline: 2.0819x; 2.0819x over previous
//
#include <hip/hip_runtime.h>

#define BB 32
#define LLAYERS 12
#define HDIM 768
#define NHEAD 12
#define DHEAD 64
#define SEQ 197
#define IND 800
#define NOUT 1000
#define EPSF 1e-5f
#define NTOK (BB * SEQ)     // 6304
#define NPATCH (BB * 196)   // 6272
#define SCALE 0.125f        // 1/sqrt(64)

typedef __attribute__((ext_vector_type(4))) float f32x4;
typedef __attribute__((ext_vector_type(8))) short short8;

static __device__ __forceinline__ ushort f2bf(float f) {
    union { float f; unsigned u; } v; v.f = f;
    unsigned r = v.u + 0x7FFFu + ((v.u >> 16) & 1u);   // round-to-nearest-even
    return (ushort)(r >> 16);
}

// ---------------------------------------------------------------------------
// K1: conv(5x5, stride4, pad1) + bias + BN + ReLU + patchify -> X[n,p,800]
// ---------------------------------------------------------------------------
__global__ __launch_bounds__(256) void k_conv_patch(
    const float* __restrict__ img, const float* __restrict__ cw,
    const float* __restrict__ cb, const float* __restrict__ bg,
    const float* __restrict__ bbias, const float* __restrict__ bm,
    const float* __restrict__ bvv, float* __restrict__ X)
{
    __shared__ float tile[3][21][21];
    __shared__ float w[2400];
    __shared__ float scale[32], shift[32];
    int blk = blockIdx.x;
    int n = blk / 196, p = blk % 196;
    int py = p / 14, px = p % 14;
    int tid = threadIdx.x;

    for (int i = tid; i < 2400; i += 256) w[i] = cw[i];
    if (tid < 32) {
        float sc = bg[tid] * rsqrtf(bvv[tid] + EPSF);
        scale[tid] = sc;
        shift[tid] = (cb[tid] - bm[tid]) * sc + bbias[tid];
    }
    int h0 = py * 20 - 1, w0 = px * 20 - 1;
    for (int i = tid; i < 3 * 21 * 21; i += 256) {
        int c = i / 441, r = (i / 21) % 21, cc = i % 21;
        int gh = h0 + r, gw = w0 + cc;
        float v = 0.f;
        if (gh >= 0 && gh < 280 && gw >= 0 && gw < 280)
            v = img[((long)(n * 3 + c) * 280 + gh) * 280 + gw];
        tile[c][r][cc] = v;
    }
    __syncthreads();
    for (int o = tid; o < 800; o += 256) {
        int c = o / 25, r = o % 25, ph = r / 5, pw = r % 5;
        float acc = 0.f;
        const float* wp = &w[c * 75];
        #pragma unroll
        for (int ci = 0; ci < 3; ci++)
            #pragma unroll
            for (int kh = 0; kh < 5; kh++)
                #pragma unroll
                for (int kw = 0; kw < 5; kw++)
                    acc += tile[ci][ph * 4 + kh][pw * 4 + kw] * wp[ci * 25 + kh * 5 + kw];
        float val = acc * scale[c] + shift[c];
        X[(long)blk * 800 + o] = fmaxf(val, 0.f);
    }
}

__global__ void k_cls(const float* __restrict__ cls_tok, float* __restrict__ tok)
{
    int n = blockIdx.x, tid = threadIdx.x;
    for (int e = tid; e < HDIM; e += 256)
        tok[(long)n * SEQ * HDIM + e] = cls_tok[e] + ((e & 1) ? 1.0f : 0.0f);
}

// ---------------------------------------------------------------------------
// K2: patch embed GEMM (fp32, unchanged this round)
// ---------------------------------------------------------------------------
__global__ __launch_bounds__(256) void k_embed(
    const float* __restrict__ Xg, const float* __restrict__ Wg,
    const float* __restrict__ bias, float* __restrict__ tok)
{
    __shared__ float As[64][33];
    __shared__ float Bs[64][33];
    int m0 = blockIdx.x * 64, e0 = blockIdx.y * 64;
    int tid = threadIdx.x;
    int tx = tid % 16, ty = tid / 16;
    float acc[4][4] = {};
    for (int k0 = 0; k0 < 800; k0 += 32) {
        #pragma unroll
        for (int i = 0; i < 2; i++) {
            int id = tid + i * 256;
            int r = id >> 3, c4 = id & 7;
            float4 av = *(const float4*)&Xg[(long)(m0 + r) * 800 + k0 + c4 * 4];
            As[r][c4 * 4 + 0] = av.x; As[r][c4 * 4 + 1] = av.y;
            As[r][c4 * 4 + 2] = av.z; As[r][c4 * 4 + 3] = av.w;
            float4 bv = *(const float4*)&Wg[(long)(e0 + r) * 800 + k0 + c4 * 4];
            Bs[r][c4 * 4 + 0] = bv.x; Bs[r][c4 * 4 + 1] = bv.y;
            Bs[r][c4 * 4 + 2] = bv.z; Bs[r][c4 * 4 + 3] = bv.w;
        }
        __syncthreads();
        #pragma unroll
        for (int kk = 0; kk < 32; kk++) {
            float a[4], b[4];
            #pragma unroll
            for (int i = 0; i < 4; i++) a[i] = As[ty * 4 + i][kk];
            #pragma unroll
            for (int j = 0; j < 4; j++) b[j] = Bs[tx * 4 + j][kk];
            #pragma unroll
            for (int i = 0; i < 4; i++)
                #pragma unroll
                for (int j = 0; j < 4; j++) acc[i][j] += a[i] * b[j];
        }
        __syncthreads();
    }
    #pragma unroll
    for (int i = 0; i < 4; i++) {
        int m = m0 + ty * 4 + i;
        int n = m / 196, pp = m % 196, s = pp + 1;
        #pragma unroll
        for (int j = 0; j < 4; j++) {
            int e = e0 + tx * 4 + j;
            float freq = expf((float)(e & ~1) * (-9.210340371976184f / 768.0f));
            float ang = (float)s * freq;
            float pos = (e & 1) ? cosf(ang) : sinf(ang);
            tok[((long)n * SEQ + s) * HDIM + e] = acc[i][j] + bias[e] + pos;
        }
    }
}

// ---------------------------------------------------------------------------
// K3: LayerNorm stats per token row
// ---------------------------------------------------------------------------
__global__ __launch_bounds__(256) void k_lnstats(
    const float* __restrict__ tok, float* __restrict__ stats)
{
    int row = blockIdx.x, tid = threadIdx.x;
    const float* p = tok + (long)row * HDIM;
    float s = 0.f, sq = 0.f;
    for (int i = tid; i < HDIM; i += 256) { float v = p[i]; s += v; sq += v * v; }
    __shared__ float rs[256], rq[256];
    rs[tid] = s; rq[tid] = sq; __syncthreads();
    for (int off = 128; off > 0; off >>= 1) {
        if (tid < off) { rs[tid] += rs[tid + off]; rq[tid] += rq[tid + off]; }
        __syncthreads();
    }
    if (tid == 0) {
        float mu = rs[0] / 768.f;
        float var = rq[0] / 768.f - mu * mu;
        stats[row * 2] = mu;
        stats[row * 2 + 1] = rsqrtf(var + EPSF);
    }
}

// ---------------------------------------------------------------------------
// K4: QKV per head (fp32, unchanged this round)
// ---------------------------------------------------------------------------
__global__ __launch_bounds__(256) void k_qkv(
    const float* __restrict__ tok, const float* __restrict__ stats,
    const float* __restrict__ lng, const float* __restrict__ lnb,
    const float* __restrict__ wqp, const float* __restrict__ bqp,
    const float* __restrict__ wkp, const float* __restrict__ bkp,
    const float* __restrict__ wvp, const float* __restrict__ bvp,
    float* __restrict__ qo, float* __restrict__ ko, float* __restrict__ vo)
{
    __shared__ float xh[64][65];
    __shared__ float W[3][64][65];
    __shared__ float bias[3][64];
    int h = blockIdx.y, t0 = blockIdx.x * 64, tid = threadIdx.x;

    const float* wsrc0 = wqp + (long)h * 4096;
    const float* wsrc1 = wkp + (long)h * 4096;
    const float* wsrc2 = wvp + (long)h * 4096;
    #pragma unroll
    for (int i = 0; i < 4; i++) {
        int id = tid + i * 256;
        int r = id >> 4, c4 = id & 15;
        float4 v0 = *(const float4*)&wsrc0[r * 64 + c4 * 4];
        W[0][r][c4 * 4 + 0] = v0.x; W[0][r][c4 * 4 + 1] = v0.y;
        W[0][r][c4 * 4 + 2] = v0.z; W[0][r][c4 * 4 + 3] = v0.w;
        float4 v1 = *(const float4*)&wsrc1[r * 64 + c4 * 4];
        W[1][r][c4 * 4 + 0] = v1.x; W[1][r][c4 * 4 + 1] = v1.y;
        W[1][r][c4 * 4 + 2] = v1.z; W[1][r][c4 * 4 + 3] = v1.w;
        float4 v2 = *(const float4*)&wsrc2[r * 64 + c4 * 4];
        W[2][r][c4 * 4 + 0] = v2.x; W[2][r][c4 * 4 + 1] = v2.y;
        W[2][r][c4 * 4 + 2] = v2.z; W[2][r][c4 * 4 + 3] = v2.w;
    }
    if (tid < 64) {
        bias[0][tid] = bqp[h * 64 + tid];
        bias[1][tid] = bkp[h * 64 + tid];
        bias[2][tid] = bvp[h * 64 + tid];
    }
    #pragma unroll
    for (int i = 0; i < 4; i++) {
        int id = tid + i * 256;
        int r = id >> 4, c4 = id & 15;
        int row = t0 + r;
        float4 v = {0.f, 0.f, 0.f, 0.f};
        float mu = 0.f, rstd = 0.f;
        if (row < NTOK) {
            v = *(const float4*)&tok[(long)row * HDIM + h * 64 + c4 * 4];
            mu = stats[row * 2]; rstd = stats[row * 2 + 1];
        }
        int d = c4 * 4;
        xh[r][d + 0] = (v.x - mu) * rstd * lng[h * 64 + d + 0] + lnb[h * 64 + d + 0];
        xh[r][d + 1] = (v.y - mu) * rstd * lng[h * 64 + d + 1] + lnb[h * 64 + d + 1];
        xh[r][d + 2] = (v.z - mu) * rstd * lng[h * 64 + d + 2] + lnb[h * 64 + d + 2];
        xh[r][d + 3] = (v.w - mu) * rstd * lng[h * 64 + d + 3] + lnb[h * 64 + d + 3];
    }
    __syncthreads();

    int tx = tid % 16, ty = tid / 16;
    for (int m = 0; m < 3; m++) {
        const float (*Wm)[65] = W[m];
        float acc[4][4] = {};
        #pragma unroll 8
        for (int d = 0; d < 64; d++) {
            float a[4], b[4];
            #pragma unroll
            for (int i = 0; i < 4; i++) a[i] = xh[ty * 4 + i][d];
            #pragma unroll
            for (int j = 0; j < 4; j++) b[j] = Wm[tx * 4 + j][d];
            #pragma unroll
            for (int i = 0; i < 4; i++)
                #pragma unroll
                for (int j = 0; j < 4; j++) acc[i][j] += a[i] * b[j];
        }
        float* op = (m == 0) ? qo : (m == 1) ? ko : vo;
        #pragma unroll
        for (int i = 0; i < 4; i++) {
            int row = t0 + ty * 4 + i;
            if (row < NTOK) {
                int n = row / SEQ, s = row % SEQ;
                long base = (((long)n * NHEAD + h) * SEQ + s) * DHEAD;
                #pragma unroll
                for (int j = 0; j < 4; j++)
                    op[base + tx * 4 + j] = acc[i][j] + bias[m][tx * 4 + j];
            }
        }
    }
}

// ---------------------------------------------------------------------------
// K5: bf16-MFMA fused attention + residual.
// grid (4 qblocks, 12 heads, 32 batch), 256 thr = 4 waves.
// Each wave owns a 16-query strip; block stages K [208][72] bf16 and
// V transposed [64][232] bf16 in LDS. Scores kept in 13 C-frags; softmax
// via 16-lane shuffle reductions; P->A-layout via per-wave LDS scratch.
// ---------------------------------------------------------------------------
__global__ __launch_bounds__(256, 2) void k_attn(
    const float* __restrict__ qg, const float* __restrict__ kg,
    const float* __restrict__ vg, float* __restrict__ tok)
{
    __shared__ __align__(16) ushort Ks[208 * 72];    // K rows, stride 72 bf16
    __shared__ __align__(16) ushort Vt[64 * 232];    // V^T: [e][t], stride 232
    __shared__ __align__(16) ushort Ps[4][16 * 40];  // per-wave P scratch

    int n = blockIdx.z, h = blockIdx.y;
    int tid = threadIdx.x;
    int lane = tid & 63;
    int wave = tid >> 6;
    int col = lane & 15;          // MFMA n / C-col index
    int quad = lane >> 4;         // 0..3
    long base = ((long)n * NHEAD + h) * SEQ * DHEAD;

    // ---- stage K (bf16, zero-padded rows 197..207) ----
    for (int id = tid; id < 208 * 16; id += 256) {
        int t = id >> 4, e4 = id & 15;
        ushort4 w = {0, 0, 0, 0};
        if (t < SEQ) {
            float4 v = *(const float4*)&kg[base + (long)t * 64 + e4 * 4];
            w.x = f2bf(v.x); w.y = f2bf(v.y); w.z = f2bf(v.z); w.w = f2bf(v.w);
        }
        *(ushort4*)&Ks[t * 72 + e4 * 4] = w;
    }
    // ---- stage V transposed (bf16, zero-padded t 197..223) ----
    for (int c = wave; c < 56; c += 4) {
        int tb = (c >> 2) * 16;
        int eb = (c & 3) * 4;
        int t = tb + (lane & 15);
        int e4 = eb + (lane >> 4);
        float4 v = {0.f, 0.f, 0.f, 0.f};
        if (t < SEQ) v = *(const float4*)&vg[base + (long)t * 64 + e4 * 4];
        Vt[(e4 * 4 + 0) * 232 + t] = f2bf(v.x);
        Vt[(e4 * 4 + 1) * 232 + t] = f2bf(v.y);
        Vt[(e4 * 4 + 2) * 232 + t] = f2bf(v.z);
        Vt[(e4 * 4 + 3) * 232 + t] = f2bf(v.w);
    }

    // ---- Q A-fragments from global (clamped rows) ----
    int q0w = blockIdx.x * 64 + wave * 16;
    int qrow = q0w + col; if (qrow > SEQ - 1) qrow = SEQ - 1;
    short8 aq[2];
    #pragma unroll
    for (int dt = 0; dt < 2; dt++) {
        const float* qp = &qg[base + (long)qrow * 64 + dt * 32 + quad * 8];
        float4 u0 = *(const float4*)qp;
        float4 u1 = *(const float4*)(qp + 4);
        aq[dt][0] = (short)f2bf(u0.x); aq[dt][1] = (short)f2bf(u0.y);
        aq[dt][2] = (short)f2bf(u0.z); aq[dt][3] = (short)f2bf(u0.w);
        aq[dt][4] = (short)f2bf(u1.x); aq[dt][5] = (short)f2bf(u1.y);
        aq[dt][6] = (short)f2bf(u1.z); aq[dt][7] = (short)f2bf(u1.w);
    }

    __syncthreads();
    if (q0w >= SEQ) return;       // idle strips: after the only barrier

    // ---- scores: 13 key-tiles x (K=64 as 2 MFMAs) ----
    f32x4 zero4 = {0.f, 0.f, 0.f, 0.f};
    f32x4 sc[13];
    #pragma unroll
    for (int tt = 0; tt < 13; tt++) sc[tt] = zero4;
    #pragma unroll
    for (int tt = 0; tt < 13; tt++) {
        #pragma unroll
        for (int dt = 0; dt < 2; dt++) {
            short8 bk = *(const short8*)&Ks[(tt * 16 + col) * 72 + dt * 32 + quad * 8];
            sc[tt] = __builtin_amdgcn_mfma_f32_16x16x32_bf16(aq[dt], bk, sc[tt], 0, 0, 0);
        }
    }

    // ---- softmax over t (rows = quad*4+r), masked cols >= 197 in tile 12 ----
    float rinv[4];
    #pragma unroll
    for (int r = 0; r < 4; r++) {
        float m = -1e30f;
        #pragma unroll
        for (int tt = 0; tt < 12; tt++) m = fmaxf(m, sc[tt][r]);
        if (col < 5) m = fmaxf(m, sc[12][r]);
        #pragma unroll
        for (int off = 1; off < 16; off <<= 1) m = fmaxf(m, __shfl_xor(m, off));
        float s = 0.f;
        #pragma unroll
        for (int tt = 0; tt < 12; tt++) {
            float e = __expf((sc[tt][r] - m) * SCALE);
            sc[tt][r] = e; s += e;
        }
        float e12 = (col < 5) ? __expf((sc[12][r] - m) * SCALE) : 0.f;
        sc[12][r] = e12; s += e12;
        #pragma unroll
        for (int off = 1; off < 16; off <<= 1) s += __shfl_xor(s, off);
        rinv[r] = 1.f / s;
    }

    // ---- P @ V: 7 chunks of 32 keys; P->A via per-wave LDS scratch ----
    ushort* myP = &Ps[wave][0];
    f32x4 oacc[4];
    #pragma unroll
    for (int nt = 0; nt < 4; nt++) oacc[nt] = zero4;
    #pragma unroll
    for (int kt = 0; kt < 7; kt++) {
        #pragma unroll
        for (int half = 0; half < 2; half++) {
            int tt = kt * 2 + half;
            #pragma unroll
            for (int r = 0; r < 4; r++) {
                float v = (tt < 13) ? sc[tt][r] : 0.f;
                myP[(quad * 4 + r) * 40 + half * 16 + col] = f2bf(v);
            }
        }
        short8 pa = *(const short8*)&myP[col * 40 + quad * 8];
        #pragma unroll
        for (int nt = 0; nt < 4; nt++) {
            short8 vb = *(const short8*)&Vt[(nt * 16 + col) * 232 + kt * 32 + quad * 8];
            oacc[nt] = __builtin_amdgcn_mfma_f32_16x16x32_bf16(pa, vb, oacc[nt], 0, 0, 0);
        }
    }

    // ---- residual add (rows = quad*4+r match rinv layout) ----
    #pragma unroll
    for (int nt = 0; nt < 4; nt++) {
        #pragma unroll
        for (int r = 0; r < 4; r++) {
            int row = q0w + quad * 4 + r;
            if (row < SEQ) {
                long o = ((long)n * SEQ + row) * HDIM + h * 64 + nt * 16 + col;
                tok[o] += oacc[nt][r] * rinv[r];
            }
        }
    }
}

// ---------------------------------------------------------------------------
// K6: classifier head + softmax
// ---------------------------------------------------------------------------
__global__ __launch_bounds__(256) void k_head(
    const float* __restrict__ tok, const float* __restrict__ W,
    const float* __restrict__ b, float* __restrict__ out)
{
    __shared__ float cls[HDIM];
    __shared__ float logit[NOUT];
    __shared__ float red[256];
    int n = blockIdx.x, tid = threadIdx.x;
    for (int i = tid; i < HDIM; i += 256) cls[i] = tok[(long)n * SEQ * HDIM + i];
    __syncthreads();
    for (int o = tid; o < NOUT; o += 256) {
        float acc = 0.f;
        const float* wr = &W[(long)o * HDIM];
        for (int d = 0; d < HDIM; d++) acc += cls[d] * wr[d];
        logit[o] = acc + b[o];
    }
    __syncthreads();
    float m = -1e30f;
    for (int o = tid; o < NOUT; o += 256) m = fmaxf(m, logit[o]);
    red[tid] = m; __syncthreads();
    for (int off = 128; off > 0; off >>= 1) {
        if (tid < off) red[tid] = fmaxf(red[tid], red[tid + off]);
        __syncthreads();
    }
    float mx = red[0];
    __syncthreads();
    float s = 0.f;
    for (int o = tid; o < NOUT; o += 256) {
        float e = __expf(logit[o] - mx);
        logit[o] = e; s += e;
    }
    red[tid] = s; __syncthreads();
    for (int off = 128; off > 0; off >>= 1) {
        if (tid < off) red[tid] += red[tid + off];
        __syncthreads();
    }
    float inv = 1.f / red[0];
    for (int o = tid; o < NOUT; o += 256) out[(long)n * NOUT + o] = logit[o] * inv;
}

// ---------------------------------------------------------------------------
extern "C" void kernel_launch(void* const* d_in, const int* in_sizes, int n_in,
                              void* d_out, int out_size, void* d_ws, size_t ws_size,
                              hipStream_t stream)
{
    const float* images  = (const float*)d_in[0];
    const float* conv_w  = (const float*)d_in[1];
    const float* conv_b  = (const float*)d_in[2];
    const float* bn_g    = (const float*)d_in[3];
    const float* bn_b    = (const float*)d_in[4];
    const float* bn_m    = (const float*)d_in[5];
    const float* bn_v    = (const float*)d_in[6];
    const float* map_w   = (const float*)d_in[7];
    const float* map_b   = (const float*)d_in[8];
    const float* cls_tok = (const float*)d_in[9];
    const float* ln_g    = (const float*)d_in[10];
    const float* ln_b    = (const float*)d_in[11];
    const float* wq      = (const float*)d_in[12];
    const float* bq      = (const float*)d_in[13];
    const float* wk      = (const float*)d_in[14];
    const float* bk      = (const float*)d_in[15];
    const float* wv      = (const float*)d_in[16];
    const float* bv      = (const float*)d_in[17];
    const float* mlp_w   = (const float*)d_in[18];
    const float* mlp_b   = (const float*)d_in[19];
    float* out = (float*)d_out;

    float* ws = (float*)d_ws;
    const long SZ_X   = (long)NPATCH * IND;
    const long SZ_TOK = (long)NTOK * HDIM;
    float* X     = ws;
    float* tok   = X + SZ_X;
    float* kb    = tok + SZ_TOK;
    float* vb    = kb + SZ_TOK;
    float* stats = vb + SZ_TOK;
    float* qb    = X;                 // X dead after k_embed

    k_conv_patch<<<NPATCH, 256, 0, stream>>>(images, conv_w, conv_b, bn_g, bn_b,
                                             bn_m, bn_v, X);
    k_cls<<<BB, 256, 0, stream>>>(cls_tok, tok);
    dim3 ge(98, 12);
    k_embed<<<ge, 256, 0, stream>>>(X, map_w, map_b, tok);

    for (int l = 0; l < LLAYERS; l++) {
        k_lnstats<<<NTOK, 256, 0, stream>>>(tok, stats);
        dim3 gq(99, 12);
        k_qkv<<<gq, 256, 0, stream>>>(tok, stats,
            ln_g + (long)l * HDIM, ln_b + (long)l * HDIM,
            wq + (long)l * NHEAD * DHEAD * DHEAD, bq + (long)l * NHEAD * DHEAD,
            wk + (long)l * NHEAD * DHEAD * DHEAD, bk + (long)l * NHEAD * DHEAD,
            wv + (long)l * NHEAD * DHEAD * DHEAD, bv + (long)l * NHEAD * DHEAD,
            qb, kb, vb);
        dim3 ga(4, 12, 32);
        k_attn<<<ga, 256, 0, stream>>>(qb, kb, vb, tok);
    }
    k_head<<<BB, 256, 0, stream>>>(tok, mlp_w, mlp_b, out);
}

// Round 3
// 1225.326 us; speedup vs baseline: 3.1442x; 1.5102x over previous
//
#include <hip/hip_runtime.h>

#define BB 32
#define LLAYERS 12
#define HDIM 768
#define NHEAD 12
#define DHEAD 64
#define SEQ 197
#define IND 800
#define NOUT 1000
#define EPSF 1e-5f
#define NTOK (BB * SEQ)     // 6304
#define NPATCH (BB * 196)   // 6272
#define SCALE 0.125f        // 1/sqrt(64)

typedef __attribute__((ext_vector_type(4))) float f32x4;
typedef __attribute__((ext_vector_type(8))) short short8;

static __device__ __forceinline__ ushort f2bf(float f) {
    union { float f; unsigned u; } v; v.f = f;
    unsigned r = v.u + 0x7FFFu + ((v.u >> 16) & 1u);   // round-to-nearest-even
    return (ushort)(r >> 16);
}

static __device__ __forceinline__ void gload_lds16(const void* g, void* l) {
    __builtin_amdgcn_global_load_lds(
        (const __attribute__((address_space(1))) void*)g,
        (__attribute__((address_space(3))) void*)l, 16, 0, 0);
}

// ---------------------------------------------------------------------------
// K0a: convert map_w fp32 -> bf16 (once per launch)
// ---------------------------------------------------------------------------
__global__ __launch_bounds__(256) void k_cvt(
    const float* __restrict__ s, ushort* __restrict__ d, int n4)
{
    int i = blockIdx.x * 256 + threadIdx.x;
    if (i < n4) {
        float4 v = *(const float4*)&s[i * 4];
        ushort4 u = {f2bf(v.x), f2bf(v.y), f2bf(v.z), f2bf(v.w)};
        *(ushort4*)&d[i * 4] = u;
    }
}

// ---------------------------------------------------------------------------
// K0b: sinusoidal pos-emb table [SEQ][HDIM]
// ---------------------------------------------------------------------------
__global__ __launch_bounds__(256) void k_pos(float* __restrict__ pos)
{
    int s = blockIdx.x;
    for (int e = threadIdx.x; e < HDIM; e += 256) {
        float freq = expf((float)(e & ~1) * (-9.210340371976184f / 768.0f));
        float ang = (float)s * freq;
        pos[s * HDIM + e] = (e & 1) ? cosf(ang) : sinf(ang);
    }
}

// ---------------------------------------------------------------------------
// K1: conv(5x5, stride4, pad1) + bias + BN + ReLU + patchify -> Xbf[n,p,800]
// ---------------------------------------------------------------------------
__global__ __launch_bounds__(256) void k_conv_patch(
    const float* __restrict__ img, const float* __restrict__ cw,
    const float* __restrict__ cb, const float* __restrict__ bg,
    const float* __restrict__ bbias, const float* __restrict__ bm,
    const float* __restrict__ bvv, ushort* __restrict__ X)
{
    __shared__ float tile[3][21][21];
    __shared__ float w[2400];
    __shared__ float scale[32], shift[32];
    int blk = blockIdx.x;
    int n = blk / 196, p = blk % 196;
    int py = p / 14, px = p % 14;
    int tid = threadIdx.x;

    for (int i = tid; i < 2400; i += 256) w[i] = cw[i];
    if (tid < 32) {
        float sc = bg[tid] * rsqrtf(bvv[tid] + EPSF);
        scale[tid] = sc;
        shift[tid] = (cb[tid] - bm[tid]) * sc + bbias[tid];
    }
    int h0 = py * 20 - 1, w0 = px * 20 - 1;
    for (int i = tid; i < 3 * 21 * 21; i += 256) {
        int c = i / 441, r = (i / 21) % 21, cc = i % 21;
        int gh = h0 + r, gw = w0 + cc;
        float v = 0.f;
        if (gh >= 0 && gh < 280 && gw >= 0 && gw < 280)
            v = img[((long)(n * 3 + c) * 280 + gh) * 280 + gw];
        tile[c][r][cc] = v;
    }
    __syncthreads();
    for (int o = tid; o < 800; o += 256) {
        int c = o / 25, r = o % 25, ph = r / 5, pw = r % 5;
        float acc = 0.f;
        const float* wp = &w[c * 75];
        #pragma unroll
        for (int ci = 0; ci < 3; ci++)
            #pragma unroll
            for (int kh = 0; kh < 5; kh++)
                #pragma unroll
                for (int kw = 0; kw < 5; kw++)
                    acc += tile[ci][ph * 4 + kh][pw * 4 + kw] * wp[ci * 25 + kh * 5 + kw];
        float val = acc * scale[c] + shift[c];
        X[(long)blk * 800 + o] = f2bf(fmaxf(val, 0.f));
    }
}

__global__ void k_cls(const float* __restrict__ cls_tok,
                      const float* __restrict__ pos, float* __restrict__ tok)
{
    int n = blockIdx.x, tid = threadIdx.x;
    for (int e = tid; e < HDIM; e += 256)
        tok[(long)n * SEQ * HDIM + e] = cls_tok[e] + pos[e];
}

// ---------------------------------------------------------------------------
// K2: patch embed GEMM, bf16 MFMA. M=6272, N=768, K=800.
// BM=128, BN=64, BK=32; global_load_lds width=16 staging; grid (49,12).
// ---------------------------------------------------------------------------
__global__ __launch_bounds__(256, 2) void k_embed(
    const ushort* __restrict__ Xg, const ushort* __restrict__ Wg,
    const float* __restrict__ bias, const float* __restrict__ pos,
    float* __restrict__ tok)
{
    __shared__ __align__(16) ushort As[128 * 32];   // 8 KB
    __shared__ __align__(16) ushort Bs[64 * 32];    // 4 KB
    int m0 = blockIdx.x * 128, e0 = blockIdx.y * 64;
    int tid = threadIdx.x, lane = tid & 63, wave = tid >> 6;
    int col = lane & 15, quad = lane >> 4;
    int wm = (wave & 1) * 64, wn = (wave >> 1) * 32;
    int lr = lane >> 2, lc = (lane & 3) * 8;        // chunk-local row / col
    f32x4 zero4 = {0.f, 0.f, 0.f, 0.f};
    f32x4 acc[4][2];
    #pragma unroll
    for (int mt = 0; mt < 4; mt++)
        #pragma unroll
        for (int nt = 0; nt < 2; nt++) acc[mt][nt] = zero4;

    for (int k0 = 0; k0 < 800; k0 += 32) {
        __syncthreads();    // prior-iter frag reads done before overwrite
        #pragma unroll
        for (int i = 0; i < 2; i++) {               // A: 8 chunks of 16 rows
            int c = wave * 2 + i;
            gload_lds16(&Xg[(long)(m0 + c * 16 + lr) * 800 + k0 + lc], &As[c * 512]);
        }
        {                                           // B: 4 chunks
            int c = wave;
            gload_lds16(&Wg[(long)(e0 + c * 16 + lr) * 800 + k0 + lc], &Bs[c * 512]);
        }
        __syncthreads();    // drains vmcnt -> LDS writes visible
        short8 a[4], b[2];
        #pragma unroll
        for (int mt = 0; mt < 4; mt++)
            a[mt] = *(const short8*)&As[(wm + mt * 16 + col) * 32 + quad * 8];
        #pragma unroll
        for (int nt = 0; nt < 2; nt++)
            b[nt] = *(const short8*)&Bs[(wn + nt * 16 + col) * 32 + quad * 8];
        #pragma unroll
        for (int mt = 0; mt < 4; mt++)
            #pragma unroll
            for (int nt = 0; nt < 2; nt++)
                acc[mt][nt] = __builtin_amdgcn_mfma_f32_16x16x32_bf16(a[mt], b[nt], acc[mt][nt], 0, 0, 0);
    }
    #pragma unroll
    for (int mt = 0; mt < 4; mt++) {
        #pragma unroll
        for (int r = 0; r < 4; r++) {
            int m = m0 + wm + mt * 16 + quad * 4 + r;
            int n = m / 196, s = m - n * 196 + 1;
            long rowb = ((long)n * SEQ + s) * HDIM;
            #pragma unroll
            for (int nt = 0; nt < 2; nt++) {
                int e = e0 + wn + nt * 16 + col;
                tok[rowb + e] = acc[mt][nt][r] + bias[e] + pos[s * HDIM + e];
            }
        }
    }
}

// ---------------------------------------------------------------------------
// K3: LayerNorm stats per token row
// ---------------------------------------------------------------------------
__global__ __launch_bounds__(256) void k_lnstats(
    const float* __restrict__ tok, float* __restrict__ stats)
{
    int row = blockIdx.x, tid = threadIdx.x;
    const float* p = tok + (long)row * HDIM;
    float s = 0.f, sq = 0.f;
    for (int i = tid; i < HDIM; i += 256) { float v = p[i]; s += v; sq += v * v; }
    __shared__ float rs[256], rq[256];
    rs[tid] = s; rq[tid] = sq; __syncthreads();
    for (int off = 128; off > 0; off >>= 1) {
        if (tid < off) { rs[tid] += rs[tid + off]; rq[tid] += rq[tid + off]; }
        __syncthreads();
    }
    if (tid == 0) {
        float mu = rs[0] / 768.f;
        float var = rq[0] / 768.f - mu * mu;
        stats[row * 2] = mu;
        stats[row * 2 + 1] = rsqrtf(var + EPSF);
    }
}

// ---------------------------------------------------------------------------
// K4: QKV per head, bf16 MFMA. Block = 128 tokens x 1 head, 4 waves.
// LN fused into bf16 staging; A-frags reused across Q/K/V; bf16 outputs.
// grid (50, 12).
// ---------------------------------------------------------------------------
__global__ __launch_bounds__(256, 2) void k_qkv(
    const float* __restrict__ tok, const float* __restrict__ stats,
    const float* __restrict__ lng, const float* __restrict__ lnb,
    const float* __restrict__ wqp, const float* __restrict__ bqp,
    const float* __restrict__ wkp, const float* __restrict__ bkp,
    const float* __restrict__ wvp, const float* __restrict__ bvp,
    ushort* __restrict__ qo, ushort* __restrict__ ko, ushort* __restrict__ vo)
{
    __shared__ __align__(16) ushort xh[128 * 72];    // 18.4 KB
    __shared__ __align__(16) ushort Wl[3][64 * 72];  // 27.6 KB
    __shared__ float bias[3][64];
    int h = blockIdx.y, t0 = blockIdx.x * 128;
    int tid = threadIdx.x, lane = tid & 63, wave = tid >> 6;
    int col = lane & 15, quad = lane >> 4;

    // stage W (3 x 64x64 fp32 -> bf16, stride 72)
    for (int i = tid; i < 3072; i += 256) {
        int m = i >> 10, rc = i & 1023;
        int r = rc >> 4, c4 = rc & 15;
        const float* wsrc = ((m == 0) ? wqp : (m == 1) ? wkp : wvp) + (long)h * 4096;
        float4 v = *(const float4*)&wsrc[r * 64 + c4 * 4];
        ushort4 u = {f2bf(v.x), f2bf(v.y), f2bf(v.z), f2bf(v.w)};
        *(ushort4*)&Wl[m][r * 72 + c4 * 4] = u;
    }
    if (tid < 192) {
        int m = tid >> 6, e = tid & 63;
        bias[m][e] = ((m == 0) ? bqp : (m == 1) ? bkp : bvp)[h * 64 + e];
    }
    // stage xh = LN(tok) head-slice, bf16
    for (int i = tid; i < 2048; i += 256) {
        int r = i >> 4, c4 = i & 15;
        int row = t0 + r;
        float4 v = {0.f, 0.f, 0.f, 0.f};
        float mu = 0.f, rstd = 0.f;
        if (row < NTOK) {
            v = *(const float4*)&tok[(long)row * HDIM + h * 64 + c4 * 4];
            mu = stats[row * 2]; rstd = stats[row * 2 + 1];
        }
        int d = c4 * 4;
        const float* g = &lng[h * 64 + d];
        const float* bb = &lnb[h * 64 + d];
        ushort4 u = {f2bf((v.x - mu) * rstd * g[0] + bb[0]),
                     f2bf((v.y - mu) * rstd * g[1] + bb[1]),
                     f2bf((v.z - mu) * rstd * g[2] + bb[2]),
                     f2bf((v.w - mu) * rstd * g[3] + bb[3])};
        *(ushort4*)&xh[r * 72 + d] = u;
    }
    __syncthreads();

    short8 a[2][2];
    #pragma unroll
    for (int mt = 0; mt < 2; mt++)
        #pragma unroll
        for (int kt = 0; kt < 2; kt++)
            a[mt][kt] = *(const short8*)&xh[(wave * 32 + mt * 16 + col) * 72 + kt * 32 + quad * 8];

    f32x4 zero4 = {0.f, 0.f, 0.f, 0.f};
    #pragma unroll
    for (int m = 0; m < 3; m++) {
        f32x4 acc[2][4];
        #pragma unroll
        for (int mt = 0; mt < 2; mt++)
            #pragma unroll
            for (int nt = 0; nt < 4; nt++) acc[mt][nt] = zero4;
        #pragma unroll
        for (int kt = 0; kt < 2; kt++) {
            short8 b[4];
            #pragma unroll
            for (int nt = 0; nt < 4; nt++)
                b[nt] = *(const short8*)&Wl[m][(nt * 16 + col) * 72 + kt * 32 + quad * 8];
            #pragma unroll
            for (int mt = 0; mt < 2; mt++)
                #pragma unroll
                for (int nt = 0; nt < 4; nt++)
                    acc[mt][nt] = __builtin_amdgcn_mfma_f32_16x16x32_bf16(a[mt][kt], b[nt], acc[mt][nt], 0, 0, 0);
        }
        ushort* op = (m == 0) ? qo : (m == 1) ? ko : vo;
        #pragma unroll
        for (int mt = 0; mt < 2; mt++) {
            #pragma unroll
            for (int r = 0; r < 4; r++) {
                int row = t0 + wave * 32 + mt * 16 + quad * 4 + r;
                if (row < NTOK) {
                    int n = row / SEQ, s = row - n * SEQ;
                    long ob = (((long)n * NHEAD + h) * SEQ + s) * DHEAD;
                    #pragma unroll
                    for (int nt = 0; nt < 4; nt++) {
                        int e = nt * 16 + col;
                        op[ob + e] = f2bf(acc[mt][nt][r] + bias[m][e]);
                    }
                }
            }
        }
    }
}

// ---------------------------------------------------------------------------
// K5: bf16-MFMA fused attention + residual (q/k/v now bf16 in global).
// grid (4 qblocks, 12 heads, 32 batch), 256 thr = 4 waves.
// ---------------------------------------------------------------------------
__global__ __launch_bounds__(256, 2) void k_attn(
    const ushort* __restrict__ qg, const ushort* __restrict__ kg,
    const ushort* __restrict__ vg, float* __restrict__ tok)
{
    __shared__ __align__(16) ushort Ks[208 * 72];
    __shared__ __align__(16) ushort Vt[64 * 232];
    __shared__ __align__(16) ushort Ps[4][16 * 40];

    int n = blockIdx.z, h = blockIdx.y;
    int tid = threadIdx.x;
    int lane = tid & 63;
    int wave = tid >> 6;
    int col = lane & 15;
    int quad = lane >> 4;
    long base = ((long)n * NHEAD + h) * SEQ * DHEAD;

    short8 zero8 = {0, 0, 0, 0, 0, 0, 0, 0};
    // ---- stage K (16B loads) ----
    for (int id = tid; id < 208 * 8; id += 256) {
        int t = id >> 3, e8 = id & 7;
        short8 w = zero8;
        if (t < SEQ) w = *(const short8*)&kg[base + (long)t * 64 + e8 * 8];
        *(short8*)&Ks[t * 72 + e8 * 8] = w;
    }
    // ---- stage V transposed ----
    for (int c = wave; c < 56; c += 4) {
        int tb = (c >> 2) * 16;
        int eb = (c & 3) * 4;
        int t = tb + (lane & 15);
        int e4 = eb + (lane >> 4);
        ushort4 v = {0, 0, 0, 0};
        if (t < SEQ) v = *(const ushort4*)&vg[base + (long)t * 64 + e4 * 4];
        Vt[(e4 * 4 + 0) * 232 + t] = v.x;
        Vt[(e4 * 4 + 1) * 232 + t] = v.y;
        Vt[(e4 * 4 + 2) * 232 + t] = v.z;
        Vt[(e4 * 4 + 3) * 232 + t] = v.w;
    }

    // ---- Q A-fragments direct from global bf16 ----
    int q0w = blockIdx.x * 64 + wave * 16;
    int qrow = q0w + col; if (qrow > SEQ - 1) qrow = SEQ - 1;
    short8 aq[2];
    #pragma unroll
    for (int dt = 0; dt < 2; dt++)
        aq[dt] = *(const short8*)&qg[base + (long)qrow * 64 + dt * 32 + quad * 8];

    __syncthreads();
    if (q0w >= SEQ) return;

    // ---- scores ----
    f32x4 zero4 = {0.f, 0.f, 0.f, 0.f};
    f32x4 sc[13];
    #pragma unroll
    for (int tt = 0; tt < 13; tt++) sc[tt] = zero4;
    #pragma unroll
    for (int tt = 0; tt < 13; tt++) {
        #pragma unroll
        for (int dt = 0; dt < 2; dt++) {
            short8 bk = *(const short8*)&Ks[(tt * 16 + col) * 72 + dt * 32 + quad * 8];
            sc[tt] = __builtin_amdgcn_mfma_f32_16x16x32_bf16(aq[dt], bk, sc[tt], 0, 0, 0);
        }
    }

    // ---- softmax ----
    float rinv[4];
    #pragma unroll
    for (int r = 0; r < 4; r++) {
        float m = -1e30f;
        #pragma unroll
        for (int tt = 0; tt < 12; tt++) m = fmaxf(m, sc[tt][r]);
        if (col < 5) m = fmaxf(m, sc[12][r]);
        #pragma unroll
        for (int off = 1; off < 16; off <<= 1) m = fmaxf(m, __shfl_xor(m, off));
        float s = 0.f;
        #pragma unroll
        for (int tt = 0; tt < 12; tt++) {
            float e = __expf((sc[tt][r] - m) * SCALE);
            sc[tt][r] = e; s += e;
        }
        float e12 = (col < 5) ? __expf((sc[12][r] - m) * SCALE) : 0.f;
        sc[12][r] = e12; s += e12;
        #pragma unroll
        for (int off = 1; off < 16; off <<= 1) s += __shfl_xor(s, off);
        rinv[r] = 1.f / s;
    }

    // ---- P @ V ----
    ushort* myP = &Ps[wave][0];
    f32x4 oacc[4];
    #pragma unroll
    for (int nt = 0; nt < 4; nt++) oacc[nt] = zero4;
    #pragma unroll
    for (int kt = 0; kt < 7; kt++) {
        #pragma unroll
        for (int half = 0; half < 2; half++) {
            int tt = kt * 2 + half;
            #pragma unroll
            for (int r = 0; r < 4; r++) {
                float v = (tt < 13) ? sc[tt][r] : 0.f;
                myP[(quad * 4 + r) * 40 + half * 16 + col] = f2bf(v);
            }
        }
        short8 pa = *(const short8*)&myP[col * 40 + quad * 8];
        #pragma unroll
        for (int nt = 0; nt < 4; nt++) {
            short8 vb = *(const short8*)&Vt[(nt * 16 + col) * 232 + kt * 32 + quad * 8];
            oacc[nt] = __builtin_amdgcn_mfma_f32_16x16x32_bf16(pa, vb, oacc[nt], 0, 0, 0);
        }
    }

    // ---- residual add ----
    #pragma unroll
    for (int nt = 0; nt < 4; nt++) {
        #pragma unroll
        for (int r = 0; r < 4; r++) {
            int row = q0w + quad * 4 + r;
            if (row < SEQ) {
                long o = ((long)n * SEQ + row) * HDIM + h * 64 + nt * 16 + col;
                tok[o] += oacc[nt][r] * rinv[r];
            }
        }
    }
}

// ---------------------------------------------------------------------------
// K6: classifier head + softmax
// ---------------------------------------------------------------------------
__global__ __launch_bounds__(256) void k_head(
    const float* __restrict__ tok, const float* __restrict__ W,
    const float* __restrict__ b, float* __restrict__ out)
{
    __shared__ float cls[HDIM];
    __shared__ float logit[NOUT];
    __shared__ float red[256];
    int n = blockIdx.x, tid = threadIdx.x;
    for (int i = tid; i < HDIM; i += 256) cls[i] = tok[(long)n * SEQ * HDIM + i];
    __syncthreads();
    for (int o = tid; o < NOUT; o += 256) {
        float acc = 0.f;
        const float* wr = &W[(long)o * HDIM];
        for (int d = 0; d < HDIM; d++) acc += cls[d] * wr[d];
        logit[o] = acc + b[o];
    }
    __syncthreads();
    float m = -1e30f;
    for (int o = tid; o < NOUT; o += 256) m = fmaxf(m, logit[o]);
    red[tid] = m; __syncthreads();
    for (int off = 128; off > 0; off >>= 1) {
        if (tid < off) red[tid] = fmaxf(red[tid], red[tid + off]);
        __syncthreads();
    }
    float mx = red[0];
    __syncthreads();
    float s = 0.f;
    for (int o = tid; o < NOUT; o += 256) {
        float e = __expf(logit[o] - mx);
        logit[o] = e; s += e;
    }
    red[tid] = s; __syncthreads();
    for (int off = 128; off > 0; off >>= 1) {
        if (tid < off) red[tid] += red[tid + off];
        __syncthreads();
    }
    float inv = 1.f / red[0];
    for (int o = tid; o < NOUT; o += 256) out[(long)n * NOUT + o] = logit[o] * inv;
}

// ---------------------------------------------------------------------------
extern "C" void kernel_launch(void* const* d_in, const int* in_sizes, int n_in,
                              void* d_out, int out_size, void* d_ws, size_t ws_size,
                              hipStream_t stream)
{
    const float* images  = (const float*)d_in[0];
    const float* conv_w  = (const float*)d_in[1];
    const float* conv_b  = (const float*)d_in[2];
    const float* bn_g    = (const float*)d_in[3];
    const float* bn_b    = (const float*)d_in[4];
    const float* bn_m    = (const float*)d_in[5];
    const float* bn_v    = (const float*)d_in[6];
    const float* map_w   = (const float*)d_in[7];
    const float* map_b   = (const float*)d_in[8];
    const float* cls_tok = (const float*)d_in[9];
    const float* ln_g    = (const float*)d_in[10];
    const float* ln_b    = (const float*)d_in[11];
    const float* wq      = (const float*)d_in[12];
    const float* bq      = (const float*)d_in[13];
    const float* wk      = (const float*)d_in[14];
    const float* bk      = (const float*)d_in[15];
    const float* wv      = (const float*)d_in[16];
    const float* bv      = (const float*)d_in[17];
    const float* mlp_w   = (const float*)d_in[18];
    const float* mlp_b   = (const float*)d_in[19];
    float* out = (float*)d_out;

    const long SZ_X   = (long)NPATCH * IND;       // 5,017,600 ushorts
    const long SZ_W   = (long)HDIM * IND;         // 614,400 ushorts
    const long SZ_POS = (long)SEQ * HDIM;         // 151,296 floats
    const long SZ_TOK = (long)NTOK * HDIM;        // 4,841,472
    const long SZ_QKV = (long)NTOK * HDIM;        // ushorts each

    ushort* Xbf = (ushort*)d_ws;
    ushort* Wbf = Xbf + SZ_X;
    float*  pos = (float*)(Wbf + SZ_W);
    float*  tok = pos + SZ_POS;
    ushort* qb  = (ushort*)(tok + SZ_TOK);
    ushort* kb  = qb + SZ_QKV;
    ushort* vb  = kb + SZ_QKV;
    float* stats = (float*)(vb + SZ_QKV);

    k_cvt<<<600, 256, 0, stream>>>(map_w, Wbf, (int)(SZ_W / 4));
    k_pos<<<SEQ, 256, 0, stream>>>(pos);
    k_conv_patch<<<NPATCH, 256, 0, stream>>>(images, conv_w, conv_b, bn_g, bn_b,
                                             bn_m, bn_v, Xbf);
    k_cls<<<BB, 256, 0, stream>>>(cls_tok, pos, tok);
    dim3 ge(49, 12);
    k_embed<<<ge, 256, 0, stream>>>(Xbf, Wbf, map_b, pos, tok);

    for (int l = 0; l < LLAYERS; l++) {
        k_lnstats<<<NTOK, 256, 0, stream>>>(tok, stats);
        dim3 gq(50, 12);
        k_qkv<<<gq, 256, 0, stream>>>(tok, stats,
            ln_g + (long)l * HDIM, ln_b + (long)l * HDIM,
            wq + (long)l * NHEAD * DHEAD * DHEAD, bq + (long)l * NHEAD * DHEAD,
            wk + (long)l * NHEAD * DHEAD * DHEAD, bk + (long)l * NHEAD * DHEAD,
            wv + (long)l * NHEAD * DHEAD * DHEAD, bv + (long)l * NHEAD * DHEAD,
            qb, kb, vb);
        dim3 ga(4, 12, 32);
        k_attn<<<ga, 256, 0, stream>>>(qb, kb, vb, tok);
    }
    k_head<<<BB, 256, 0, stream>>>(tok, mlp_w, mlp_b, out);
}

// Round 4
// 1057.989 us; speedup vs baseline: 3.6415x; 1.1582x over previous
//
#include <hip/hip_runtime.h>

#define BB 32
#define LLAYERS 12
#define HDIM 768
#define NHEAD 12
#define DHEAD 64
#define SEQ 197
#define IND 800
#define NOUT 1000
#define EPSF 1e-5f
#define NTOK (BB * SEQ)     // 6304
#define NPATCH (BB * 196)   // 6272
#define SCALE 0.125f        // 1/sqrt(64)

typedef __attribute__((ext_vector_type(4))) float f32x4;
typedef __attribute__((ext_vector_type(8))) short short8;

static __device__ __forceinline__ ushort f2bf(float f) {
    union { float f; unsigned u; } v; v.f = f;
    unsigned r = v.u + 0x7FFFu + ((v.u >> 16) & 1u);   // round-to-nearest-even
    return (ushort)(r >> 16);
}

static __device__ __forceinline__ void gload_lds16(const void* g, void* l) {
    __builtin_amdgcn_global_load_lds(
        (const __attribute__((address_space(1))) void*)g,
        (__attribute__((address_space(3))) void*)l, 16, 0, 0);
}

// ---------------------------------------------------------------------------
// K0a: convert map_w fp32 -> bf16
// ---------------------------------------------------------------------------
__global__ __launch_bounds__(256) void k_cvt(
    const float* __restrict__ s, ushort* __restrict__ d, int n4)
{
    int i = blockIdx.x * 256 + threadIdx.x;
    if (i < n4) {
        float4 v = *(const float4*)&s[i * 4];
        ushort4 u = {f2bf(v.x), f2bf(v.y), f2bf(v.z), f2bf(v.w)};
        *(ushort4*)&d[i * 4] = u;
    }
}

// ---------------------------------------------------------------------------
// K0b: convert wq/wk/wv fp32 -> bf16 in MFMA B-frag order.
// dst[((m*12+l)*12+h)*4096 + (kt*4+nt)*512 + lane*8 + j]
//   = W_m[l][h][e=nt*16+(lane&15)][d=kt*32+(lane>>4)*8+j]
// ---------------------------------------------------------------------------
__global__ __launch_bounds__(256) void k_cvtw(
    const float* __restrict__ wq, const float* __restrict__ wk,
    const float* __restrict__ wv, ushort* __restrict__ dst)
{
    int t = blockIdx.x * 256 + threadIdx.x;          // < 3*12*12*8*64
    if (t >= 3 * 144 * 512) return;
    int lane = t & 63;
    int rest = t >> 6;
    int ktnt = rest & 7;
    int mlh = rest >> 3;                              // (m*12+l)*12+h
    int h = mlh % 12, ml = mlh / 12;
    int l = ml % 12, m = ml / 12;
    int nt = ktnt & 3, kt = ktnt >> 2;
    int e = nt * 16 + (lane & 15);
    int d = kt * 32 + (lane >> 4) * 8;
    const float* src = ((m == 0) ? wq : (m == 1) ? wk : wv)
                       + (((long)l * 12 + h) * 64 + e) * 64 + d;
    float4 a = *(const float4*)src;
    float4 b = *(const float4*)(src + 4);
    short8 u;
    u[0] = (short)f2bf(a.x); u[1] = (short)f2bf(a.y);
    u[2] = (short)f2bf(a.z); u[3] = (short)f2bf(a.w);
    u[4] = (short)f2bf(b.x); u[5] = (short)f2bf(b.y);
    u[6] = (short)f2bf(b.z); u[7] = (short)f2bf(b.w);
    *(short8*)&dst[(long)mlh * 4096 + ktnt * 512 + lane * 8] = u;
}

// ---------------------------------------------------------------------------
// K0c: sinusoidal pos-emb table [SEQ][HDIM]
// ---------------------------------------------------------------------------
__global__ __launch_bounds__(256) void k_pos(float* __restrict__ pos)
{
    int s = blockIdx.x;
    for (int e = threadIdx.x; e < HDIM; e += 256) {
        float freq = expf((float)(e & ~1) * (-9.210340371976184f / 768.0f));
        float ang = (float)s * freq;
        pos[s * HDIM + e] = (e & 1) ? cosf(ang) : sinf(ang);
    }
}

// ---------------------------------------------------------------------------
// K1: conv + BN + ReLU + patchify -> Xbf. 2 patches/block, 320 threads.
// Compute mapping: thread=(pp, c, ph); lanes sharing ph broadcast tile reads
// (5 distinct addrs/instr, stride-21 banks 0/20/8/28/16 -> conflict-free).
// ---------------------------------------------------------------------------
__global__ __launch_bounds__(320) void k_conv_patch(
    const float* __restrict__ img, const float* __restrict__ cw,
    const float* __restrict__ cb, const float* __restrict__ bg,
    const float* __restrict__ bbias, const float* __restrict__ bm,
    const float* __restrict__ bvv, ushort* __restrict__ X)
{
    __shared__ float tile[2][3][21][21];
    __shared__ float w[2400];
    __shared__ float scale[32], shift[32];
    int tid = threadIdx.x;

    for (int i = tid; i < 2400; i += 320) w[i] = cw[i];
    if (tid < 32) {
        float sc = bg[tid] * rsqrtf(bvv[tid] + EPSF);
        scale[tid] = sc;
        shift[tid] = (cb[tid] - bm[tid]) * sc + bbias[tid];
    }
    for (int i = tid; i < 2 * 3 * 441; i += 320) {
        int pp = i / 1323, j = i % 1323;
        int c = j / 441, r = (j / 21) % 21, cc = j % 21;
        int gp = blockIdx.x * 2 + pp;
        int n = gp / 196, p = gp % 196;
        int h0 = (p / 14) * 20 - 1, w0 = (p % 14) * 20 - 1;
        int gh = h0 + r, gw = w0 + cc;
        float v = 0.f;
        if (gh >= 0 && gh < 280 && gw >= 0 && gw < 280)
            v = img[((long)(n * 3 + c) * 280 + gh) * 280 + gw];
        tile[pp][c][r][cc] = v;
    }
    __syncthreads();

    int pp = tid / 160, u = tid % 160;
    int c = u / 5, ph = u % 5;
    float acc[5] = {0.f, 0.f, 0.f, 0.f, 0.f};
    const float* wp = &w[c * 75];
    #pragma unroll
    for (int ci = 0; ci < 3; ci++) {
        #pragma unroll
        for (int kh = 0; kh < 5; kh++) {
            const float* row = &tile[pp][ci][ph * 4 + kh][0];
            float rv[21];
            #pragma unroll
            for (int j = 0; j < 21; j++) rv[j] = row[j];
            #pragma unroll
            for (int kw = 0; kw < 5; kw++) {
                float wv = wp[ci * 25 + kh * 5 + kw];
                #pragma unroll
                for (int pw = 0; pw < 5; pw++)
                    acc[pw] += rv[pw * 4 + kw] * wv;
            }
        }
    }
    int gp = blockIdx.x * 2 + pp;
    long ob = (long)gp * 800 + c * 25 + ph * 5;
    #pragma unroll
    for (int pw = 0; pw < 5; pw++) {
        float val = acc[pw] * scale[c] + shift[c];
        X[ob + pw] = f2bf(fmaxf(val, 0.f));
    }
}

__global__ void k_cls(const float* __restrict__ cls_tok,
                      const float* __restrict__ pos, float* __restrict__ tok)
{
    int n = blockIdx.x, tid = threadIdx.x;
    for (int e = tid; e < HDIM; e += 256)
        tok[(long)n * SEQ * HDIM + e] = cls_tok[e] + pos[e];
}

// ---------------------------------------------------------------------------
// K2: patch embed GEMM, bf16 MFMA (unchanged)
// ---------------------------------------------------------------------------
__global__ __launch_bounds__(256, 2) void k_embed(
    const ushort* __restrict__ Xg, const ushort* __restrict__ Wg,
    const float* __restrict__ bias, const float* __restrict__ pos,
    float* __restrict__ tok)
{
    __shared__ __align__(16) ushort As[128 * 32];
    __shared__ __align__(16) ushort Bs[64 * 32];
    int m0 = blockIdx.x * 128, e0 = blockIdx.y * 64;
    int tid = threadIdx.x, lane = tid & 63, wave = tid >> 6;
    int col = lane & 15, quad = lane >> 4;
    int wm = (wave & 1) * 64, wn = (wave >> 1) * 32;
    int lr = lane >> 2, lc = (lane & 3) * 8;
    f32x4 zero4 = {0.f, 0.f, 0.f, 0.f};
    f32x4 acc[4][2];
    #pragma unroll
    for (int mt = 0; mt < 4; mt++)
        #pragma unroll
        for (int nt = 0; nt < 2; nt++) acc[mt][nt] = zero4;

    for (int k0 = 0; k0 < 800; k0 += 32) {
        __syncthreads();
        #pragma unroll
        for (int i = 0; i < 2; i++) {
            int c = wave * 2 + i;
            gload_lds16(&Xg[(long)(m0 + c * 16 + lr) * 800 + k0 + lc], &As[c * 512]);
        }
        {
            int c = wave;
            gload_lds16(&Wg[(long)(e0 + c * 16 + lr) * 800 + k0 + lc], &Bs[c * 512]);
        }
        __syncthreads();
        short8 a[4], b[2];
        #pragma unroll
        for (int mt = 0; mt < 4; mt++)
            a[mt] = *(const short8*)&As[(wm + mt * 16 + col) * 32 + quad * 8];
        #pragma unroll
        for (int nt = 0; nt < 2; nt++)
            b[nt] = *(const short8*)&Bs[(wn + nt * 16 + col) * 32 + quad * 8];
        #pragma unroll
        for (int mt = 0; mt < 4; mt++)
            #pragma unroll
            for (int nt = 0; nt < 2; nt++)
                acc[mt][nt] = __builtin_amdgcn_mfma_f32_16x16x32_bf16(a[mt], b[nt], acc[mt][nt], 0, 0, 0);
    }
    #pragma unroll
    for (int mt = 0; mt < 4; mt++) {
        #pragma unroll
        for (int r = 0; r < 4; r++) {
            int m = m0 + wm + mt * 16 + quad * 4 + r;
            int n = m / 196, s = m - n * 196 + 1;
            long rowb = ((long)n * SEQ + s) * HDIM;
            #pragma unroll
            for (int nt = 0; nt < 2; nt++) {
                int e = e0 + wn + nt * 16 + col;
                tok[rowb + e] = acc[mt][nt][r] + bias[e] + pos[s * HDIM + e];
            }
        }
    }
}

// ---------------------------------------------------------------------------
// K3: LayerNorm stats per token row
// ---------------------------------------------------------------------------
__global__ __launch_bounds__(256) void k_lnstats(
    const float* __restrict__ tok, float* __restrict__ stats)
{
    int row = blockIdx.x, tid = threadIdx.x;
    const float* p = tok + (long)row * HDIM;
    float s = 0.f, sq = 0.f;
    for (int i = tid; i < HDIM; i += 256) { float v = p[i]; s += v; sq += v * v; }
    __shared__ float rs[256], rq[256];
    rs[tid] = s; rq[tid] = sq; __syncthreads();
    for (int off = 128; off > 0; off >>= 1) {
        if (tid < off) { rs[tid] += rs[tid + off]; rq[tid] += rq[tid + off]; }
        __syncthreads();
    }
    if (tid == 0) {
        float mu = rs[0] / 768.f;
        float var = rq[0] / 768.f - mu * mu;
        stats[row * 2] = mu;
        stats[row * 2 + 1] = rsqrtf(var + EPSF);
    }
}

// ---------------------------------------------------------------------------
// K4: QKV per head, bf16 MFMA; weights pre-swizzled bf16, global_load_lds.
// grid (50, 12).
// ---------------------------------------------------------------------------
__global__ __launch_bounds__(256, 2) void k_qkv(
    const float* __restrict__ tok, const float* __restrict__ stats,
    const float* __restrict__ lng, const float* __restrict__ lnb,
    const ushort* __restrict__ wqs, const float* __restrict__ bqp,
    const ushort* __restrict__ wks, const float* __restrict__ bkp,
    const ushort* __restrict__ wvs, const float* __restrict__ bvp,
    ushort* __restrict__ qo, ushort* __restrict__ ko, ushort* __restrict__ vo)
{
    __shared__ __align__(16) ushort xh[128 * 72];    // 18.4 KB
    __shared__ __align__(16) ushort Wl[3][4096];     // 24 KB, frag-order
    __shared__ float bias[3][64];
    int h = blockIdx.y, t0 = blockIdx.x * 128;
    int tid = threadIdx.x, lane = tid & 63, wave = tid >> 6;
    int col = lane & 15, quad = lane >> 4;

    // stage swizzled weights: 3 x 8KB via global_load_lds width-16
    const ushort* wsz0 = wqs + (long)h * 4096;
    const ushort* wsz1 = wks + (long)h * 4096;
    const ushort* wsz2 = wvs + (long)h * 4096;
    #pragma unroll
    for (int i = 0; i < 2; i++) {
        int c = wave * 2 + i;
        gload_lds16(&wsz0[c * 512 + lane * 8], &Wl[0][c * 512]);
        gload_lds16(&wsz1[c * 512 + lane * 8], &Wl[1][c * 512]);
        gload_lds16(&wsz2[c * 512 + lane * 8], &Wl[2][c * 512]);
    }
    if (tid < 192) {
        int m = tid >> 6, e = tid & 63;
        bias[m][e] = ((m == 0) ? bqp : (m == 1) ? bkp : bvp)[h * 64 + e];
    }
    // stage xh = LN(tok) head-slice, bf16
    for (int i = tid; i < 2048; i += 256) {
        int r = i >> 4, c4 = i & 15;
        int row = t0 + r;
        float4 v = {0.f, 0.f, 0.f, 0.f};
        float mu = 0.f, rstd = 0.f;
        if (row < NTOK) {
            v = *(const float4*)&tok[(long)row * HDIM + h * 64 + c4 * 4];
            mu = stats[row * 2]; rstd = stats[row * 2 + 1];
        }
        int d = c4 * 4;
        const float* g = &lng[h * 64 + d];
        const float* bb = &lnb[h * 64 + d];
        ushort4 u = {f2bf((v.x - mu) * rstd * g[0] + bb[0]),
                     f2bf((v.y - mu) * rstd * g[1] + bb[1]),
                     f2bf((v.z - mu) * rstd * g[2] + bb[2]),
                     f2bf((v.w - mu) * rstd * g[3] + bb[3])};
        *(ushort4*)&xh[r * 72 + d] = u;
    }
    __syncthreads();

    short8 a[2][2];
    #pragma unroll
    for (int mt = 0; mt < 2; mt++)
        #pragma unroll
        for (int kt = 0; kt < 2; kt++)
            a[mt][kt] = *(const short8*)&xh[(wave * 32 + mt * 16 + col) * 72 + kt * 32 + quad * 8];

    f32x4 zero4 = {0.f, 0.f, 0.f, 0.f};
    #pragma unroll
    for (int m = 0; m < 3; m++) {
        f32x4 acc[2][4];
        #pragma unroll
        for (int mt = 0; mt < 2; mt++)
            #pragma unroll
            for (int nt = 0; nt < 4; nt++) acc[mt][nt] = zero4;
        #pragma unroll
        for (int kt = 0; kt < 2; kt++) {
            short8 b[4];
            #pragma unroll
            for (int nt = 0; nt < 4; nt++)
                b[nt] = *(const short8*)&Wl[m][(kt * 4 + nt) * 512 + lane * 8];
            #pragma unroll
            for (int mt = 0; mt < 2; mt++)
                #pragma unroll
                for (int nt = 0; nt < 4; nt++)
                    acc[mt][nt] = __builtin_amdgcn_mfma_f32_16x16x32_bf16(a[mt][kt], b[nt], acc[mt][nt], 0, 0, 0);
        }
        ushort* op = (m == 0) ? qo : (m == 1) ? ko : vo;
        #pragma unroll
        for (int mt = 0; mt < 2; mt++) {
            #pragma unroll
            for (int r = 0; r < 4; r++) {
                int row = t0 + wave * 32 + mt * 16 + quad * 4 + r;
                if (row < NTOK) {
                    int n = row / SEQ, s = row - n * SEQ;
                    long ob = (((long)n * NHEAD + h) * SEQ + s) * DHEAD;
                    #pragma unroll
                    for (int nt = 0; nt < 4; nt++) {
                        int e = nt * 16 + col;
                        op[ob + e] = f2bf(acc[mt][nt][r] + bias[m][e]);
                    }
                }
            }
        }
    }
}

// ---------------------------------------------------------------------------
// K5: bf16-MFMA fused attention + residual (unchanged)
// ---------------------------------------------------------------------------
__global__ __launch_bounds__(256, 2) void k_attn(
    const ushort* __restrict__ qg, const ushort* __restrict__ kg,
    const ushort* __restrict__ vg, float* __restrict__ tok)
{
    __shared__ __align__(16) ushort Ks[208 * 72];
    __shared__ __align__(16) ushort Vt[64 * 232];
    __shared__ __align__(16) ushort Ps[4][16 * 40];

    int n = blockIdx.z, h = blockIdx.y;
    int tid = threadIdx.x;
    int lane = tid & 63;
    int wave = tid >> 6;
    int col = lane & 15;
    int quad = lane >> 4;
    long base = ((long)n * NHEAD + h) * SEQ * DHEAD;

    short8 zero8 = {0, 0, 0, 0, 0, 0, 0, 0};
    for (int id = tid; id < 208 * 8; id += 256) {
        int t = id >> 3, e8 = id & 7;
        short8 w = zero8;
        if (t < SEQ) w = *(const short8*)&kg[base + (long)t * 64 + e8 * 8];
        *(short8*)&Ks[t * 72 + e8 * 8] = w;
    }
    for (int c = wave; c < 56; c += 4) {
        int tb = (c >> 2) * 16;
        int eb = (c & 3) * 4;
        int t = tb + (lane & 15);
        int e4 = eb + (lane >> 4);
        ushort4 v = {0, 0, 0, 0};
        if (t < SEQ) v = *(const ushort4*)&vg[base + (long)t * 64 + e4 * 4];
        Vt[(e4 * 4 + 0) * 232 + t] = v.x;
        Vt[(e4 * 4 + 1) * 232 + t] = v.y;
        Vt[(e4 * 4 + 2) * 232 + t] = v.z;
        Vt[(e4 * 4 + 3) * 232 + t] = v.w;
    }

    int q0w = blockIdx.x * 64 + wave * 16;
    int qrow = q0w + col; if (qrow > SEQ - 1) qrow = SEQ - 1;
    short8 aq[2];
    #pragma unroll
    for (int dt = 0; dt < 2; dt++)
        aq[dt] = *(const short8*)&qg[base + (long)qrow * 64 + dt * 32 + quad * 8];

    __syncthreads();
    if (q0w >= SEQ) return;

    f32x4 zero4 = {0.f, 0.f, 0.f, 0.f};
    f32x4 sc[13];
    #pragma unroll
    for (int tt = 0; tt < 13; tt++) sc[tt] = zero4;
    #pragma unroll
    for (int tt = 0; tt < 13; tt++) {
        #pragma unroll
        for (int dt = 0; dt < 2; dt++) {
            short8 bk = *(const short8*)&Ks[(tt * 16 + col) * 72 + dt * 32 + quad * 8];
            sc[tt] = __builtin_amdgcn_mfma_f32_16x16x32_bf16(aq[dt], bk, sc[tt], 0, 0, 0);
        }
    }

    float rinv[4];
    #pragma unroll
    for (int r = 0; r < 4; r++) {
        float m = -1e30f;
        #pragma unroll
        for (int tt = 0; tt < 12; tt++) m = fmaxf(m, sc[tt][r]);
        if (col < 5) m = fmaxf(m, sc[12][r]);
        #pragma unroll
        for (int off = 1; off < 16; off <<= 1) m = fmaxf(m, __shfl_xor(m, off));
        float s = 0.f;
        #pragma unroll
        for (int tt = 0; tt < 12; tt++) {
            float e = __expf((sc[tt][r] - m) * SCALE);
            sc[tt][r] = e; s += e;
        }
        float e12 = (col < 5) ? __expf((sc[12][r] - m) * SCALE) : 0.f;
        sc[12][r] = e12; s += e12;
        #pragma unroll
        for (int off = 1; off < 16; off <<= 1) s += __shfl_xor(s, off);
        rinv[r] = 1.f / s;
    }

    ushort* myP = &Ps[wave][0];
    f32x4 oacc[4];
    #pragma unroll
    for (int nt = 0; nt < 4; nt++) oacc[nt] = zero4;
    #pragma unroll
    for (int kt = 0; kt < 7; kt++) {
        #pragma unroll
        for (int half = 0; half < 2; half++) {
            int tt = kt * 2 + half;
            #pragma unroll
            for (int r = 0; r < 4; r++) {
                float v = (tt < 13) ? sc[tt][r] : 0.f;
                myP[(quad * 4 + r) * 40 + half * 16 + col] = f2bf(v);
            }
        }
        short8 pa = *(const short8*)&myP[col * 40 + quad * 8];
        #pragma unroll
        for (int nt = 0; nt < 4; nt++) {
            short8 vb = *(const short8*)&Vt[(nt * 16 + col) * 232 + kt * 32 + quad * 8];
            oacc[nt] = __builtin_amdgcn_mfma_f32_16x16x32_bf16(pa, vb, oacc[nt], 0, 0, 0);
        }
    }

    #pragma unroll
    for (int nt = 0; nt < 4; nt++) {
        #pragma unroll
        for (int r = 0; r < 4; r++) {
            int row = q0w + quad * 4 + r;
            if (row < SEQ) {
                long o = ((long)n * SEQ + row) * HDIM + h * 64 + nt * 16 + col;
                tok[o] += oacc[nt][r] * rinv[r];
            }
        }
    }
}

// ---------------------------------------------------------------------------
// K6a: logits GEMM, fp32, wave-cooperative. grid (32 n, 8 ochunks).
// cls cached in 12 regs/lane; coalesced W loads; wave shuffle-reduce.
// ---------------------------------------------------------------------------
__global__ __launch_bounds__(256) void k_logits(
    const float* __restrict__ tok, const float* __restrict__ W,
    const float* __restrict__ b, float* __restrict__ logits)
{
    int n = blockIdx.x, oc = blockIdx.y;
    int tid = threadIdx.x, lane = tid & 63, wave = tid >> 6;
    const float* cp = &tok[(long)n * SEQ * HDIM];
    float4 c0 = *(const float4*)&cp[lane * 4];
    float4 c1 = *(const float4*)&cp[256 + lane * 4];
    float4 c2 = *(const float4*)&cp[512 + lane * 4];
    int obeg = oc * 125, oend = obeg + 125;
    for (int o = obeg + wave; o < oend; o += 4) {
        const float* wr = &W[(long)o * HDIM];
        float4 w0 = *(const float4*)&wr[lane * 4];
        float4 w1 = *(const float4*)&wr[256 + lane * 4];
        float4 w2 = *(const float4*)&wr[512 + lane * 4];
        float s = c0.x * w0.x + c0.y * w0.y + c0.z * w0.z + c0.w * w0.w
                + c1.x * w1.x + c1.y * w1.y + c1.z * w1.z + c1.w * w1.w
                + c2.x * w2.x + c2.y * w2.y + c2.z * w2.z + c2.w * w2.w;
        #pragma unroll
        for (int off = 1; off < 64; off <<= 1) s += __shfl_xor(s, off);
        if (lane == 0) logits[n * NOUT + o] = s + b[o];
    }
}

// ---------------------------------------------------------------------------
// K6b: softmax over 1000 logits per image
// ---------------------------------------------------------------------------
__global__ __launch_bounds__(256) void k_smax(
    const float* __restrict__ logits, float* __restrict__ out)
{
    __shared__ float lg[NOUT];
    __shared__ float red[256];
    int n = blockIdx.x, tid = threadIdx.x;
    for (int o = tid; o < NOUT; o += 256) lg[o] = logits[n * NOUT + o];
    __syncthreads();
    float m = -1e30f;
    for (int o = tid; o < NOUT; o += 256) m = fmaxf(m, lg[o]);
    red[tid] = m; __syncthreads();
    for (int off = 128; off > 0; off >>= 1) {
        if (tid < off) red[tid] = fmaxf(red[tid], red[tid + off]);
        __syncthreads();
    }
    float mx = red[0];
    __syncthreads();
    float s = 0.f;
    for (int o = tid; o < NOUT; o += 256) {
        float e = __expf(lg[o] - mx);
        lg[o] = e; s += e;
    }
    red[tid] = s; __syncthreads();
    for (int off = 128; off > 0; off >>= 1) {
        if (tid < off) red[tid] += red[tid + off];
        __syncthreads();
    }
    float inv = 1.f / red[0];
    for (int o = tid; o < NOUT; o += 256) out[(long)n * NOUT + o] = lg[o] * inv;
}

// ---------------------------------------------------------------------------
extern "C" void kernel_launch(void* const* d_in, const int* in_sizes, int n_in,
                              void* d_out, int out_size, void* d_ws, size_t ws_size,
                              hipStream_t stream)
{
    const float* images  = (const float*)d_in[0];
    const float* conv_w  = (const float*)d_in[1];
    const float* conv_b  = (const float*)d_in[2];
    const float* bn_g    = (const float*)d_in[3];
    const float* bn_b    = (const float*)d_in[4];
    const float* bn_m    = (const float*)d_in[5];
    const float* bn_v    = (const float*)d_in[6];
    const float* map_w   = (const float*)d_in[7];
    const float* map_b   = (const float*)d_in[8];
    const float* cls_tok = (const float*)d_in[9];
    const float* ln_g    = (const float*)d_in[10];
    const float* ln_b    = (const float*)d_in[11];
    const float* wq      = (const float*)d_in[12];
    const float* bq      = (const float*)d_in[13];
    const float* wk      = (const float*)d_in[14];
    const float* bk      = (const float*)d_in[15];
    const float* wv      = (const float*)d_in[16];
    const float* bv      = (const float*)d_in[17];
    const float* mlp_w   = (const float*)d_in[18];
    const float* mlp_b   = (const float*)d_in[19];
    float* out = (float*)d_out;

    const long SZ_X   = (long)NPATCH * IND;       // ushorts
    const long SZ_W   = (long)HDIM * IND;         // ushorts
    const long SZ_WS  = (long)3 * 144 * 4096;     // swizzled qkv weights, ushorts
    const long SZ_POS = (long)SEQ * HDIM;         // floats
    const long SZ_TOK = (long)NTOK * HDIM;        // floats
    const long SZ_QKV = (long)NTOK * HDIM;        // ushorts each

    ushort* Xbf  = (ushort*)d_ws;
    ushort* Wbf  = Xbf + SZ_X;
    ushort* Wswz = Wbf + SZ_W;
    float*  pos  = (float*)(Wswz + SZ_WS);
    float*  tok  = pos + SZ_POS;
    ushort* qb   = (ushort*)(tok + SZ_TOK);
    ushort* kb   = qb + SZ_QKV;
    ushort* vb   = kb + SZ_QKV;
    float* stats = (float*)(vb + SZ_QKV);
    float* logits = (float*)Xbf;                  // Xbf dead after k_embed

    k_cvt<<<600, 256, 0, stream>>>(map_w, Wbf, (int)(SZ_W / 4));
    k_cvtw<<<(3 * 144 * 512 + 255) / 256, 256, 0, stream>>>(wq, wk, wv, Wswz);
    k_pos<<<SEQ, 256, 0, stream>>>(pos);
    k_conv_patch<<<NPATCH / 2, 320, 0, stream>>>(images, conv_w, conv_b, bn_g,
                                                 bn_b, bn_m, bn_v, Xbf);
    k_cls<<<BB, 256, 0, stream>>>(cls_tok, pos, tok);
    dim3 ge(49, 12);
    k_embed<<<ge, 256, 0, stream>>>(Xbf, Wbf, map_b, pos, tok);

    for (int l = 0; l < LLAYERS; l++) {
        k_lnstats<<<NTOK, 256, 0, stream>>>(tok, stats);
        dim3 gq(50, 12);
        k_qkv<<<gq, 256, 0, stream>>>(tok, stats,
            ln_g + (long)l * HDIM, ln_b + (long)l * HDIM,
            Wswz + (long)(0 * 144 + l * 12) * 4096, bq + (long)l * NHEAD * DHEAD,
            Wswz + (long)(1 * 144 + l * 12) * 4096, bk + (long)l * NHEAD * DHEAD,
            Wswz + (long)(2 * 144 + l * 12) * 4096, bv + (long)l * NHEAD * DHEAD,
            qb, kb, vb);
        dim3 ga(4, 12, 32);
        k_attn<<<ga, 256, 0, stream>>>(qb, kb, vb, tok);
    }
    dim3 gl(BB, 8);
    k_logits<<<gl, 256, 0, stream>>>(tok, mlp_w, mlp_b, logits);
    k_smax<<<BB, 256, 0, stream>>>(logits, out);
}

// Round 5
// 883.188 us; speedup vs baseline: 4.3622x; 1.1979x over previous
//
#include <hip/hip_runtime.h>

#define BB 32
#define LLAYERS 12
#define HDIM 768
#define NHEAD 12
#define DHEAD 64
#define SEQ 197
#define IND 800
#define NOUT 1000
#define EPSF 1e-5f
#define NTOK (BB * SEQ)     // 6304
#define NPATCH (BB * 196)   // 6272
#define SCALE 0.125f        // 1/sqrt(64)

typedef __attribute__((ext_vector_type(4))) float f32x4;
typedef __attribute__((ext_vector_type(8))) short short8;

static __device__ __forceinline__ ushort f2bf(float f) {
    union { float f; unsigned u; } v; v.f = f;
    unsigned r = v.u + 0x7FFFu + ((v.u >> 16) & 1u);   // round-to-nearest-even
    return (ushort)(r >> 16);
}

static __device__ __forceinline__ void gload_lds16(const void* g, void* l) {
    __builtin_amdgcn_global_load_lds(
        (const __attribute__((address_space(1))) void*)g,
        (__attribute__((address_space(3))) void*)l, 16, 0, 0);
}

// ---------------------------------------------------------------------------
// K0a: convert map_w fp32 -> bf16
// ---------------------------------------------------------------------------
__global__ __launch_bounds__(256) void k_cvt(
    const float* __restrict__ s, ushort* __restrict__ d, int n4)
{
    int i = blockIdx.x * 256 + threadIdx.x;
    if (i < n4) {
        float4 v = *(const float4*)&s[i * 4];
        ushort4 u = {f2bf(v.x), f2bf(v.y), f2bf(v.z), f2bf(v.w)};
        *(ushort4*)&d[i * 4] = u;
    }
}

// ---------------------------------------------------------------------------
// K0b: convert wq/wk/wv fp32 -> bf16 in MFMA B-frag order.
// ---------------------------------------------------------------------------
__global__ __launch_bounds__(256) void k_cvtw(
    const float* __restrict__ wq, const float* __restrict__ wk,
    const float* __restrict__ wv, ushort* __restrict__ dst)
{
    int t = blockIdx.x * 256 + threadIdx.x;
    if (t >= 3 * 144 * 512) return;
    int lane = t & 63;
    int rest = t >> 6;
    int ktnt = rest & 7;
    int mlh = rest >> 3;
    int h = mlh % 12, ml = mlh / 12;
    int l = ml % 12, m = ml / 12;
    int nt = ktnt & 3, kt = ktnt >> 2;
    int e = nt * 16 + (lane & 15);
    int d = kt * 32 + (lane >> 4) * 8;
    const float* src = ((m == 0) ? wq : (m == 1) ? wk : wv)
                       + (((long)l * 12 + h) * 64 + e) * 64 + d;
    float4 a = *(const float4*)src;
    float4 b = *(const float4*)(src + 4);
    short8 u;
    u[0] = (short)f2bf(a.x); u[1] = (short)f2bf(a.y);
    u[2] = (short)f2bf(a.z); u[3] = (short)f2bf(a.w);
    u[4] = (short)f2bf(b.x); u[5] = (short)f2bf(b.y);
    u[6] = (short)f2bf(b.z); u[7] = (short)f2bf(b.w);
    *(short8*)&dst[(long)mlh * 4096 + ktnt * 512 + lane * 8] = u;
}

// ---------------------------------------------------------------------------
// K0c: sinusoidal pos-emb table [SEQ][HDIM]
// ---------------------------------------------------------------------------
__global__ __launch_bounds__(256) void k_pos(float* __restrict__ pos)
{
    int s = blockIdx.x;
    for (int e = threadIdx.x; e < HDIM; e += 256) {
        float freq = expf((float)(e & ~1) * (-9.210340371976184f / 768.0f));
        float ang = (float)s * freq;
        pos[s * HDIM + e] = (e & 1) ? cosf(ang) : sinf(ang);
    }
}

// ---------------------------------------------------------------------------
// K1: conv + BN + ReLU + patchify -> Xbf. 2 patches/block, 320 threads.
// ---------------------------------------------------------------------------
__global__ __launch_bounds__(320) void k_conv_patch(
    const float* __restrict__ img, const float* __restrict__ cw,
    const float* __restrict__ cb, const float* __restrict__ bg,
    const float* __restrict__ bbias, const float* __restrict__ bm,
    const float* __restrict__ bvv, ushort* __restrict__ X)
{
    __shared__ float tile[2][3][21][21];
    __shared__ float w[2400];
    __shared__ float scale[32], shift[32];
    int tid = threadIdx.x;

    for (int i = tid; i < 2400; i += 320) w[i] = cw[i];
    if (tid < 32) {
        float sc = bg[tid] * rsqrtf(bvv[tid] + EPSF);
        scale[tid] = sc;
        shift[tid] = (cb[tid] - bm[tid]) * sc + bbias[tid];
    }
    for (int i = tid; i < 2 * 3 * 441; i += 320) {
        int pp = i / 1323, j = i % 1323;
        int c = j / 441, r = (j / 21) % 21, cc = j % 21;
        int gp = blockIdx.x * 2 + pp;
        int n = gp / 196, p = gp % 196;
        int h0 = (p / 14) * 20 - 1, w0 = (p % 14) * 20 - 1;
        int gh = h0 + r, gw = w0 + cc;
        float v = 0.f;
        if (gh >= 0 && gh < 280 && gw >= 0 && gw < 280)
            v = img[((long)(n * 3 + c) * 280 + gh) * 280 + gw];
        tile[pp][c][r][cc] = v;
    }
    __syncthreads();

    int pp = tid / 160, u = tid % 160;
    int c = u / 5, ph = u % 5;
    float acc[5] = {0.f, 0.f, 0.f, 0.f, 0.f};
    const float* wp = &w[c * 75];
    #pragma unroll
    for (int ci = 0; ci < 3; ci++) {
        #pragma unroll
        for (int kh = 0; kh < 5; kh++) {
            const float* row = &tile[pp][ci][ph * 4 + kh][0];
            float rv[21];
            #pragma unroll
            for (int j = 0; j < 21; j++) rv[j] = row[j];
            #pragma unroll
            for (int kw = 0; kw < 5; kw++) {
                float wv = wp[ci * 25 + kh * 5 + kw];
                #pragma unroll
                for (int pw = 0; pw < 5; pw++)
                    acc[pw] += rv[pw * 4 + kw] * wv;
            }
        }
    }
    int gp = blockIdx.x * 2 + pp;
    long ob = (long)gp * 800 + c * 25 + ph * 5;
    #pragma unroll
    for (int pw = 0; pw < 5; pw++) {
        float val = acc[pw] * scale[c] + shift[c];
        X[ob + pw] = f2bf(fmaxf(val, 0.f));
    }
}

__global__ void k_cls(const float* __restrict__ cls_tok,
                      const float* __restrict__ pos, float* __restrict__ tok)
{
    int n = blockIdx.x, tid = threadIdx.x;
    for (int e = tid; e < HDIM; e += 256)
        tok[(long)n * SEQ * HDIM + e] = cls_tok[e] + pos[e];
}

// ---------------------------------------------------------------------------
// K2: patch embed GEMM, bf16 MFMA
// ---------------------------------------------------------------------------
__global__ __launch_bounds__(256, 2) void k_embed(
    const ushort* __restrict__ Xg, const ushort* __restrict__ Wg,
    const float* __restrict__ bias, const float* __restrict__ pos,
    float* __restrict__ tok)
{
    __shared__ __align__(16) ushort As[128 * 32];
    __shared__ __align__(16) ushort Bs[64 * 32];
    int m0 = blockIdx.x * 128, e0 = blockIdx.y * 64;
    int tid = threadIdx.x, lane = tid & 63, wave = tid >> 6;
    int col = lane & 15, quad = lane >> 4;
    int wm = (wave & 1) * 64, wn = (wave >> 1) * 32;
    int lr = lane >> 2, lc = (lane & 3) * 8;
    f32x4 zero4 = {0.f, 0.f, 0.f, 0.f};
    f32x4 acc[4][2];
    #pragma unroll
    for (int mt = 0; mt < 4; mt++)
        #pragma unroll
        for (int nt = 0; nt < 2; nt++) acc[mt][nt] = zero4;

    for (int k0 = 0; k0 < 800; k0 += 32) {
        __syncthreads();
        #pragma unroll
        for (int i = 0; i < 2; i++) {
            int c = wave * 2 + i;
            gload_lds16(&Xg[(long)(m0 + c * 16 + lr) * 800 + k0 + lc], &As[c * 512]);
        }
        {
            int c = wave;
            gload_lds16(&Wg[(long)(e0 + c * 16 + lr) * 800 + k0 + lc], &Bs[c * 512]);
        }
        __syncthreads();
        short8 a[4], b[2];
        #pragma unroll
        for (int mt = 0; mt < 4; mt++)
            a[mt] = *(const short8*)&As[(wm + mt * 16 + col) * 32 + quad * 8];
        #pragma unroll
        for (int nt = 0; nt < 2; nt++)
            b[nt] = *(const short8*)&Bs[(wn + nt * 16 + col) * 32 + quad * 8];
        #pragma unroll
        for (int mt = 0; mt < 4; mt++)
            #pragma unroll
            for (int nt = 0; nt < 2; nt++)
                acc[mt][nt] = __builtin_amdgcn_mfma_f32_16x16x32_bf16(a[mt], b[nt], acc[mt][nt], 0, 0, 0);
    }
    #pragma unroll
    for (int mt = 0; mt < 4; mt++) {
        #pragma unroll
        for (int r = 0; r < 4; r++) {
            int m = m0 + wm + mt * 16 + quad * 4 + r;
            int n = m / 196, s = m - n * 196 + 1;
            long rowb = ((long)n * SEQ + s) * HDIM;
            #pragma unroll
            for (int nt = 0; nt < 2; nt++) {
                int e = e0 + wn + nt * 16 + col;
                tok[rowb + e] = acc[mt][nt][r] + bias[e] + pos[s * HDIM + e];
            }
        }
    }
}

// ---------------------------------------------------------------------------
// K3: LayerNorm stats — wave-per-row, shuffle-reduce, no LDS. grid 1576.
// ---------------------------------------------------------------------------
__global__ __launch_bounds__(256) void k_lnstats(
    const float* __restrict__ tok, float* __restrict__ stats)
{
    int tid = threadIdx.x, lane = tid & 63, wave = tid >> 6;
    int row = blockIdx.x * 4 + wave;          // NTOK = 4*1576 exact
    const float* p = tok + (long)row * HDIM;
    float s = 0.f, sq = 0.f;
    #pragma unroll
    for (int k = 0; k < 3; k++) {
        float4 v = *(const float4*)&p[k * 256 + lane * 4];
        s += v.x + v.y + v.z + v.w;
        sq += v.x * v.x + v.y * v.y + v.z * v.z + v.w * v.w;
    }
    #pragma unroll
    for (int off = 1; off < 64; off <<= 1) {
        s += __shfl_xor(s, off);
        sq += __shfl_xor(sq, off);
    }
    if (lane == 0) {
        float mu = s / 768.f;
        float var = sq / 768.f - mu * mu;
        stats[row * 2] = mu;
        stats[row * 2 + 1] = rsqrtf(var + EPSF);
    }
}

// ---------------------------------------------------------------------------
// K4: QKV per head, bf16 MFMA; weights pre-swizzled. grid (50, 12).
// ---------------------------------------------------------------------------
__global__ __launch_bounds__(256, 2) void k_qkv(
    const float* __restrict__ tok, const float* __restrict__ stats,
    const float* __restrict__ lng, const float* __restrict__ lnb,
    const ushort* __restrict__ wqs, const float* __restrict__ bqp,
    const ushort* __restrict__ wks, const float* __restrict__ bkp,
    const ushort* __restrict__ wvs, const float* __restrict__ bvp,
    ushort* __restrict__ qo, ushort* __restrict__ ko, ushort* __restrict__ vo)
{
    __shared__ __align__(16) ushort xh[128 * 72];
    __shared__ __align__(16) ushort Wl[3][4096];
    __shared__ float bias[3][64];
    int h = blockIdx.y, t0 = blockIdx.x * 128;
    int tid = threadIdx.x, lane = tid & 63, wave = tid >> 6;
    int col = lane & 15, quad = lane >> 4;

    const ushort* wsz0 = wqs + (long)h * 4096;
    const ushort* wsz1 = wks + (long)h * 4096;
    const ushort* wsz2 = wvs + (long)h * 4096;
    #pragma unroll
    for (int i = 0; i < 2; i++) {
        int c = wave * 2 + i;
        gload_lds16(&wsz0[c * 512 + lane * 8], &Wl[0][c * 512]);
        gload_lds16(&wsz1[c * 512 + lane * 8], &Wl[1][c * 512]);
        gload_lds16(&wsz2[c * 512 + lane * 8], &Wl[2][c * 512]);
    }
    if (tid < 192) {
        int m = tid >> 6, e = tid & 63;
        bias[m][e] = ((m == 0) ? bqp : (m == 1) ? bkp : bvp)[h * 64 + e];
    }
    for (int i = tid; i < 2048; i += 256) {
        int r = i >> 4, c4 = i & 15;
        int row = t0 + r;
        float4 v = {0.f, 0.f, 0.f, 0.f};
        float mu = 0.f, rstd = 0.f;
        if (row < NTOK) {
            v = *(const float4*)&tok[(long)row * HDIM + h * 64 + c4 * 4];
            mu = stats[row * 2]; rstd = stats[row * 2 + 1];
        }
        int d = c4 * 4;
        const float* g = &lng[h * 64 + d];
        const float* bb = &lnb[h * 64 + d];
        ushort4 u = {f2bf((v.x - mu) * rstd * g[0] + bb[0]),
                     f2bf((v.y - mu) * rstd * g[1] + bb[1]),
                     f2bf((v.z - mu) * rstd * g[2] + bb[2]),
                     f2bf((v.w - mu) * rstd * g[3] + bb[3])};
        *(ushort4*)&xh[r * 72 + d] = u;
    }
    __syncthreads();

    short8 a[2][2];
    #pragma unroll
    for (int mt = 0; mt < 2; mt++)
        #pragma unroll
        for (int kt = 0; kt < 2; kt++)
            a[mt][kt] = *(const short8*)&xh[(wave * 32 + mt * 16 + col) * 72 + kt * 32 + quad * 8];

    f32x4 zero4 = {0.f, 0.f, 0.f, 0.f};
    #pragma unroll
    for (int m = 0; m < 3; m++) {
        f32x4 acc[2][4];
        #pragma unroll
        for (int mt = 0; mt < 2; mt++)
            #pragma unroll
            for (int nt = 0; nt < 4; nt++) acc[mt][nt] = zero4;
        #pragma unroll
        for (int kt = 0; kt < 2; kt++) {
            short8 b[4];
            #pragma unroll
            for (int nt = 0; nt < 4; nt++)
                b[nt] = *(const short8*)&Wl[m][(kt * 4 + nt) * 512 + lane * 8];
            #pragma unroll
            for (int mt = 0; mt < 2; mt++)
                #pragma unroll
                for (int nt = 0; nt < 4; nt++)
                    acc[mt][nt] = __builtin_amdgcn_mfma_f32_16x16x32_bf16(a[mt][kt], b[nt], acc[mt][nt], 0, 0, 0);
        }
        ushort* op = (m == 0) ? qo : (m == 1) ? ko : vo;
        #pragma unroll
        for (int mt = 0; mt < 2; mt++) {
            #pragma unroll
            for (int r = 0; r < 4; r++) {
                int row = t0 + wave * 32 + mt * 16 + quad * 4 + r;
                if (row < NTOK) {
                    int n = row / SEQ, s = row - n * SEQ;
                    long ob = (((long)n * NHEAD + h) * SEQ + s) * DHEAD;
                    #pragma unroll
                    for (int nt = 0; nt < 4; nt++) {
                        int e = nt * 16 + col;
                        op[ob + e] = f2bf(acc[mt][nt][r] + bias[m][e]);
                    }
                }
            }
        }
    }
}

// ---------------------------------------------------------------------------
// K5: bf16-MFMA fused attention + residual.
// grid (12 heads, 32 batch) — K/V staged ONCE per (n,h); 4 waves sweep the
// 13 query strips (strip = 16 rows).
// ---------------------------------------------------------------------------
__global__ __launch_bounds__(256, 2) void k_attn(
    const ushort* __restrict__ qg, const ushort* __restrict__ kg,
    const ushort* __restrict__ vg, float* __restrict__ tok)
{
    __shared__ __align__(16) ushort Ks[208 * 72];
    __shared__ __align__(16) ushort Vt[64 * 232];
    __shared__ __align__(16) ushort Ps[4][16 * 40];

    int h = blockIdx.x, n = blockIdx.y;
    int tid = threadIdx.x;
    int lane = tid & 63;
    int wave = tid >> 6;
    int col = lane & 15;
    int quad = lane >> 4;
    long base = ((long)n * NHEAD + h) * SEQ * DHEAD;

    short8 zero8 = {0, 0, 0, 0, 0, 0, 0, 0};
    for (int id = tid; id < 208 * 8; id += 256) {
        int t = id >> 3, e8 = id & 7;
        short8 w = zero8;
        if (t < SEQ) w = *(const short8*)&kg[base + (long)t * 64 + e8 * 8];
        *(short8*)&Ks[t * 72 + e8 * 8] = w;
    }
    for (int c = wave; c < 56; c += 4) {
        int tb = (c >> 2) * 16;
        int eb = (c & 3) * 4;
        int t = tb + (lane & 15);
        int e4 = eb + (lane >> 4);
        ushort4 v = {0, 0, 0, 0};
        if (t < SEQ) v = *(const ushort4*)&vg[base + (long)t * 64 + e4 * 4];
        Vt[(e4 * 4 + 0) * 232 + t] = v.x;
        Vt[(e4 * 4 + 1) * 232 + t] = v.y;
        Vt[(e4 * 4 + 2) * 232 + t] = v.z;
        Vt[(e4 * 4 + 3) * 232 + t] = v.w;
    }
    __syncthreads();

    f32x4 zero4 = {0.f, 0.f, 0.f, 0.f};
    ushort* myP = &Ps[wave][0];

    for (int st = wave; st < 13; st += 4) {
        int q0 = st * 16;
        int qrow = q0 + col; if (qrow > SEQ - 1) qrow = SEQ - 1;
        short8 aq[2];
        #pragma unroll
        for (int dt = 0; dt < 2; dt++)
            aq[dt] = *(const short8*)&qg[base + (long)qrow * 64 + dt * 32 + quad * 8];

        // ---- scores: 13 key-tiles x 2 MFMAs ----
        f32x4 sc[13];
        #pragma unroll
        for (int tt = 0; tt < 13; tt++) sc[tt] = zero4;
        #pragma unroll
        for (int tt = 0; tt < 13; tt++) {
            #pragma unroll
            for (int dt = 0; dt < 2; dt++) {
                short8 bk = *(const short8*)&Ks[(tt * 16 + col) * 72 + dt * 32 + quad * 8];
                sc[tt] = __builtin_amdgcn_mfma_f32_16x16x32_bf16(aq[dt], bk, sc[tt], 0, 0, 0);
            }
        }

        // ---- softmax (rows = quad*4+r) ----
        float rinv[4];
        #pragma unroll
        for (int r = 0; r < 4; r++) {
            float m = -1e30f;
            #pragma unroll
            for (int tt = 0; tt < 12; tt++) m = fmaxf(m, sc[tt][r]);
            if (col < 5) m = fmaxf(m, sc[12][r]);
            #pragma unroll
            for (int off = 1; off < 16; off <<= 1) m = fmaxf(m, __shfl_xor(m, off));
            float s = 0.f;
            #pragma unroll
            for (int tt = 0; tt < 12; tt++) {
                float e = __expf((sc[tt][r] - m) * SCALE);
                sc[tt][r] = e; s += e;
            }
            float e12 = (col < 5) ? __expf((sc[12][r] - m) * SCALE) : 0.f;
            sc[12][r] = e12; s += e12;
            #pragma unroll
            for (int off = 1; off < 16; off <<= 1) s += __shfl_xor(s, off);
            rinv[r] = 1.f / s;
        }

        // ---- P @ V ----
        f32x4 oacc[4];
        #pragma unroll
        for (int nt = 0; nt < 4; nt++) oacc[nt] = zero4;
        #pragma unroll
        for (int kt = 0; kt < 7; kt++) {
            #pragma unroll
            for (int half = 0; half < 2; half++) {
                int tt = kt * 2 + half;
                #pragma unroll
                for (int r = 0; r < 4; r++) {
                    float v = (tt < 13) ? sc[tt][r] : 0.f;
                    myP[(quad * 4 + r) * 40 + half * 16 + col] = f2bf(v);
                }
            }
            short8 pa = *(const short8*)&myP[col * 40 + quad * 8];
            #pragma unroll
            for (int nt = 0; nt < 4; nt++) {
                short8 vb = *(const short8*)&Vt[(nt * 16 + col) * 232 + kt * 32 + quad * 8];
                oacc[nt] = __builtin_amdgcn_mfma_f32_16x16x32_bf16(pa, vb, oacc[nt], 0, 0, 0);
            }
        }

        // ---- residual add ----
        #pragma unroll
        for (int nt = 0; nt < 4; nt++) {
            #pragma unroll
            for (int r = 0; r < 4; r++) {
                int row = q0 + quad * 4 + r;
                if (row < SEQ) {
                    long o = ((long)n * SEQ + row) * HDIM + h * 64 + nt * 16 + col;
                    tok[o] += oacc[nt][r] * rinv[r];
                }
            }
        }
    }
}

// ---------------------------------------------------------------------------
// K6a: logits GEMM, fp32, wave-cooperative. grid (32 n, 8 ochunks).
// ---------------------------------------------------------------------------
__global__ __launch_bounds__(256) void k_logits(
    const float* __restrict__ tok, const float* __restrict__ W,
    const float* __restrict__ b, float* __restrict__ logits)
{
    int n = blockIdx.x, oc = blockIdx.y;
    int tid = threadIdx.x, lane = tid & 63, wave = tid >> 6;
    const float* cp = &tok[(long)n * SEQ * HDIM];
    float4 c0 = *(const float4*)&cp[lane * 4];
    float4 c1 = *(const float4*)&cp[256 + lane * 4];
    float4 c2 = *(const float4*)&cp[512 + lane * 4];
    int obeg = oc * 125, oend = obeg + 125;
    for (int o = obeg + wave; o < oend; o += 4) {
        const float* wr = &W[(long)o * HDIM];
        float4 w0 = *(const float4*)&wr[lane * 4];
        float4 w1 = *(const float4*)&wr[256 + lane * 4];
        float4 w2 = *(const float4*)&wr[512 + lane * 4];
        float s = c0.x * w0.x + c0.y * w0.y + c0.z * w0.z + c0.w * w0.w
                + c1.x * w1.x + c1.y * w1.y + c1.z * w1.z + c1.w * w1.w
                + c2.x * w2.x + c2.y * w2.y + c2.z * w2.z + c2.w * w2.w;
        #pragma unroll
        for (int off = 1; off < 64; off <<= 1) s += __shfl_xor(s, off);
        if (lane == 0) logits[n * NOUT + o] = s + b[o];
    }
}

// ---------------------------------------------------------------------------
// K6b: softmax over 1000 logits per image
// ---------------------------------------------------------------------------
__global__ __launch_bounds__(256) void k_smax(
    const float* __restrict__ logits, float* __restrict__ out)
{
    __shared__ float lg[NOUT];
    __shared__ float red[256];
    int n = blockIdx.x, tid = threadIdx.x;
    for (int o = tid; o < NOUT; o += 256) lg[o] = logits[n * NOUT + o];
    __syncthreads();
    float m = -1e30f;
    for (int o = tid; o < NOUT; o += 256) m = fmaxf(m, lg[o]);
    red[tid] = m; __syncthreads();
    for (int off = 128; off > 0; off >>= 1) {
        if (tid < off) red[tid] = fmaxf(red[tid], red[tid + off]);
        __syncthreads();
    }
    float mx = red[0];
    __syncthreads();
    float s = 0.f;
    for (int o = tid; o < NOUT; o += 256) {
        float e = __expf(lg[o] - mx);
        lg[o] = e; s += e;
    }
    red[tid] = s; __syncthreads();
    for (int off = 128; off > 0; off >>= 1) {
        if (tid < off) red[tid] += red[tid + off];
        __syncthreads();
    }
    float inv = 1.f / red[0];
    for (int o = tid; o < NOUT; o += 256) out[(long)n * NOUT + o] = lg[o] * inv;
}

// ---------------------------------------------------------------------------
extern "C" void kernel_launch(void* const* d_in, const int* in_sizes, int n_in,
                              void* d_out, int out_size, void* d_ws, size_t ws_size,
                              hipStream_t stream)
{
    const float* images  = (const float*)d_in[0];
    const float* conv_w  = (const float*)d_in[1];
    const float* conv_b  = (const float*)d_in[2];
    const float* bn_g    = (const float*)d_in[3];
    const float* bn_b    = (const float*)d_in[4];
    const float* bn_m    = (const float*)d_in[5];
    const float* bn_v    = (const float*)d_in[6];
    const float* map_w   = (const float*)d_in[7];
    const float* map_b   = (const float*)d_in[8];
    const float* cls_tok = (const float*)d_in[9];
    const float* ln_g    = (const float*)d_in[10];
    const float* ln_b    = (const float*)d_in[11];
    const float* wq      = (const float*)d_in[12];
    const float* bq      = (const float*)d_in[13];
    const float* wk      = (const float*)d_in[14];
    const float* bk      = (const float*)d_in[15];
    const float* wv      = (const float*)d_in[16];
    const float* bv      = (const float*)d_in[17];
    const float* mlp_w   = (const float*)d_in[18];
    const float* mlp_b   = (const float*)d_in[19];
    float* out = (float*)d_out;

    const long SZ_X   = (long)NPATCH * IND;
    const long SZ_W   = (long)HDIM * IND;
    const long SZ_WS  = (long)3 * 144 * 4096;
    const long SZ_POS = (long)SEQ * HDIM;
    const long SZ_TOK = (long)NTOK * HDIM;
    const long SZ_QKV = (long)NTOK * HDIM;

    ushort* Xbf  = (ushort*)d_ws;
    ushort* Wbf  = Xbf + SZ_X;
    ushort* Wswz = Wbf + SZ_W;
    float*  pos  = (float*)(Wswz + SZ_WS);
    float*  tok  = pos + SZ_POS;
    ushort* qb   = (ushort*)(tok + SZ_TOK);
    ushort* kb   = qb + SZ_QKV;
    ushort* vb   = kb + SZ_QKV;
    float* stats = (float*)(vb + SZ_QKV);
    float* logits = (float*)Xbf;

    k_cvt<<<600, 256, 0, stream>>>(map_w, Wbf, (int)(SZ_W / 4));
    k_cvtw<<<(3 * 144 * 512 + 255) / 256, 256, 0, stream>>>(wq, wk, wv, Wswz);
    k_pos<<<SEQ, 256, 0, stream>>>(pos);
    k_conv_patch<<<NPATCH / 2, 320, 0, stream>>>(images, conv_w, conv_b, bn_g,
                                                 bn_b, bn_m, bn_v, Xbf);
    k_cls<<<BB, 256, 0, stream>>>(cls_tok, pos, tok);
    dim3 ge(49, 12);
    k_embed<<<ge, 256, 0, stream>>>(Xbf, Wbf, map_b, pos, tok);

    for (int l = 0; l < LLAYERS; l++) {
        k_lnstats<<<NTOK / 4, 256, 0, stream>>>(tok, stats);
        dim3 gq(50, 12);
        k_qkv<<<gq, 256, 0, stream>>>(tok, stats,
            ln_g + (long)l * HDIM, ln_b + (long)l * HDIM,
            Wswz + (long)(0 * 144 + l * 12) * 4096, bq + (long)l * NHEAD * DHEAD,
            Wswz + (long)(1 * 144 + l * 12) * 4096, bk + (long)l * NHEAD * DHEAD,
            Wswz + (long)(2 * 144 + l * 12) * 4096, bv + (long)l * NHEAD * DHEAD,
            qb, kb, vb);
        dim3 ga(12, 32);
        k_attn<<<ga, 256, 0, stream>>>(qb, kb, vb, tok);
    }
    dim3 gl(BB, 8);
    k_logits<<<gl, 256, 0, stream>>>(tok, mlp_w, mlp_b, logits);
    k_smax<<<BB, 256, 0, stream>>>(logits, out);
}

// Round 6
// 843.771 us; speedup vs baseline: 4.5660x; 1.0467x over previous
//
#include <hip/hip_runtime.h>

#define BB 32
#define LLAYERS 12
#define HDIM 768
#define NHEAD 12
#define DHEAD 64
#define SEQ 197
#define IND 800
#define NOUT 1000
#define EPSF 1e-5f
#define NTOK (BB * SEQ)     // 6304
#define NPATCH (BB * 196)   // 6272
#define SCALE 0.125f        // 1/sqrt(64)

typedef __attribute__((ext_vector_type(4))) float f32x4;
typedef __attribute__((ext_vector_type(8))) short short8;

static __device__ __forceinline__ ushort f2bf(float f) {
    union { float f; unsigned u; } v; v.f = f;
    unsigned r = v.u + 0x7FFFu + ((v.u >> 16) & 1u);   // round-to-nearest-even
    return (ushort)(r >> 16);
}

static __device__ __forceinline__ void gload_lds16(const void* g, void* l) {
    __builtin_amdgcn_global_load_lds(
        (const __attribute__((address_space(1))) void*)g,
        (__attribute__((address_space(3))) void*)l, 16, 0, 0);
}

// ---------------------------------------------------------------------------
// K0a: convert map_w fp32 -> bf16
// ---------------------------------------------------------------------------
__global__ __launch_bounds__(256) void k_cvt(
    const float* __restrict__ s, ushort* __restrict__ d, int n4)
{
    int i = blockIdx.x * 256 + threadIdx.x;
    if (i < n4) {
        float4 v = *(const float4*)&s[i * 4];
        ushort4 u = {f2bf(v.x), f2bf(v.y), f2bf(v.z), f2bf(v.w)};
        *(ushort4*)&d[i * 4] = u;
    }
}

// ---------------------------------------------------------------------------
// K0b: convert wq/wk/wv fp32 -> bf16 in MFMA B-frag order.
// ---------------------------------------------------------------------------
__global__ __launch_bounds__(256) void k_cvtw(
    const float* __restrict__ wq, const float* __restrict__ wk,
    const float* __restrict__ wv, ushort* __restrict__ dst)
{
    int t = blockIdx.x * 256 + threadIdx.x;
    if (t >= 3 * 144 * 512) return;
    int lane = t & 63;
    int rest = t >> 6;
    int ktnt = rest & 7;
    int mlh = rest >> 3;
    int h = mlh % 12, ml = mlh / 12;
    int l = ml % 12, m = ml / 12;
    int nt = ktnt & 3, kt = ktnt >> 2;
    int e = nt * 16 + (lane & 15);
    int d = kt * 32 + (lane >> 4) * 8;
    const float* src = ((m == 0) ? wq : (m == 1) ? wk : wv)
                       + (((long)l * 12 + h) * 64 + e) * 64 + d;
    float4 a = *(const float4*)src;
    float4 b = *(const float4*)(src + 4);
    short8 u;
    u[0] = (short)f2bf(a.x); u[1] = (short)f2bf(a.y);
    u[2] = (short)f2bf(a.z); u[3] = (short)f2bf(a.w);
    u[4] = (short)f2bf(b.x); u[5] = (short)f2bf(b.y);
    u[6] = (short)f2bf(b.z); u[7] = (short)f2bf(b.w);
    *(short8*)&dst[(long)mlh * 4096 + ktnt * 512 + lane * 8] = u;
}

// ---------------------------------------------------------------------------
// K0c: sinusoidal pos-emb table [SEQ][HDIM]
// ---------------------------------------------------------------------------
__global__ __launch_bounds__(256) void k_pos(float* __restrict__ pos)
{
    int s = blockIdx.x;
    for (int e = threadIdx.x; e < HDIM; e += 256) {
        float freq = expf((float)(e & ~1) * (-9.210340371976184f / 768.0f));
        float ang = (float)s * freq;
        pos[s * HDIM + e] = (e & 1) ? cosf(ang) : sinf(ang);
    }
}

// ---------------------------------------------------------------------------
// K1: conv + BN + ReLU + patchify -> Xbf. 2 patches/block, 320 threads.
// ---------------------------------------------------------------------------
__global__ __launch_bounds__(320) void k_conv_patch(
    const float* __restrict__ img, const float* __restrict__ cw,
    const float* __restrict__ cb, const float* __restrict__ bg,
    const float* __restrict__ bbias, const float* __restrict__ bm,
    const float* __restrict__ bvv, ushort* __restrict__ X)
{
    __shared__ float tile[2][3][21][21];
    __shared__ float w[2400];
    __shared__ float scale[32], shift[32];
    int tid = threadIdx.x;

    for (int i = tid; i < 2400; i += 320) w[i] = cw[i];
    if (tid < 32) {
        float sc = bg[tid] * rsqrtf(bvv[tid] + EPSF);
        scale[tid] = sc;
        shift[tid] = (cb[tid] - bm[tid]) * sc + bbias[tid];
    }
    for (int i = tid; i < 2 * 3 * 441; i += 320) {
        int pp = i / 1323, j = i % 1323;
        int c = j / 441, r = (j / 21) % 21, cc = j % 21;
        int gp = blockIdx.x * 2 + pp;
        int n = gp / 196, p = gp % 196;
        int h0 = (p / 14) * 20 - 1, w0 = (p % 14) * 20 - 1;
        int gh = h0 + r, gw = w0 + cc;
        float v = 0.f;
        if (gh >= 0 && gh < 280 && gw >= 0 && gw < 280)
            v = img[((long)(n * 3 + c) * 280 + gh) * 280 + gw];
        tile[pp][c][r][cc] = v;
    }
    __syncthreads();

    int pp = tid / 160, u = tid % 160;
    int c = u / 5, ph = u % 5;
    float acc[5] = {0.f, 0.f, 0.f, 0.f, 0.f};
    const float* wp = &w[c * 75];
    #pragma unroll
    for (int ci = 0; ci < 3; ci++) {
        #pragma unroll
        for (int kh = 0; kh < 5; kh++) {
            const float* row = &tile[pp][ci][ph * 4 + kh][0];
            float rv[21];
            #pragma unroll
            for (int j = 0; j < 21; j++) rv[j] = row[j];
            #pragma unroll
            for (int kw = 0; kw < 5; kw++) {
                float wv = wp[ci * 25 + kh * 5 + kw];
                #pragma unroll
                for (int pw = 0; pw < 5; pw++)
                    acc[pw] += rv[pw * 4 + kw] * wv;
            }
        }
    }
    int gp = blockIdx.x * 2 + pp;
    long ob = (long)gp * 800 + c * 25 + ph * 5;
    #pragma unroll
    for (int pw = 0; pw < 5; pw++) {
        float val = acc[pw] * scale[c] + shift[c];
        X[ob + pw] = f2bf(fmaxf(val, 0.f));
    }
}

__global__ void k_cls(const float* __restrict__ cls_tok,
                      const float* __restrict__ pos, float* __restrict__ tok)
{
    int n = blockIdx.x, tid = threadIdx.x;
    for (int e = tid; e < HDIM; e += 256)
        tok[(long)n * SEQ * HDIM + e] = cls_tok[e] + pos[e];
}

// ---------------------------------------------------------------------------
// K2: patch embed GEMM, bf16 MFMA
// ---------------------------------------------------------------------------
__global__ __launch_bounds__(256, 2) void k_embed(
    const ushort* __restrict__ Xg, const ushort* __restrict__ Wg,
    const float* __restrict__ bias, const float* __restrict__ pos,
    float* __restrict__ tok)
{
    __shared__ __align__(16) ushort As[128 * 32];
    __shared__ __align__(16) ushort Bs[64 * 32];
    int m0 = blockIdx.x * 128, e0 = blockIdx.y * 64;
    int tid = threadIdx.x, lane = tid & 63, wave = tid >> 6;
    int col = lane & 15, quad = lane >> 4;
    int wm = (wave & 1) * 64, wn = (wave >> 1) * 32;
    int lr = lane >> 2, lc = (lane & 3) * 8;
    f32x4 zero4 = {0.f, 0.f, 0.f, 0.f};
    f32x4 acc[4][2];
    #pragma unroll
    for (int mt = 0; mt < 4; mt++)
        #pragma unroll
        for (int nt = 0; nt < 2; nt++) acc[mt][nt] = zero4;

    for (int k0 = 0; k0 < 800; k0 += 32) {
        __syncthreads();
        #pragma unroll
        for (int i = 0; i < 2; i++) {
            int c = wave * 2 + i;
            gload_lds16(&Xg[(long)(m0 + c * 16 + lr) * 800 + k0 + lc], &As[c * 512]);
        }
        {
            int c = wave;
            gload_lds16(&Wg[(long)(e0 + c * 16 + lr) * 800 + k0 + lc], &Bs[c * 512]);
        }
        __syncthreads();
        short8 a[4], b[2];
        #pragma unroll
        for (int mt = 0; mt < 4; mt++)
            a[mt] = *(const short8*)&As[(wm + mt * 16 + col) * 32 + quad * 8];
        #pragma unroll
        for (int nt = 0; nt < 2; nt++)
            b[nt] = *(const short8*)&Bs[(wn + nt * 16 + col) * 32 + quad * 8];
        #pragma unroll
        for (int mt = 0; mt < 4; mt++)
            #pragma unroll
            for (int nt = 0; nt < 2; nt++)
                acc[mt][nt] = __builtin_amdgcn_mfma_f32_16x16x32_bf16(a[mt], b[nt], acc[mt][nt], 0, 0, 0);
    }
    #pragma unroll
    for (int mt = 0; mt < 4; mt++) {
        #pragma unroll
        for (int r = 0; r < 4; r++) {
            int m = m0 + wm + mt * 16 + quad * 4 + r;
            int n = m / 196, s = m - n * 196 + 1;
            long rowb = ((long)n * SEQ + s) * HDIM;
            #pragma unroll
            for (int nt = 0; nt < 2; nt++) {
                int e = e0 + wn + nt * 16 + col;
                tok[rowb + e] = acc[mt][nt][r] + bias[e] + pos[s * HDIM + e];
            }
        }
    }
}

// ---------------------------------------------------------------------------
// K3: initial LN partial-stats (layer 0): raw (s, sq) into slot h=0, zero rest.
// stats layout: [row][12][2] floats.
// ---------------------------------------------------------------------------
__global__ __launch_bounds__(256) void k_lnstats0(
    const float* __restrict__ tok, float* __restrict__ stats_out)
{
    int tid = threadIdx.x, lane = tid & 63, wave = tid >> 6;
    int row = blockIdx.x * 4 + wave;          // NTOK = 4*1576 exact
    const float* p = tok + (long)row * HDIM;
    float s = 0.f, sq = 0.f;
    #pragma unroll
    for (int k = 0; k < 3; k++) {
        float4 v = *(const float4*)&p[k * 256 + lane * 4];
        s += v.x + v.y + v.z + v.w;
        sq += v.x * v.x + v.y * v.y + v.z * v.z + v.w * v.w;
    }
    #pragma unroll
    for (int off = 1; off < 64; off <<= 1) {
        s += __shfl_xor(s, off);
        sq += __shfl_xor(sq, off);
    }
    float* sp = &stats_out[(long)row * 24];
    if (lane == 0) { sp[0] = s; sp[1] = sq; }
    if (lane >= 2 && lane < 24) sp[lane] = 0.f;
}

// ---------------------------------------------------------------------------
// K4: FUSED transformer layer: LN + QKV + attention + residual + next-layer
// partial stats. One block per (n,h): grid (12, 32), 256 thr = 4 waves.
//   phase 1: stage frag-order W (async), per-row mu/rstd from stats partials
//   phase 2: xh = bf16(LN(tok slice))   [208 rows, pad tail zeroed]
//   phase 3: per strip: K -> Ks, V -> Vt (transposed), Q -> back into xh rows
//   phase 4: per strip: scores -> softmax -> PV -> tok RMW + stats partials
// ---------------------------------------------------------------------------
__global__ __launch_bounds__(256, 1) void k_layer(
    float* __restrict__ tok,
    const float* __restrict__ stats_in, float* __restrict__ stats_out,
    const float* __restrict__ lng, const float* __restrict__ lnb,
    const ushort* __restrict__ wqs, const float* __restrict__ bqp,
    const ushort* __restrict__ wks, const float* __restrict__ bkp,
    const ushort* __restrict__ wvs, const float* __restrict__ bvp)
{
    __shared__ __align__(16) ushort Wl[3][4096];   // 24 KB frag-order weights
    __shared__ __align__(16) ushort xh[208 * 72];  // LN'd tokens -> later Q
    __shared__ __align__(16) ushort Ks[208 * 72];
    __shared__ __align__(16) ushort Vt[64 * 232];
    __shared__ __align__(16) ushort Ps[4][16 * 40];
    __shared__ float smu[208], srstd[208];
    __shared__ float bias[3][64];

    int h = blockIdx.x, n = blockIdx.y;
    int tid = threadIdx.x, lane = tid & 63, wave = tid >> 6;
    int col = lane & 15, quad = lane >> 4;
    f32x4 zero4 = {0.f, 0.f, 0.f, 0.f};

    // ---- phase 1: weights (async), bias, per-row stats reduce ----
    const ushort* wsz0 = wqs + (long)h * 4096;
    const ushort* wsz1 = wks + (long)h * 4096;
    const ushort* wsz2 = wvs + (long)h * 4096;
    #pragma unroll
    for (int i = 0; i < 2; i++) {
        int c = wave * 2 + i;
        gload_lds16(&wsz0[c * 512 + lane * 8], &Wl[0][c * 512]);
        gload_lds16(&wsz1[c * 512 + lane * 8], &Wl[1][c * 512]);
        gload_lds16(&wsz2[c * 512 + lane * 8], &Wl[2][c * 512]);
    }
    if (tid < 192) {
        int m = tid >> 6, e = tid & 63;
        bias[m][e] = ((m == 0) ? bqp : (m == 1) ? bkp : bvp)[h * 64 + e];
    }
    for (int r = tid; r < SEQ; r += 256) {
        const float* sp = &stats_in[((long)n * SEQ + r) * 24];
        float s = 0.f, sq = 0.f;
        #pragma unroll
        for (int j = 0; j < 6; j++) {
            float4 v = *(const float4*)&sp[j * 4];
            s += v.x + v.z;
            sq += v.y + v.w;
        }
        float mu = s / 768.f;
        smu[r] = mu;
        srstd[r] = rsqrtf(sq / 768.f - mu * mu + EPSF);
    }
    // zero Vt pad columns t in [208,232)
    for (int i = tid; i < 64 * 24; i += 256) {
        int e = i / 24, t = 208 + i % 24;
        Vt[e * 232 + t] = 0;
    }
    __syncthreads();

    // ---- phase 2: xh = bf16(LN(tok head-slice)) ----
    for (int i = tid; i < 208 * 16; i += 256) {
        int r = i >> 4, c4 = i & 15;
        ushort4 u = {0, 0, 0, 0};
        if (r < SEQ) {
            float4 v = *(const float4*)&tok[((long)n * SEQ + r) * HDIM + h * 64 + c4 * 4];
            float mu = smu[r], rstd = srstd[r];
            int d = c4 * 4;
            const float* g = &lng[h * 64 + d];
            const float* bb = &lnb[h * 64 + d];
            u.x = f2bf((v.x - mu) * rstd * g[0] + bb[0]);
            u.y = f2bf((v.y - mu) * rstd * g[1] + bb[1]);
            u.z = f2bf((v.z - mu) * rstd * g[2] + bb[2]);
            u.w = f2bf((v.w - mu) * rstd * g[3] + bb[3]);
        }
        *(ushort4*)&xh[r * 72 + c4 * 4] = u;
    }
    __syncthreads();   // xh visible; Wl gloads drained

    // ---- phase 3: QKV per strip (strip = 16 tokens, st = sl*4 + wave) ----
    #pragma unroll
    for (int sl = 0; sl < 4; sl++) {
        int st = sl * 4 + wave;
        if (st < 13) {
            int q0 = st * 16;
            short8 a[2];
            a[0] = *(const short8*)&xh[(q0 + col) * 72 + quad * 8];
            a[1] = *(const short8*)&xh[(q0 + col) * 72 + 32 + quad * 8];
            #pragma unroll
            for (int m = 0; m < 3; m++) {
                f32x4 acc[4] = {zero4, zero4, zero4, zero4};
                #pragma unroll
                for (int kt = 0; kt < 2; kt++)
                    #pragma unroll
                    for (int nt = 0; nt < 4; nt++) {
                        short8 b = *(const short8*)&Wl[m][(kt * 4 + nt) * 512 + lane * 8];
                        acc[nt] = __builtin_amdgcn_mfma_f32_16x16x32_bf16(a[kt], b, acc[nt], 0, 0, 0);
                    }
                if (m == 0) {
                    // Q written back into xh rows (this wave owns these rows;
                    // A-frags already in regs)
                    #pragma unroll
                    for (int nt = 0; nt < 4; nt++)
                        #pragma unroll
                        for (int r = 0; r < 4; r++)
                            xh[(q0 + quad * 4 + r) * 72 + nt * 16 + col] =
                                f2bf(acc[nt][r] + bias[0][nt * 16 + col]);
                } else if (m == 1) {
                    #pragma unroll
                    for (int nt = 0; nt < 4; nt++)
                        #pragma unroll
                        for (int r = 0; r < 4; r++)
                            Ks[(q0 + quad * 4 + r) * 72 + nt * 16 + col] =
                                f2bf(acc[nt][r] + bias[1][nt * 16 + col]);
                } else {
                    #pragma unroll
                    for (int nt = 0; nt < 4; nt++)
                        #pragma unroll
                        for (int r = 0; r < 4; r++)
                            Vt[(nt * 16 + col) * 232 + q0 + quad * 4 + r] =
                                f2bf(acc[nt][r] + bias[2][nt * 16 + col]);
                }
            }
        }
    }
    __syncthreads();   // K, V, Q all staged

    // ---- phase 4: attention per strip ----
    ushort* myP = &Ps[wave][0];
    #pragma unroll
    for (int sl = 0; sl < 4; sl++) {
        int st = sl * 4 + wave;
        if (st >= 13) continue;
        int q0 = st * 16;
        short8 aq[2];
        aq[0] = *(const short8*)&xh[(q0 + col) * 72 + quad * 8];
        aq[1] = *(const short8*)&xh[(q0 + col) * 72 + 32 + quad * 8];

        // scores: 13 key tiles x 2 MFMAs
        f32x4 sc[13];
        #pragma unroll
        for (int tt = 0; tt < 13; tt++) sc[tt] = zero4;
        #pragma unroll
        for (int tt = 0; tt < 13; tt++) {
            #pragma unroll
            for (int dt = 0; dt < 2; dt++) {
                short8 bk = *(const short8*)&Ks[(tt * 16 + col) * 72 + dt * 32 + quad * 8];
                sc[tt] = __builtin_amdgcn_mfma_f32_16x16x32_bf16(aq[dt], bk, sc[tt], 0, 0, 0);
            }
        }

        // softmax (rows = quad*4+r; key = tt*16+col, mask >=197 in tile 12)
        float rinv[4];
        #pragma unroll
        for (int r = 0; r < 4; r++) {
            float m = -1e30f;
            #pragma unroll
            for (int tt = 0; tt < 12; tt++) m = fmaxf(m, sc[tt][r]);
            if (col < 5) m = fmaxf(m, sc[12][r]);
            #pragma unroll
            for (int off = 1; off < 16; off <<= 1) m = fmaxf(m, __shfl_xor(m, off));
            float s = 0.f;
            #pragma unroll
            for (int tt = 0; tt < 12; tt++) {
                float e = __expf((sc[tt][r] - m) * SCALE);
                sc[tt][r] = e; s += e;
            }
            float e12 = (col < 5) ? __expf((sc[12][r] - m) * SCALE) : 0.f;
            sc[12][r] = e12; s += e12;
            #pragma unroll
            for (int off = 1; off < 16; off <<= 1) s += __shfl_xor(s, off);
            rinv[r] = 1.f / s;
        }

        // P @ V
        f32x4 oacc[4];
        #pragma unroll
        for (int nt = 0; nt < 4; nt++) oacc[nt] = zero4;
        #pragma unroll
        for (int kt = 0; kt < 7; kt++) {
            #pragma unroll
            for (int half = 0; half < 2; half++) {
                int tt = kt * 2 + half;
                #pragma unroll
                for (int r = 0; r < 4; r++) {
                    float v = (tt < 13) ? sc[tt][r] : 0.f;
                    myP[(quad * 4 + r) * 40 + half * 16 + col] = f2bf(v);
                }
            }
            short8 pa = *(const short8*)&myP[col * 40 + quad * 8];
            #pragma unroll
            for (int nt = 0; nt < 4; nt++) {
                short8 vb = *(const short8*)&Vt[(nt * 16 + col) * 232 + kt * 32 + quad * 8];
                oacc[nt] = __builtin_amdgcn_mfma_f32_16x16x32_bf16(pa, vb, oacc[nt], 0, 0, 0);
            }
        }

        // residual RMW + next-layer partial stats for this 64-col slice
        #pragma unroll
        for (int r = 0; r < 4; r++) {
            int row = q0 + quad * 4 + r;
            float s = 0.f, sq = 0.f;
            if (row < SEQ) {
                float rv = rinv[r];
                #pragma unroll
                for (int nt = 0; nt < 4; nt++) {
                    long o = ((long)n * SEQ + row) * HDIM + h * 64 + nt * 16 + col;
                    float nv = tok[o] + oacc[nt][r] * rv;
                    tok[o] = nv;
                    s += nv; sq += nv * nv;
                }
            }
            #pragma unroll
            for (int off = 1; off < 16; off <<= 1) {
                s += __shfl_xor(s, off);
                sq += __shfl_xor(sq, off);
            }
            if (row < SEQ && col == 0) {
                float* sp = &stats_out[((long)n * SEQ + row) * 24 + h * 2];
                sp[0] = s; sp[1] = sq;
            }
        }
    }
}

// ---------------------------------------------------------------------------
// K6a: logits GEMM, fp32, wave-cooperative. grid (32 n, 8 ochunks).
// ---------------------------------------------------------------------------
__global__ __launch_bounds__(256) void k_logits(
    const float* __restrict__ tok, const float* __restrict__ W,
    const float* __restrict__ b, float* __restrict__ logits)
{
    int n = blockIdx.x, oc = blockIdx.y;
    int tid = threadIdx.x, lane = tid & 63, wave = tid >> 6;
    const float* cp = &tok[(long)n * SEQ * HDIM];
    float4 c0 = *(const float4*)&cp[lane * 4];
    float4 c1 = *(const float4*)&cp[256 + lane * 4];
    float4 c2 = *(const float4*)&cp[512 + lane * 4];
    int obeg = oc * 125, oend = obeg + 125;
    for (int o = obeg + wave; o < oend; o += 4) {
        const float* wr = &W[(long)o * HDIM];
        float4 w0 = *(const float4*)&wr[lane * 4];
        float4 w1 = *(const float4*)&wr[256 + lane * 4];
        float4 w2 = *(const float4*)&wr[512 + lane * 4];
        float s = c0.x * w0.x + c0.y * w0.y + c0.z * w0.z + c0.w * w0.w
                + c1.x * w1.x + c1.y * w1.y + c1.z * w1.z + c1.w * w1.w
                + c2.x * w2.x + c2.y * w2.y + c2.z * w2.z + c2.w * w2.w;
        #pragma unroll
        for (int off = 1; off < 64; off <<= 1) s += __shfl_xor(s, off);
        if (lane == 0) logits[n * NOUT + o] = s + b[o];
    }
}

// ---------------------------------------------------------------------------
// K6b: softmax over 1000 logits per image
// ---------------------------------------------------------------------------
__global__ __launch_bounds__(256) void k_smax(
    const float* __restrict__ logits, float* __restrict__ out)
{
    __shared__ float lg[NOUT];
    __shared__ float red[256];
    int n = blockIdx.x, tid = threadIdx.x;
    for (int o = tid; o < NOUT; o += 256) lg[o] = logits[n * NOUT + o];
    __syncthreads();
    float m = -1e30f;
    for (int o = tid; o < NOUT; o += 256) m = fmaxf(m, lg[o]);
    red[tid] = m; __syncthreads();
    for (int off = 128; off > 0; off >>= 1) {
        if (tid < off) red[tid] = fmaxf(red[tid], red[tid + off]);
        __syncthreads();
    }
    float mx = red[0];
    __syncthreads();
    float s = 0.f;
    for (int o = tid; o < NOUT; o += 256) {
        float e = __expf(lg[o] - mx);
        lg[o] = e; s += e;
    }
    red[tid] = s; __syncthreads();
    for (int off = 128; off > 0; off >>= 1) {
        if (tid < off) red[tid] += red[tid + off];
        __syncthreads();
    }
    float inv = 1.f / red[0];
    for (int o = tid; o < NOUT; o += 256) out[(long)n * NOUT + o] = lg[o] * inv;
}

// ---------------------------------------------------------------------------
extern "C" void kernel_launch(void* const* d_in, const int* in_sizes, int n_in,
                              void* d_out, int out_size, void* d_ws, size_t ws_size,
                              hipStream_t stream)
{
    const float* images  = (const float*)d_in[0];
    const float* conv_w  = (const float*)d_in[1];
    const float* conv_b  = (const float*)d_in[2];
    const float* bn_g    = (const float*)d_in[3];
    const float* bn_b    = (const float*)d_in[4];
    const float* bn_m    = (const float*)d_in[5];
    const float* bn_v    = (const float*)d_in[6];
    const float* map_w   = (const float*)d_in[7];
    const float* map_b   = (const float*)d_in[8];
    const float* cls_tok = (const float*)d_in[9];
    const float* ln_g    = (const float*)d_in[10];
    const float* ln_b    = (const float*)d_in[11];
    const float* wq      = (const float*)d_in[12];
    const float* bq      = (const float*)d_in[13];
    const float* wk      = (const float*)d_in[14];
    const float* bk      = (const float*)d_in[15];
    const float* wv      = (const float*)d_in[16];
    const float* bv      = (const float*)d_in[17];
    const float* mlp_w   = (const float*)d_in[18];
    const float* mlp_b   = (const float*)d_in[19];
    float* out = (float*)d_out;

    const long SZ_X   = (long)NPATCH * IND;       // ushorts
    const long SZ_W   = (long)HDIM * IND;         // ushorts
    const long SZ_WS  = (long)3 * 144 * 4096;     // ushorts
    const long SZ_POS = (long)SEQ * HDIM;         // floats
    const long SZ_TOK = (long)NTOK * HDIM;        // floats
    const long SZ_ST  = (long)NTOK * 24;          // floats

    ushort* Xbf   = (ushort*)d_ws;
    ushort* Wbf   = Xbf + SZ_X;
    ushort* Wswz  = Wbf + SZ_W;
    float*  pos   = (float*)(Wswz + SZ_WS);
    float*  tok   = pos + SZ_POS;
    float*  sta   = tok + SZ_TOK;
    float*  stb   = sta + SZ_ST;
    float* logits = (float*)Xbf;                  // Xbf dead after k_embed

    k_cvt<<<600, 256, 0, stream>>>(map_w, Wbf, (int)(SZ_W / 4));
    k_cvtw<<<(3 * 144 * 512 + 255) / 256, 256, 0, stream>>>(wq, wk, wv, Wswz);
    k_pos<<<SEQ, 256, 0, stream>>>(pos);
    k_conv_patch<<<NPATCH / 2, 320, 0, stream>>>(images, conv_w, conv_b, bn_g,
                                                 bn_b, bn_m, bn_v, Xbf);
    k_cls<<<BB, 256, 0, stream>>>(cls_tok, pos, tok);
    dim3 ge(49, 12);
    k_embed<<<ge, 256, 0, stream>>>(Xbf, Wbf, map_b, pos, tok);

    k_lnstats0<<<NTOK / 4, 256, 0, stream>>>(tok, sta);
    for (int l = 0; l < LLAYERS; l++) {
        float* srd = (l & 1) ? stb : sta;
        float* swr = (l & 1) ? sta : stb;
        dim3 gl(12, 32);
        k_layer<<<gl, 256, 0, stream>>>(tok, srd, swr,
            ln_g + (long)l * HDIM, ln_b + (long)l * HDIM,
            Wswz + (long)(0 * 144 + l * 12) * 4096, bq + (long)l * NHEAD * DHEAD,
            Wswz + (long)(1 * 144 + l * 12) * 4096, bk + (long)l * NHEAD * DHEAD,
            Wswz + (long)(2 * 144 + l * 12) * 4096, bv + (long)l * NHEAD * DHEAD);
    }
    dim3 glo(BB, 8);
    k_logits<<<glo, 256, 0, stream>>>(tok, mlp_w, mlp_b, logits);
    k_smax<<<BB, 256, 0, stream>>>(logits, out);
}

// Round 7
// 624.514 us; speedup vs baseline: 6.1690x; 1.3511x over previous
//
#include <hip/hip_runtime.h>

#define BB 32
#define LLAYERS 12
#define HDIM 768
#define NHEAD 12
#define DHEAD 64
#define SEQ 197
#define IND 800
#define NOUT 1000
#define EPSF 1e-5f
#define NTOK (BB * SEQ)     // 6304
#define NPATCH (BB * 196)   // 6272
#define SCALE 0.125f        // 1/sqrt(64)

typedef __attribute__((ext_vector_type(4))) float f32x4;
typedef __attribute__((ext_vector_type(8))) short short8;

static __device__ __forceinline__ ushort f2bf(float f) {
    union { float f; unsigned u; } v; v.f = f;
    unsigned r = v.u + 0x7FFFu + ((v.u >> 16) & 1u);   // round-to-nearest-even
    return (ushort)(r >> 16);
}

static __device__ __forceinline__ void gload_lds16(const void* g, void* l) {
    __builtin_amdgcn_global_load_lds(
        (const __attribute__((address_space(1))) void*)g,
        (__attribute__((address_space(3))) void*)l, 16, 0, 0);
}

// ---------------------------------------------------------------------------
// K0a: convert map_w fp32 -> bf16
// ---------------------------------------------------------------------------
__global__ __launch_bounds__(256) void k_cvt(
    const float* __restrict__ s, ushort* __restrict__ d, int n4)
{
    int i = blockIdx.x * 256 + threadIdx.x;
    if (i < n4) {
        float4 v = *(const float4*)&s[i * 4];
        ushort4 u = {f2bf(v.x), f2bf(v.y), f2bf(v.z), f2bf(v.w)};
        *(ushort4*)&d[i * 4] = u;
    }
}

// ---------------------------------------------------------------------------
// K0b: convert wq/wk/wv fp32 -> bf16 in MFMA B-frag order.
// ---------------------------------------------------------------------------
__global__ __launch_bounds__(256) void k_cvtw(
    const float* __restrict__ wq, const float* __restrict__ wk,
    const float* __restrict__ wv, ushort* __restrict__ dst)
{
    int t = blockIdx.x * 256 + threadIdx.x;
    if (t >= 3 * 144 * 512) return;
    int lane = t & 63;
    int rest = t >> 6;
    int ktnt = rest & 7;
    int mlh = rest >> 3;
    int h = mlh % 12, ml = mlh / 12;
    int l = ml % 12, m = ml / 12;
    int nt = ktnt & 3, kt = ktnt >> 2;
    int e = nt * 16 + (lane & 15);
    int d = kt * 32 + (lane >> 4) * 8;
    const float* src = ((m == 0) ? wq : (m == 1) ? wk : wv)
                       + (((long)l * 12 + h) * 64 + e) * 64 + d;
    float4 a = *(const float4*)src;
    float4 b = *(const float4*)(src + 4);
    short8 u;
    u[0] = (short)f2bf(a.x); u[1] = (short)f2bf(a.y);
    u[2] = (short)f2bf(a.z); u[3] = (short)f2bf(a.w);
    u[4] = (short)f2bf(b.x); u[5] = (short)f2bf(b.y);
    u[6] = (short)f2bf(b.z); u[7] = (short)f2bf(b.w);
    *(short8*)&dst[(long)mlh * 4096 + ktnt * 512 + lane * 8] = u;
}

// ---------------------------------------------------------------------------
// K0c: sinusoidal pos-emb table [SEQ][HDIM]
// ---------------------------------------------------------------------------
__global__ __launch_bounds__(256) void k_pos(float* __restrict__ pos)
{
    int s = blockIdx.x;
    for (int e = threadIdx.x; e < HDIM; e += 256) {
        float freq = expf((float)(e & ~1) * (-9.210340371976184f / 768.0f));
        float ang = (float)s * freq;
        pos[s * HDIM + e] = (e & 1) ? cosf(ang) : sinf(ang);
    }
}

// ---------------------------------------------------------------------------
// K1: conv + BN + ReLU + patchify -> Xbf. 2 patches/block, 320 threads.
// ---------------------------------------------------------------------------
__global__ __launch_bounds__(320) void k_conv_patch(
    const float* __restrict__ img, const float* __restrict__ cw,
    const float* __restrict__ cb, const float* __restrict__ bg,
    const float* __restrict__ bbias, const float* __restrict__ bm,
    const float* __restrict__ bvv, ushort* __restrict__ X)
{
    __shared__ float tile[2][3][21][21];
    __shared__ float w[2400];
    __shared__ float scale[32], shift[32];
    int tid = threadIdx.x;

    for (int i = tid; i < 2400; i += 320) w[i] = cw[i];
    if (tid < 32) {
        float sc = bg[tid] * rsqrtf(bvv[tid] + EPSF);
        scale[tid] = sc;
        shift[tid] = (cb[tid] - bm[tid]) * sc + bbias[tid];
    }
    for (int i = tid; i < 2 * 3 * 441; i += 320) {
        int pp = i / 1323, j = i % 1323;
        int c = j / 441, r = (j / 21) % 21, cc = j % 21;
        int gp = blockIdx.x * 2 + pp;
        int n = gp / 196, p = gp % 196;
        int h0 = (p / 14) * 20 - 1, w0 = (p % 14) * 20 - 1;
        int gh = h0 + r, gw = w0 + cc;
        float v = 0.f;
        if (gh >= 0 && gh < 280 && gw >= 0 && gw < 280)
            v = img[((long)(n * 3 + c) * 280 + gh) * 280 + gw];
        tile[pp][c][r][cc] = v;
    }
    __syncthreads();

    int pp = tid / 160, u = tid % 160;
    int c = u / 5, ph = u % 5;
    float acc[5] = {0.f, 0.f, 0.f, 0.f, 0.f};
    const float* wp = &w[c * 75];
    #pragma unroll
    for (int ci = 0; ci < 3; ci++) {
        #pragma unroll
        for (int kh = 0; kh < 5; kh++) {
            const float* row = &tile[pp][ci][ph * 4 + kh][0];
            float rv[21];
            #pragma unroll
            for (int j = 0; j < 21; j++) rv[j] = row[j];
            #pragma unroll
            for (int kw = 0; kw < 5; kw++) {
                float wv = wp[ci * 25 + kh * 5 + kw];
                #pragma unroll
                for (int pw = 0; pw < 5; pw++)
                    acc[pw] += rv[pw * 4 + kw] * wv;
            }
        }
    }
    int gp = blockIdx.x * 2 + pp;
    long ob = (long)gp * 800 + c * 25 + ph * 5;
    #pragma unroll
    for (int pw = 0; pw < 5; pw++) {
        float val = acc[pw] * scale[c] + shift[c];
        X[ob + pw] = f2bf(fmaxf(val, 0.f));
    }
}

__global__ void k_cls(const float* __restrict__ cls_tok,
                      const float* __restrict__ pos, float* __restrict__ tok)
{
    int n = blockIdx.x, tid = threadIdx.x;
    for (int e = tid; e < HDIM; e += 256)
        tok[(long)n * SEQ * HDIM + e] = cls_tok[e] + pos[e];
}

// ---------------------------------------------------------------------------
// K2: patch embed GEMM, bf16 MFMA
// ---------------------------------------------------------------------------
__global__ __launch_bounds__(256, 2) void k_embed(
    const ushort* __restrict__ Xg, const ushort* __restrict__ Wg,
    const float* __restrict__ bias, const float* __restrict__ pos,
    float* __restrict__ tok)
{
    __shared__ __align__(16) ushort As[128 * 32];
    __shared__ __align__(16) ushort Bs[64 * 32];
    int m0 = blockIdx.x * 128, e0 = blockIdx.y * 64;
    int tid = threadIdx.x, lane = tid & 63, wave = tid >> 6;
    int col = lane & 15, quad = lane >> 4;
    int wm = (wave & 1) * 64, wn = (wave >> 1) * 32;
    int lr = lane >> 2, lc = (lane & 3) * 8;
    f32x4 zero4 = {0.f, 0.f, 0.f, 0.f};
    f32x4 acc[4][2];
    #pragma unroll
    for (int mt = 0; mt < 4; mt++)
        #pragma unroll
        for (int nt = 0; nt < 2; nt++) acc[mt][nt] = zero4;

    for (int k0 = 0; k0 < 800; k0 += 32) {
        __syncthreads();
        #pragma unroll
        for (int i = 0; i < 2; i++) {
            int c = wave * 2 + i;
            gload_lds16(&Xg[(long)(m0 + c * 16 + lr) * 800 + k0 + lc], &As[c * 512]);
        }
        {
            int c = wave;
            gload_lds16(&Wg[(long)(e0 + c * 16 + lr) * 800 + k0 + lc], &Bs[c * 512]);
        }
        __syncthreads();
        short8 a[4], b[2];
        #pragma unroll
        for (int mt = 0; mt < 4; mt++)
            a[mt] = *(const short8*)&As[(wm + mt * 16 + col) * 32 + quad * 8];
        #pragma unroll
        for (int nt = 0; nt < 2; nt++)
            b[nt] = *(const short8*)&Bs[(wn + nt * 16 + col) * 32 + quad * 8];
        #pragma unroll
        for (int mt = 0; mt < 4; mt++)
            #pragma unroll
            for (int nt = 0; nt < 2; nt++)
                acc[mt][nt] = __builtin_amdgcn_mfma_f32_16x16x32_bf16(a[mt], b[nt], acc[mt][nt], 0, 0, 0);
    }
    #pragma unroll
    for (int mt = 0; mt < 4; mt++) {
        #pragma unroll
        for (int r = 0; r < 4; r++) {
            int m = m0 + wm + mt * 16 + quad * 4 + r;
            int n = m / 196, s = m - n * 196 + 1;
            long rowb = ((long)n * SEQ + s) * HDIM;
            #pragma unroll
            for (int nt = 0; nt < 2; nt++) {
                int e = e0 + wn + nt * 16 + col;
                tok[rowb + e] = acc[mt][nt][r] + bias[e] + pos[s * HDIM + e];
            }
        }
    }
}

// ---------------------------------------------------------------------------
// K3: initial LN partial-stats (layer 0): raw (s, sq) into slot h=0, zero rest.
// stats layout: [row][12][2] floats.
// ---------------------------------------------------------------------------
__global__ __launch_bounds__(256) void k_lnstats0(
    const float* __restrict__ tok, float* __restrict__ stats_out)
{
    int tid = threadIdx.x, lane = tid & 63, wave = tid >> 6;
    int row = blockIdx.x * 4 + wave;          // NTOK = 4*1576 exact
    const float* p = tok + (long)row * HDIM;
    float s = 0.f, sq = 0.f;
    #pragma unroll
    for (int k = 0; k < 3; k++) {
        float4 v = *(const float4*)&p[k * 256 + lane * 4];
        s += v.x + v.y + v.z + v.w;
        sq += v.x * v.x + v.y * v.y + v.z * v.z + v.w * v.w;
    }
    #pragma unroll
    for (int off = 1; off < 64; off <<= 1) {
        s += __shfl_xor(s, off);
        sq += __shfl_xor(sq, off);
    }
    float* sp = &stats_out[(long)row * 24];
    if (lane == 0) { sp[0] = s; sp[1] = sq; }
    if (lane >= 2 && lane < 24) sp[lane] = 0.f;
}

// ---------------------------------------------------------------------------
// K4: FUSED transformer layer — 512 threads = 8 waves (2 waves/SIMD for
// latency hiding; 13 strips over 8 waves = 2-strip critical path).
// One block per (n,h): grid (12, 32).
// ---------------------------------------------------------------------------
__global__ __launch_bounds__(512, 1) void k_layer(
    float* __restrict__ tok,
    const float* __restrict__ stats_in, float* __restrict__ stats_out,
    const float* __restrict__ lng, const float* __restrict__ lnb,
    const ushort* __restrict__ wqs, const float* __restrict__ bqp,
    const ushort* __restrict__ wks, const float* __restrict__ bkp,
    const ushort* __restrict__ wvs, const float* __restrict__ bvp)
{
    __shared__ __align__(16) ushort Wl[3][4096];   // 24 KB frag-order weights
    __shared__ __align__(16) ushort xh[208 * 72];  // LN'd tokens -> later Q
    __shared__ __align__(16) ushort Ks[208 * 72];
    __shared__ __align__(16) ushort Vt[64 * 232];
    __shared__ __align__(16) ushort Ps[8][16 * 40];
    __shared__ float smu[208], srstd[208];
    __shared__ float bias[3][64];

    int h = blockIdx.x, n = blockIdx.y;
    int tid = threadIdx.x, lane = tid & 63, wave = tid >> 6;   // wave 0..7
    int col = lane & 15, quad = lane >> 4;
    f32x4 zero4 = {0.f, 0.f, 0.f, 0.f};

    // ---- phase 1: weights (async), bias, per-row stats reduce ----
    const ushort* wsz0 = wqs + (long)h * 4096;
    const ushort* wsz1 = wks + (long)h * 4096;
    const ushort* wsz2 = wvs + (long)h * 4096;
    {
        int c = wave;                     // 8 chunks of 512 per array
        gload_lds16(&wsz0[c * 512 + lane * 8], &Wl[0][c * 512]);
        gload_lds16(&wsz1[c * 512 + lane * 8], &Wl[1][c * 512]);
        gload_lds16(&wsz2[c * 512 + lane * 8], &Wl[2][c * 512]);
    }
    if (tid < 192) {
        int m = tid >> 6, e = tid & 63;
        bias[m][e] = ((m == 0) ? bqp : (m == 1) ? bkp : bvp)[h * 64 + e];
    }
    for (int r = tid; r < SEQ; r += 512) {
        const float* sp = &stats_in[((long)n * SEQ + r) * 24];
        float s = 0.f, sq = 0.f;
        #pragma unroll
        for (int j = 0; j < 6; j++) {
            float4 v = *(const float4*)&sp[j * 4];
            s += v.x + v.z;
            sq += v.y + v.w;
        }
        float mu = s / 768.f;
        smu[r] = mu;
        srstd[r] = rsqrtf(sq / 768.f - mu * mu + EPSF);
    }
    // zero Vt pad columns t in [208,232)
    for (int i = tid; i < 64 * 24; i += 512) {
        int e = i / 24, t = 208 + i % 24;
        Vt[e * 232 + t] = 0;
    }
    __syncthreads();

    // ---- phase 2: xh = bf16(LN(tok head-slice)) ----
    for (int i = tid; i < 208 * 16; i += 512) {
        int r = i >> 4, c4 = i & 15;
        ushort4 u = {0, 0, 0, 0};
        if (r < SEQ) {
            float4 v = *(const float4*)&tok[((long)n * SEQ + r) * HDIM + h * 64 + c4 * 4];
            float mu = smu[r], rstd = srstd[r];
            int d = c4 * 4;
            const float* g = &lng[h * 64 + d];
            const float* bb = &lnb[h * 64 + d];
            u.x = f2bf((v.x - mu) * rstd * g[0] + bb[0]);
            u.y = f2bf((v.y - mu) * rstd * g[1] + bb[1]);
            u.z = f2bf((v.z - mu) * rstd * g[2] + bb[2]);
            u.w = f2bf((v.w - mu) * rstd * g[3] + bb[3]);
        }
        *(ushort4*)&xh[r * 72 + c4 * 4] = u;
    }
    __syncthreads();   // xh visible; Wl gloads drained

    // ---- phase 3: QKV per strip (st = sl*8 + wave) ----
    #pragma unroll
    for (int sl = 0; sl < 2; sl++) {
        int st = sl * 8 + wave;
        if (st < 13) {
            int q0 = st * 16;
            short8 a[2];
            a[0] = *(const short8*)&xh[(q0 + col) * 72 + quad * 8];
            a[1] = *(const short8*)&xh[(q0 + col) * 72 + 32 + quad * 8];
            #pragma unroll
            for (int m = 0; m < 3; m++) {
                f32x4 acc[4] = {zero4, zero4, zero4, zero4};
                #pragma unroll
                for (int kt = 0; kt < 2; kt++)
                    #pragma unroll
                    for (int nt = 0; nt < 4; nt++) {
                        short8 b = *(const short8*)&Wl[m][(kt * 4 + nt) * 512 + lane * 8];
                        acc[nt] = __builtin_amdgcn_mfma_f32_16x16x32_bf16(a[kt], b, acc[nt], 0, 0, 0);
                    }
                if (m == 0) {
                    // Q written back into xh rows (this wave owns these rows;
                    // A-frags already in regs)
                    #pragma unroll
                    for (int nt = 0; nt < 4; nt++)
                        #pragma unroll
                        for (int r = 0; r < 4; r++)
                            xh[(q0 + quad * 4 + r) * 72 + nt * 16 + col] =
                                f2bf(acc[nt][r] + bias[0][nt * 16 + col]);
                } else if (m == 1) {
                    #pragma unroll
                    for (int nt = 0; nt < 4; nt++)
                        #pragma unroll
                        for (int r = 0; r < 4; r++)
                            Ks[(q0 + quad * 4 + r) * 72 + nt * 16 + col] =
                                f2bf(acc[nt][r] + bias[1][nt * 16 + col]);
                } else {
                    #pragma unroll
                    for (int nt = 0; nt < 4; nt++)
                        #pragma unroll
                        for (int r = 0; r < 4; r++)
                            Vt[(nt * 16 + col) * 232 + q0 + quad * 4 + r] =
                                f2bf(acc[nt][r] + bias[2][nt * 16 + col]);
                }
            }
        }
    }
    __syncthreads();   // K, V, Q all staged

    // ---- phase 4: attention per strip ----
    ushort* myP = &Ps[wave][0];
    #pragma unroll
    for (int sl = 0; sl < 2; sl++) {
        int st = sl * 8 + wave;
        if (st >= 13) continue;
        int q0 = st * 16;
        short8 aq[2];
        aq[0] = *(const short8*)&xh[(q0 + col) * 72 + quad * 8];
        aq[1] = *(const short8*)&xh[(q0 + col) * 72 + 32 + quad * 8];

        // scores: 13 key tiles x 2 MFMAs
        f32x4 sc[13];
        #pragma unroll
        for (int tt = 0; tt < 13; tt++) sc[tt] = zero4;
        #pragma unroll
        for (int tt = 0; tt < 13; tt++) {
            #pragma unroll
            for (int dt = 0; dt < 2; dt++) {
                short8 bk = *(const short8*)&Ks[(tt * 16 + col) * 72 + dt * 32 + quad * 8];
                sc[tt] = __builtin_amdgcn_mfma_f32_16x16x32_bf16(aq[dt], bk, sc[tt], 0, 0, 0);
            }
        }

        // softmax (rows = quad*4+r; key = tt*16+col, mask >=197 in tile 12)
        float rinv[4];
        #pragma unroll
        for (int r = 0; r < 4; r++) {
            float m = -1e30f;
            #pragma unroll
            for (int tt = 0; tt < 12; tt++) m = fmaxf(m, sc[tt][r]);
            if (col < 5) m = fmaxf(m, sc[12][r]);
            #pragma unroll
            for (int off = 1; off < 16; off <<= 1) m = fmaxf(m, __shfl_xor(m, off));
            float s = 0.f;
            #pragma unroll
            for (int tt = 0; tt < 12; tt++) {
                float e = __expf((sc[tt][r] - m) * SCALE);
                sc[tt][r] = e; s += e;
            }
            float e12 = (col < 5) ? __expf((sc[12][r] - m) * SCALE) : 0.f;
            sc[12][r] = e12; s += e12;
            #pragma unroll
            for (int off = 1; off < 16; off <<= 1) s += __shfl_xor(s, off);
            rinv[r] = 1.f / s;
        }

        // P @ V
        f32x4 oacc[4];
        #pragma unroll
        for (int nt = 0; nt < 4; nt++) oacc[nt] = zero4;
        #pragma unroll
        for (int kt = 0; kt < 7; kt++) {
            #pragma unroll
            for (int half = 0; half < 2; half++) {
                int tt = kt * 2 + half;
                #pragma unroll
                for (int r = 0; r < 4; r++) {
                    float v = (tt < 13) ? sc[tt][r] : 0.f;
                    myP[(quad * 4 + r) * 40 + half * 16 + col] = f2bf(v);
                }
            }
            short8 pa = *(const short8*)&myP[col * 40 + quad * 8];
            #pragma unroll
            for (int nt = 0; nt < 4; nt++) {
                short8 vb = *(const short8*)&Vt[(nt * 16 + col) * 232 + kt * 32 + quad * 8];
                oacc[nt] = __builtin_amdgcn_mfma_f32_16x16x32_bf16(pa, vb, oacc[nt], 0, 0, 0);
            }
        }

        // residual RMW + next-layer partial stats for this 64-col slice
        #pragma unroll
        for (int r = 0; r < 4; r++) {
            int row = q0 + quad * 4 + r;
            float s = 0.f, sq = 0.f;
            if (row < SEQ) {
                float rv = rinv[r];
                #pragma unroll
                for (int nt = 0; nt < 4; nt++) {
                    long o = ((long)n * SEQ + row) * HDIM + h * 64 + nt * 16 + col;
                    float nv = tok[o] + oacc[nt][r] * rv;
                    tok[o] = nv;
                    s += nv; sq += nv * nv;
                }
            }
            #pragma unroll
            for (int off = 1; off < 16; off <<= 1) {
                s += __shfl_xor(s, off);
                sq += __shfl_xor(sq, off);
            }
            if (row < SEQ && col == 0) {
                float* sp = &stats_out[((long)n * SEQ + row) * 24 + h * 2];
                sp[0] = s; sp[1] = sq;
            }
        }
    }
}

// ---------------------------------------------------------------------------
// K6a: logits GEMM, fp32, wave-cooperative. grid (32 n, 8 ochunks).
// ---------------------------------------------------------------------------
__global__ __launch_bounds__(256) void k_logits(
    const float* __restrict__ tok, const float* __restrict__ W,
    const float* __restrict__ b, float* __restrict__ logits)
{
    int n = blockIdx.x, oc = blockIdx.y;
    int tid = threadIdx.x, lane = tid & 63, wave = tid >> 6;
    const float* cp = &tok[(long)n * SEQ * HDIM];
    float4 c0 = *(const float4*)&cp[lane * 4];
    float4 c1 = *(const float4*)&cp[256 + lane * 4];
    float4 c2 = *(const float4*)&cp[512 + lane * 4];
    int obeg = oc * 125, oend = obeg + 125;
    for (int o = obeg + wave; o < oend; o += 4) {
        const float* wr = &W[(long)o * HDIM];
        float4 w0 = *(const float4*)&wr[lane * 4];
        float4 w1 = *(const float4*)&wr[256 + lane * 4];
        float4 w2 = *(const float4*)&wr[512 + lane * 4];
        float s = c0.x * w0.x + c0.y * w0.y + c0.z * w0.z + c0.w * w0.w
                + c1.x * w1.x + c1.y * w1.y + c1.z * w1.z + c1.w * w1.w
                + c2.x * w2.x + c2.y * w2.y + c2.z * w2.z + c2.w * w2.w;
        #pragma unroll
        for (int off = 1; off < 64; off <<= 1) s += __shfl_xor(s, off);
        if (lane == 0) logits[n * NOUT + o] = s + b[o];
    }
}

// ---------------------------------------------------------------------------
// K6b: softmax over 1000 logits per image
// ---------------------------------------------------------------------------
__global__ __launch_bounds__(256) void k_smax(
    const float* __restrict__ logits, float* __restrict__ out)
{
    __shared__ float lg[NOUT];
    __shared__ float red[256];
    int n = blockIdx.x, tid = threadIdx.x;
    for (int o = tid; o < NOUT; o += 256) lg[o] = logits[n * NOUT + o];
    __syncthreads();
    float m = -1e30f;
    for (int o = tid; o < NOUT; o += 256) m = fmaxf(m, lg[o]);
    red[tid] = m; __syncthreads();
    for (int off = 128; off > 0; off >>= 1) {
        if (tid < off) red[tid] = fmaxf(red[tid], red[tid + off]);
        __syncthreads();
    }
    float mx = red[0];
    __syncthreads();
    float s = 0.f;
    for (int o = tid; o < NOUT; o += 256) {
        float e = __expf(lg[o] - mx);
        lg[o] = e; s += e;
    }
    red[tid] = s; __syncthreads();
    for (int off = 128; off > 0; off >>= 1) {
        if (tid < off) red[tid] += red[tid + off];
        __syncthreads();
    }
    float inv = 1.f / red[0];
    for (int o = tid; o < NOUT; o += 256) out[(long)n * NOUT + o] = lg[o] * inv;
}

// ---------------------------------------------------------------------------
extern "C" void kernel_launch(void* const* d_in, const int* in_sizes, int n_in,
                              void* d_out, int out_size, void* d_ws, size_t ws_size,
                              hipStream_t stream)
{
    const float* images  = (const float*)d_in[0];
    const float* conv_w  = (const float*)d_in[1];
    const float* conv_b  = (const float*)d_in[2];
    const float* bn_g    = (const float*)d_in[3];
    const float* bn_b    = (const float*)d_in[4];
    const float* bn_m    = (const float*)d_in[5];
    const float* bn_v    = (const float*)d_in[6];
    const float* map_w   = (const float*)d_in[7];
    const float* map_b   = (const float*)d_in[8];
    const float* cls_tok = (const float*)d_in[9];
    const float* ln_g    = (const float*)d_in[10];
    const float* ln_b    = (const float*)d_in[11];
    const float* wq      = (const float*)d_in[12];
    const float* bq      = (const float*)d_in[13];
    const float* wk      = (const float*)d_in[14];
    const float* bk      = (const float*)d_in[15];
    const float* wv      = (const float*)d_in[16];
    const float* bv      = (const float*)d_in[17];
    const float* mlp_w   = (const float*)d_in[18];
    const float* mlp_b   = (const float*)d_in[19];
    float* out = (float*)d_out;

    const long SZ_X   = (long)NPATCH * IND;       // ushorts
    const long SZ_W   = (long)HDIM * IND;         // ushorts
    const long SZ_WS  = (long)3 * 144 * 4096;     // ushorts
    const long SZ_POS = (long)SEQ * HDIM;         // floats
    const long SZ_TOK = (long)NTOK * HDIM;        // floats
    const long SZ_ST  = (long)NTOK * 24;          // floats

    ushort* Xbf   = (ushort*)d_ws;
    ushort* Wbf   = Xbf + SZ_X;
    ushort* Wswz  = Wbf + SZ_W;
    float*  pos   = (float*)(Wswz + SZ_WS);
    float*  tok   = pos + SZ_POS;
    float*  sta   = tok + SZ_TOK;
    float*  stb   = sta + SZ_ST;
    float* logits = (float*)Xbf;                  // Xbf dead after k_embed

    k_cvt<<<600, 256, 0, stream>>>(map_w, Wbf, (int)(SZ_W / 4));
    k_cvtw<<<(3 * 144 * 512 + 255) / 256, 256, 0, stream>>>(wq, wk, wv, Wswz);
    k_pos<<<SEQ, 256, 0, stream>>>(pos);
    k_conv_patch<<<NPATCH / 2, 320, 0, stream>>>(images, conv_w, conv_b, bn_g,
                                                 bn_b, bn_m, bn_v, Xbf);
    k_cls<<<BB, 256, 0, stream>>>(cls_tok, pos, tok);
    dim3 ge(49, 12);
    k_embed<<<ge, 256, 0, stream>>>(Xbf, Wbf, map_b, pos, tok);

    k_lnstats0<<<NTOK / 4, 256, 0, stream>>>(tok, sta);
    for (int l = 0; l < LLAYERS; l++) {
        float* srd = (l & 1) ? stb : sta;
        float* swr = (l & 1) ? sta : stb;
        dim3 gl(12, 32);
        k_layer<<<gl, 512, 0, stream>>>(tok, srd, swr,
            ln_g + (long)l * HDIM, ln_b + (long)l * HDIM,
            Wswz + (long)(0 * 144 + l * 12) * 4096, bq + (long)l * NHEAD * DHEAD,
            Wswz + (long)(1 * 144 + l * 12) * 4096, bk + (long)l * NHEAD * DHEAD,
            Wswz + (long)(2 * 144 + l * 12) * 4096, bv + (long)l * NHEAD * DHEAD);
    }
    dim3 glo(BB, 8);
    k_logits<<<glo, 256, 0, stream>>>(tok, mlp_w, mlp_b, logits);
    k_smax<<<BB, 256, 0, stream>>>(logits, out);
}

// Round 8
// 523.066 us; speedup vs baseline: 7.3655x; 1.1939x over previous
//
#include <hip/hip_runtime.h>

#define BB 32
#define LLAYERS 12
#define HDIM 768
#define NHEAD 12
#define DHEAD 64
#define SEQ 197
#define IND 800
#define NOUT 1000
#define EPSF 1e-5f
#define NTOK (BB * SEQ)     // 6304
#define NPATCH (BB * 196)   // 6272
#define SCALE 0.125f        // 1/sqrt(64)

typedef __attribute__((ext_vector_type(4))) float f32x4;
typedef __attribute__((ext_vector_type(8))) short short8;

static __device__ __forceinline__ ushort f2bf(float f) {
    union { float f; unsigned u; } v; v.f = f;
    unsigned r = v.u + 0x7FFFu + ((v.u >> 16) & 1u);   // round-to-nearest-even
    return (ushort)(r >> 16);
}

static __device__ __forceinline__ void gload_lds16(const void* g, void* l) {
    __builtin_amdgcn_global_load_lds(
        (const __attribute__((address_space(1))) void*)g,
        (__attribute__((address_space(3))) void*)l, 16, 0, 0);
}

// ---------------------------------------------------------------------------
// K0a: convert map_w fp32 -> bf16
// ---------------------------------------------------------------------------
__global__ __launch_bounds__(256) void k_cvt(
    const float* __restrict__ s, ushort* __restrict__ d, int n4)
{
    int i = blockIdx.x * 256 + threadIdx.x;
    if (i < n4) {
        float4 v = *(const float4*)&s[i * 4];
        ushort4 u = {f2bf(v.x), f2bf(v.y), f2bf(v.z), f2bf(v.w)};
        *(ushort4*)&d[i * 4] = u;
    }
}

// ---------------------------------------------------------------------------
// K0b: convert wq/wk/wv fp32 -> bf16 in MFMA B-frag order.
// ---------------------------------------------------------------------------
__global__ __launch_bounds__(256) void k_cvtw(
    const float* __restrict__ wq, const float* __restrict__ wk,
    const float* __restrict__ wv, ushort* __restrict__ dst)
{
    int t = blockIdx.x * 256 + threadIdx.x;
    if (t >= 3 * 144 * 512) return;
    int lane = t & 63;
    int rest = t >> 6;
    int ktnt = rest & 7;
    int mlh = rest >> 3;
    int h = mlh % 12, ml = mlh / 12;
    int l = ml % 12, m = ml / 12;
    int nt = ktnt & 3, kt = ktnt >> 2;
    int e = nt * 16 + (lane & 15);
    int d = kt * 32 + (lane >> 4) * 8;
    const float* src = ((m == 0) ? wq : (m == 1) ? wk : wv)
                       + (((long)l * 12 + h) * 64 + e) * 64 + d;
    float4 a = *(const float4*)src;
    float4 b = *(const float4*)(src + 4);
    short8 u;
    u[0] = (short)f2bf(a.x); u[1] = (short)f2bf(a.y);
    u[2] = (short)f2bf(a.z); u[3] = (short)f2bf(a.w);
    u[4] = (short)f2bf(b.x); u[5] = (short)f2bf(b.y);
    u[6] = (short)f2bf(b.z); u[7] = (short)f2bf(b.w);
    *(short8*)&dst[(long)mlh * 4096 + ktnt * 512 + lane * 8] = u;
}

// ---------------------------------------------------------------------------
// K0c: sinusoidal pos-emb table [SEQ][HDIM]
// ---------------------------------------------------------------------------
__global__ __launch_bounds__(256) void k_pos(float* __restrict__ pos)
{
    int s = blockIdx.x;
    for (int e = threadIdx.x; e < HDIM; e += 256) {
        float freq = expf((float)(e & ~1) * (-9.210340371976184f / 768.0f));
        float ang = (float)s * freq;
        pos[s * HDIM + e] = (e & 1) ? cosf(ang) : sinf(ang);
    }
}

// ---------------------------------------------------------------------------
// K1: conv + BN + ReLU + patchify -> Xbf. 2 patches/block, 320 threads.
// ---------------------------------------------------------------------------
__global__ __launch_bounds__(320) void k_conv_patch(
    const float* __restrict__ img, const float* __restrict__ cw,
    const float* __restrict__ cb, const float* __restrict__ bg,
    const float* __restrict__ bbias, const float* __restrict__ bm,
    const float* __restrict__ bvv, ushort* __restrict__ X)
{
    __shared__ float tile[2][3][21][21];
    __shared__ float w[2400];
    __shared__ float scale[32], shift[32];
    int tid = threadIdx.x;

    for (int i = tid; i < 2400; i += 320) w[i] = cw[i];
    if (tid < 32) {
        float sc = bg[tid] * rsqrtf(bvv[tid] + EPSF);
        scale[tid] = sc;
        shift[tid] = (cb[tid] - bm[tid]) * sc + bbias[tid];
    }
    for (int i = tid; i < 2 * 3 * 441; i += 320) {
        int pp = i / 1323, j = i % 1323;
        int c = j / 441, r = (j / 21) % 21, cc = j % 21;
        int gp = blockIdx.x * 2 + pp;
        int n = gp / 196, p = gp % 196;
        int h0 = (p / 14) * 20 - 1, w0 = (p % 14) * 20 - 1;
        int gh = h0 + r, gw = w0 + cc;
        float v = 0.f;
        if (gh >= 0 && gh < 280 && gw >= 0 && gw < 280)
            v = img[((long)(n * 3 + c) * 280 + gh) * 280 + gw];
        tile[pp][c][r][cc] = v;
    }
    __syncthreads();

    int pp = tid / 160, u = tid % 160;
    int c = u / 5, ph = u % 5;
    float acc[5] = {0.f, 0.f, 0.f, 0.f, 0.f};
    const float* wp = &w[c * 75];
    #pragma unroll
    for (int ci = 0; ci < 3; ci++) {
        #pragma unroll
        for (int kh = 0; kh < 5; kh++) {
            const float* row = &tile[pp][ci][ph * 4 + kh][0];
            float rv[21];
            #pragma unroll
            for (int j = 0; j < 21; j++) rv[j] = row[j];
            #pragma unroll
            for (int kw = 0; kw < 5; kw++) {
                float wv = wp[ci * 25 + kh * 5 + kw];
                #pragma unroll
                for (int pw = 0; pw < 5; pw++)
                    acc[pw] += rv[pw * 4 + kw] * wv;
            }
        }
    }
    int gp = blockIdx.x * 2 + pp;
    long ob = (long)gp * 800 + c * 25 + ph * 5;
    #pragma unroll
    for (int pw = 0; pw < 5; pw++) {
        float val = acc[pw] * scale[c] + shift[c];
        X[ob + pw] = f2bf(fmaxf(val, 0.f));
    }
}

__global__ void k_cls(const float* __restrict__ cls_tok,
                      const float* __restrict__ pos, float* __restrict__ tok)
{
    int n = blockIdx.x, tid = threadIdx.x;
    for (int e = tid; e < HDIM; e += 256)
        tok[(long)n * SEQ * HDIM + e] = cls_tok[e] + pos[e];
}

// ---------------------------------------------------------------------------
// K2: patch embed GEMM, bf16 MFMA
// ---------------------------------------------------------------------------
__global__ __launch_bounds__(256, 2) void k_embed(
    const ushort* __restrict__ Xg, const ushort* __restrict__ Wg,
    const float* __restrict__ bias, const float* __restrict__ pos,
    float* __restrict__ tok)
{
    __shared__ __align__(16) ushort As[128 * 32];
    __shared__ __align__(16) ushort Bs[64 * 32];
    int m0 = blockIdx.x * 128, e0 = blockIdx.y * 64;
    int tid = threadIdx.x, lane = tid & 63, wave = tid >> 6;
    int col = lane & 15, quad = lane >> 4;
    int wm = (wave & 1) * 64, wn = (wave >> 1) * 32;
    int lr = lane >> 2, lc = (lane & 3) * 8;
    f32x4 zero4 = {0.f, 0.f, 0.f, 0.f};
    f32x4 acc[4][2];
    #pragma unroll
    for (int mt = 0; mt < 4; mt++)
        #pragma unroll
        for (int nt = 0; nt < 2; nt++) acc[mt][nt] = zero4;

    for (int k0 = 0; k0 < 800; k0 += 32) {
        __syncthreads();
        #pragma unroll
        for (int i = 0; i < 2; i++) {
            int c = wave * 2 + i;
            gload_lds16(&Xg[(long)(m0 + c * 16 + lr) * 800 + k0 + lc], &As[c * 512]);
        }
        {
            int c = wave;
            gload_lds16(&Wg[(long)(e0 + c * 16 + lr) * 800 + k0 + lc], &Bs[c * 512]);
        }
        __syncthreads();
        short8 a[4], b[2];
        #pragma unroll
        for (int mt = 0; mt < 4; mt++)
            a[mt] = *(const short8*)&As[(wm + mt * 16 + col) * 32 + quad * 8];
        #pragma unroll
        for (int nt = 0; nt < 2; nt++)
            b[nt] = *(const short8*)&Bs[(wn + nt * 16 + col) * 32 + quad * 8];
        #pragma unroll
        for (int mt = 0; mt < 4; mt++)
            #pragma unroll
            for (int nt = 0; nt < 2; nt++)
                acc[mt][nt] = __builtin_amdgcn_mfma_f32_16x16x32_bf16(a[mt], b[nt], acc[mt][nt], 0, 0, 0);
    }
    #pragma unroll
    for (int mt = 0; mt < 4; mt++) {
        #pragma unroll
        for (int r = 0; r < 4; r++) {
            int m = m0 + wm + mt * 16 + quad * 4 + r;
            int n = m / 196, s = m - n * 196 + 1;
            long rowb = ((long)n * SEQ + s) * HDIM;
            #pragma unroll
            for (int nt = 0; nt < 2; nt++) {
                int e = e0 + wn + nt * 16 + col;
                tok[rowb + e] = acc[mt][nt][r] + bias[e] + pos[s * HDIM + e];
            }
        }
    }
}

// ---------------------------------------------------------------------------
// K3: initial LN partial-stats (layer 0)
// ---------------------------------------------------------------------------
__global__ __launch_bounds__(256) void k_lnstats0(
    const float* __restrict__ tok, float* __restrict__ stats_out)
{
    int tid = threadIdx.x, lane = tid & 63, wave = tid >> 6;
    int row = blockIdx.x * 4 + wave;          // NTOK = 4*1576 exact
    const float* p = tok + (long)row * HDIM;
    float s = 0.f, sq = 0.f;
    #pragma unroll
    for (int k = 0; k < 3; k++) {
        float4 v = *(const float4*)&p[k * 256 + lane * 4];
        s += v.x + v.y + v.z + v.w;
        sq += v.x * v.x + v.y * v.y + v.z * v.z + v.w * v.w;
    }
    #pragma unroll
    for (int off = 1; off < 64; off <<= 1) {
        s += __shfl_xor(s, off);
        sq += __shfl_xor(sq, off);
    }
    float* sp = &stats_out[(long)row * 24];
    if (lane == 0) { sp[0] = s; sp[1] = sq; }
    if (lane >= 2 && lane < 24) sp[lane] = 0.f;
}

// ---------------------------------------------------------------------------
// K4: FUSED transformer layer — 512 thr = 8 waves, 2 blocks/CU (~81 KB LDS).
// No xh (LN computed into A-frag regs per owning wave), no Wl (B-frags from
// pre-swizzled global, L2-broadcast). One block per (n,h): grid (12, 32).
// ---------------------------------------------------------------------------
__global__ __launch_bounds__(512, 4) void k_layer(
    float* __restrict__ tok,
    const float* __restrict__ stats_in, float* __restrict__ stats_out,
    const float* __restrict__ lng, const float* __restrict__ lnb,
    const ushort* __restrict__ wqs, const float* __restrict__ bqp,
    const ushort* __restrict__ wks, const float* __restrict__ bkp,
    const ushort* __restrict__ wvs, const float* __restrict__ bvp)
{
    __shared__ __align__(16) ushort Ks[208 * 72];   // 29.9 KB
    __shared__ __align__(16) ushort Vt[64 * 232];   // 29.7 KB
    __shared__ __align__(16) ushort Ps[8][16 * 72]; // 18.4 KB per-wave scratch
    __shared__ float smu[208], srstd[208];
    __shared__ float bias[3][64];
    __shared__ float lngs[64], lnbs[64];

    int h = blockIdx.x, n = blockIdx.y;
    int tid = threadIdx.x, lane = tid & 63, wave = tid >> 6;   // wave 0..7
    int col = lane & 15, quad = lane >> 4;
    f32x4 zero4 = {0.f, 0.f, 0.f, 0.f};

    // ---- phase 1: bias + ln params + per-row stats reduce + Vt pad ----
    if (tid < 192) {
        int m = tid >> 6, e = tid & 63;
        bias[m][e] = ((m == 0) ? bqp : (m == 1) ? bkp : bvp)[h * 64 + e];
    } else if (tid < 256) {
        lngs[tid - 192] = lng[h * 64 + tid - 192];
    } else if (tid < 320) {
        lnbs[tid - 256] = lnb[h * 64 + tid - 256];
    }
    for (int r = tid; r < SEQ; r += 512) {
        const float* sp = &stats_in[((long)n * SEQ + r) * 24];
        float s = 0.f, sq = 0.f;
        #pragma unroll
        for (int j = 0; j < 6; j++) {
            float4 v = *(const float4*)&sp[j * 4];
            s += v.x + v.z;
            sq += v.y + v.w;
        }
        float mu = s / 768.f;
        smu[r] = mu;
        srstd[r] = rsqrtf(sq / 768.f - mu * mu + EPSF);
    }
    for (int i = tid; i < 64 * 24; i += 512) {
        int e = i / 24, t = 208 + i % 24;
        Vt[e * 232 + t] = 0;
    }
    __syncthreads();

    // ---- phase 2: per-wave LN -> A-frag registers (strips st = sl*8+wave) --
    long tokb = (long)n * SEQ * HDIM + h * 64;
    short8 a[2][2];
    #pragma unroll
    for (int sl = 0; sl < 2; sl++) {
        int st = sl * 8 + wave;
        if (st >= 13) continue;
        int row = st * 16 + col; if (row > SEQ - 1) row = SEQ - 1;
        float mu = smu[row], rs = srstd[row];
        #pragma unroll
        for (int kt = 0; kt < 2; kt++) {
            const float* tp = &tok[tokb + (long)row * HDIM + kt * 32 + quad * 8];
            float4 v0 = *(const float4*)tp;
            float4 v1 = *(const float4*)(tp + 4);
            const float* g = &lngs[kt * 32 + quad * 8];
            const float* bb = &lnbs[kt * 32 + quad * 8];
            short8 u;
            u[0] = (short)f2bf((v0.x - mu) * rs * g[0] + bb[0]);
            u[1] = (short)f2bf((v0.y - mu) * rs * g[1] + bb[1]);
            u[2] = (short)f2bf((v0.z - mu) * rs * g[2] + bb[2]);
            u[3] = (short)f2bf((v0.w - mu) * rs * g[3] + bb[3]);
            u[4] = (short)f2bf((v1.x - mu) * rs * g[4] + bb[4]);
            u[5] = (short)f2bf((v1.y - mu) * rs * g[5] + bb[5]);
            u[6] = (short)f2bf((v1.z - mu) * rs * g[6] + bb[6]);
            u[7] = (short)f2bf((v1.w - mu) * rs * g[7] + bb[7]);
            a[sl][kt] = u;
        }
    }

    // ---- phase 3: QKV (B-frags from global; Q -> aq regs via Ps scratch) ---
    ushort* myP = &Ps[wave][0];
    short8 aq[2][2];
    #pragma unroll
    for (int m = 0; m < 3; m++) {
        const ushort* wp = ((m == 0) ? wqs : (m == 1) ? wks : wvs) + (long)h * 4096;
        short8 b[8];
        #pragma unroll
        for (int f = 0; f < 8; f++)
            b[f] = *(const short8*)&wp[f * 512 + lane * 8];
        #pragma unroll
        for (int sl = 0; sl < 2; sl++) {
            int st = sl * 8 + wave;
            if (st >= 13) continue;
            int q0 = st * 16;
            f32x4 acc[4] = {zero4, zero4, zero4, zero4};
            #pragma unroll
            for (int kt = 0; kt < 2; kt++)
                #pragma unroll
                for (int nt = 0; nt < 4; nt++)
                    acc[nt] = __builtin_amdgcn_mfma_f32_16x16x32_bf16(a[sl][kt], b[kt * 4 + nt], acc[nt], 0, 0, 0);
            if (m == 0) {
                // C-layout -> Ps -> A-layout registers (wave-private)
                #pragma unroll
                for (int nt = 0; nt < 4; nt++)
                    #pragma unroll
                    for (int r = 0; r < 4; r++)
                        myP[(quad * 4 + r) * 72 + nt * 16 + col] =
                            f2bf(acc[nt][r] + bias[0][nt * 16 + col]);
                #pragma unroll
                for (int kt = 0; kt < 2; kt++)
                    aq[sl][kt] = *(const short8*)&myP[col * 72 + kt * 32 + quad * 8];
            } else if (m == 1) {
                #pragma unroll
                for (int nt = 0; nt < 4; nt++)
                    #pragma unroll
                    for (int r = 0; r < 4; r++)
                        Ks[(q0 + quad * 4 + r) * 72 + nt * 16 + col] =
                            f2bf(acc[nt][r] + bias[1][nt * 16 + col]);
            } else {
                #pragma unroll
                for (int nt = 0; nt < 4; nt++)
                    #pragma unroll
                    for (int r = 0; r < 4; r++)
                        Vt[(nt * 16 + col) * 232 + q0 + quad * 4 + r] =
                            f2bf(acc[nt][r] + bias[2][nt * 16 + col]);
            }
        }
    }
    __syncthreads();   // K, V staged across waves

    // ---- phase 4: attention per strip ----
    #pragma unroll
    for (int sl = 0; sl < 2; sl++) {
        int st = sl * 8 + wave;
        if (st >= 13) continue;
        int q0 = st * 16;

        // scores: 13 key tiles x 2 MFMAs
        f32x4 sc[13];
        #pragma unroll
        for (int tt = 0; tt < 13; tt++) sc[tt] = zero4;
        #pragma unroll
        for (int tt = 0; tt < 13; tt++) {
            #pragma unroll
            for (int dt = 0; dt < 2; dt++) {
                short8 bk = *(const short8*)&Ks[(tt * 16 + col) * 72 + dt * 32 + quad * 8];
                sc[tt] = __builtin_amdgcn_mfma_f32_16x16x32_bf16(aq[sl][dt], bk, sc[tt], 0, 0, 0);
            }
        }

        // softmax (rows = quad*4+r; key = tt*16+col, mask >=197 in tile 12)
        float rinv[4];
        #pragma unroll
        for (int r = 0; r < 4; r++) {
            float m = -1e30f;
            #pragma unroll
            for (int tt = 0; tt < 12; tt++) m = fmaxf(m, sc[tt][r]);
            if (col < 5) m = fmaxf(m, sc[12][r]);
            #pragma unroll
            for (int off = 1; off < 16; off <<= 1) m = fmaxf(m, __shfl_xor(m, off));
            float s = 0.f;
            #pragma unroll
            for (int tt = 0; tt < 12; tt++) {
                float e = __expf((sc[tt][r] - m) * SCALE);
                sc[tt][r] = e; s += e;
            }
            float e12 = (col < 5) ? __expf((sc[12][r] - m) * SCALE) : 0.f;
            sc[12][r] = e12; s += e12;
            #pragma unroll
            for (int off = 1; off < 16; off <<= 1) s += __shfl_xor(s, off);
            rinv[r] = 1.f / s;
        }

        // P @ V
        f32x4 oacc[4];
        #pragma unroll
        for (int nt = 0; nt < 4; nt++) oacc[nt] = zero4;
        #pragma unroll
        for (int kt = 0; kt < 7; kt++) {
            #pragma unroll
            for (int half = 0; half < 2; half++) {
                int tt = kt * 2 + half;
                #pragma unroll
                for (int r = 0; r < 4; r++) {
                    float v = (tt < 13) ? sc[tt][r] : 0.f;
                    myP[(quad * 4 + r) * 72 + half * 16 + col] = f2bf(v);
                }
            }
            short8 pa = *(const short8*)&myP[col * 72 + quad * 8];
            #pragma unroll
            for (int nt = 0; nt < 4; nt++) {
                short8 vb = *(const short8*)&Vt[(nt * 16 + col) * 232 + kt * 32 + quad * 8];
                oacc[nt] = __builtin_amdgcn_mfma_f32_16x16x32_bf16(pa, vb, oacc[nt], 0, 0, 0);
            }
        }

        // residual RMW + next-layer partial stats for this 64-col slice
        #pragma unroll
        for (int r = 0; r < 4; r++) {
            int row = q0 + quad * 4 + r;
            float s = 0.f, sq = 0.f;
            if (row < SEQ) {
                float rv = rinv[r];
                #pragma unroll
                for (int nt = 0; nt < 4; nt++) {
                    long o = ((long)n * SEQ + row) * HDIM + h * 64 + nt * 16 + col;
                    float nv = tok[o] + oacc[nt][r] * rv;
                    tok[o] = nv;
                    s += nv; sq += nv * nv;
                }
            }
            #pragma unroll
            for (int off = 1; off < 16; off <<= 1) {
                s += __shfl_xor(s, off);
                sq += __shfl_xor(sq, off);
            }
            if (row < SEQ && col == 0) {
                float* sp = &stats_out[((long)n * SEQ + row) * 24 + h * 2];
                sp[0] = s; sp[1] = sq;
            }
        }
    }
}

// ---------------------------------------------------------------------------
// K6a: logits GEMM, fp32, wave-cooperative. grid (32 n, 8 ochunks).
// ---------------------------------------------------------------------------
__global__ __launch_bounds__(256) void k_logits(
    const float* __restrict__ tok, const float* __restrict__ W,
    const float* __restrict__ b, float* __restrict__ logits)
{
    int n = blockIdx.x, oc = blockIdx.y;
    int tid = threadIdx.x, lane = tid & 63, wave = tid >> 6;
    const float* cp = &tok[(long)n * SEQ * HDIM];
    float4 c0 = *(const float4*)&cp[lane * 4];
    float4 c1 = *(const float4*)&cp[256 + lane * 4];
    float4 c2 = *(const float4*)&cp[512 + lane * 4];
    int obeg = oc * 125, oend = obeg + 125;
    for (int o = obeg + wave; o < oend; o += 4) {
        const float* wr = &W[(long)o * HDIM];
        float4 w0 = *(const float4*)&wr[lane * 4];
        float4 w1 = *(const float4*)&wr[256 + lane * 4];
        float4 w2 = *(const float4*)&wr[512 + lane * 4];
        float s = c0.x * w0.x + c0.y * w0.y + c0.z * w0.z + c0.w * w0.w
                + c1.x * w1.x + c1.y * w1.y + c1.z * w1.z + c1.w * w1.w
                + c2.x * w2.x + c2.y * w2.y + c2.z * w2.z + c2.w * w2.w;
        #pragma unroll
        for (int off = 1; off < 64; off <<= 1) s += __shfl_xor(s, off);
        if (lane == 0) logits[n * NOUT + o] = s + b[o];
    }
}

// ---------------------------------------------------------------------------
// K6b: softmax over 1000 logits per image
// ---------------------------------------------------------------------------
__global__ __launch_bounds__(256) void k_smax(
    const float* __restrict__ logits, float* __restrict__ out)
{
    __shared__ float lg[NOUT];
    __shared__ float red[256];
    int n = blockIdx.x, tid = threadIdx.x;
    for (int o = tid; o < NOUT; o += 256) lg[o] = logits[n * NOUT + o];
    __syncthreads();
    float m = -1e30f;
    for (int o = tid; o < NOUT; o += 256) m = fmaxf(m, lg[o]);
    red[tid] = m; __syncthreads();
    for (int off = 128; off > 0; off >>= 1) {
        if (tid < off) red[tid] = fmaxf(red[tid], red[tid + off]);
        __syncthreads();
    }
    float mx = red[0];
    __syncthreads();
    float s = 0.f;
    for (int o = tid; o < NOUT; o += 256) {
        float e = __expf(lg[o] - mx);
        lg[o] = e; s += e;
    }
    red[tid] = s; __syncthreads();
    for (int off = 128; off > 0; off >>= 1) {
        if (tid < off) red[tid] += red[tid + off];
        __syncthreads();
    }
    float inv = 1.f / red[0];
    for (int o = tid; o < NOUT; o += 256) out[(long)n * NOUT + o] = lg[o] * inv;
}

// ---------------------------------------------------------------------------
extern "C" void kernel_launch(void* const* d_in, const int* in_sizes, int n_in,
                              void* d_out, int out_size, void* d_ws, size_t ws_size,
                              hipStream_t stream)
{
    const float* images  = (const float*)d_in[0];
    const float* conv_w  = (const float*)d_in[1];
    const float* conv_b  = (const float*)d_in[2];
    const float* bn_g    = (const float*)d_in[3];
    const float* bn_b    = (const float*)d_in[4];
    const float* bn_m    = (const float*)d_in[5];
    const float* bn_v    = (const float*)d_in[6];
    const float* map_w   = (const float*)d_in[7];
    const float* map_b   = (const float*)d_in[8];
    const float* cls_tok = (const float*)d_in[9];
    const float* ln_g    = (const float*)d_in[10];
    const float* ln_b    = (const float*)d_in[11];
    const float* wq      = (const float*)d_in[12];
    const float* bq      = (const float*)d_in[13];
    const float* wk      = (const float*)d_in[14];
    const float* bk      = (const float*)d_in[15];
    const float* wv      = (const float*)d_in[16];
    const float* bv      = (const float*)d_in[17];
    const float* mlp_w   = (const float*)d_in[18];
    const float* mlp_b   = (const float*)d_in[19];
    float* out = (float*)d_out;

    const long SZ_X   = (long)NPATCH * IND;       // ushorts
    const long SZ_W   = (long)HDIM * IND;         // ushorts
    const long SZ_WS  = (long)3 * 144 * 4096;     // ushorts
    const long SZ_POS = (long)SEQ * HDIM;         // floats
    const long SZ_TOK = (long)NTOK * HDIM;        // floats
    const long SZ_ST  = (long)NTOK * 24;          // floats

    ushort* Xbf   = (ushort*)d_ws;
    ushort* Wbf   = Xbf + SZ_X;
    ushort* Wswz  = Wbf + SZ_W;
    float*  pos   = (float*)(Wswz + SZ_WS);
    float*  tok   = pos + SZ_POS;
    float*  sta   = tok + SZ_TOK;
    float*  stb   = sta + SZ_ST;
    float* logits = (float*)Xbf;                  // Xbf dead after k_embed

    k_cvt<<<600, 256, 0, stream>>>(map_w, Wbf, (int)(SZ_W / 4));
    k_cvtw<<<(3 * 144 * 512 + 255) / 256, 256, 0, stream>>>(wq, wk, wv, Wswz);
    k_pos<<<SEQ, 256, 0, stream>>>(pos);
    k_conv_patch<<<NPATCH / 2, 320, 0, stream>>>(images, conv_w, conv_b, bn_g,
                                                 bn_b, bn_m, bn_v, Xbf);
    k_cls<<<BB, 256, 0, stream>>>(cls_tok, pos, tok);
    dim3 ge(49, 12);
    k_embed<<<ge, 256, 0, stream>>>(Xbf, Wbf, map_b, pos, tok);

    k_lnstats0<<<NTOK / 4, 256, 0, stream>>>(tok, sta);
    for (int l = 0; l < LLAYERS; l++) {
        float* srd = (l & 1) ? stb : sta;
        float* swr = (l & 1) ? sta : stb;
        dim3 gl(12, 32);
        k_layer<<<gl, 512, 0, stream>>>(tok, srd, swr,
            ln_g + (long)l * HDIM, ln_b + (long)l * HDIM,
            Wswz + (long)(0 * 144 + l * 12) * 4096, bq + (long)l * NHEAD * DHEAD,
            Wswz + (long)(1 * 144 + l * 12) * 4096, bk + (long)l * NHEAD * DHEAD,
            Wswz + (long)(2 * 144 + l * 12) * 4096, bv + (long)l * NHEAD * DHEAD);
    }
    dim3 glo(BB, 8);
    k_logits<<<glo, 256, 0, stream>>>(tok, mlp_w, mlp_b, logits);
    k_smax<<<BB, 256, 0, stream>>>(logits, out);
}